// Round 7
// baseline (749.777 us; speedup 1.0000x reference)
//
#include <hip/hip_runtime.h>
#include <math.h>

#define N_TOT 524288
#define B_GR  16384

#define LOG2E 1.44269504088896f
#define LN2   0.69314718055995f

// ---------------- small device helpers ----------------
__device__ __forceinline__ float fexp2(float x) { return __builtin_amdgcn_exp2f(x); }
__device__ __forceinline__ float flog2(float x) { return __builtin_amdgcn_logf(x); }
__device__ __forceinline__ float frcp(float x)  { return __builtin_amdgcn_rcpf(x); }
__device__ __forceinline__ float sigf(float x)  { return frcp(1.0f + fexp2(-x * LOG2E)); }

__device__ __forceinline__ float wave_sum(float v) {
#pragma unroll
  for (int o = 32; o > 0; o >>= 1) v += __shfl_xor(v, o);
  return v;
}
// Reduce TWO values across 64 lanes with 8 shuffles (vs 12).
__device__ __forceinline__ void wave_sum2(float p0, float p1, bool lo, float& e0, float& e1) {
  float a = p0 + __shfl_xor(p0, 32);
  float b = p1 + __shfl_xor(p1, 32);
  float c = lo ? a : b;
#pragma unroll
  for (int o = 16; o > 0; o >>= 1) c += __shfl_xor(c, o);
  float d = __shfl_xor(c, 32);
  e0 = lo ? c : d;
  e1 = lo ? d : c;
}

// ---------------- 64x64 f32 register-tiled GEMM pieces ----------------
__device__ __forceinline__ void load_A64(const float* __restrict__ A, size_t lda, int n0, int k0,
                                         float (*As)[68], int tid) {
#pragma unroll
  for (int s = 0; s < 4; s++) {
    int e4 = tid * 4 + s * 1024;
    int r = e4 >> 6, k = e4 & 63;
    *(float4*)&As[r][k] = *(const float4*)&A[(size_t)(n0 + r) * lda + k0 + k];
  }
}
__device__ __forceinline__ void mm64(const float (*As)[68], const float (*Wt)[68],
                                     int ty, int tx, float acc[4][4]) {
#pragma unroll
  for (int k4 = 0; k4 < 64; k4 += 4) {
    float4 b0 = *(const float4*)&Wt[k4 + 0][tx * 4];
    float4 b1 = *(const float4*)&Wt[k4 + 1][tx * 4];
    float4 b2 = *(const float4*)&Wt[k4 + 2][tx * 4];
    float4 b3 = *(const float4*)&Wt[k4 + 3][tx * 4];
#pragma unroll
    for (int i = 0; i < 4; i++) {
      float4 a = *(const float4*)&As[ty * 4 + i][k4];
      acc[i][0] = fmaf(a.w, b3.x, fmaf(a.z, b2.x, fmaf(a.y, b1.x, fmaf(a.x, b0.x, acc[i][0]))));
      acc[i][1] = fmaf(a.w, b3.y, fmaf(a.z, b2.y, fmaf(a.y, b1.y, fmaf(a.x, b0.y, acc[i][1]))));
      acc[i][2] = fmaf(a.w, b3.z, fmaf(a.z, b2.z, fmaf(a.y, b1.z, fmaf(a.x, b0.z, acc[i][2]))));
      acc[i][3] = fmaf(a.w, b3.w, fmaf(a.z, b2.w, fmaf(a.y, b1.w, fmaf(a.x, b0.w, acc[i][3]))));
    }
  }
}

// ---------------- K0a: graph offsets via binary search (batch_index is sorted) ----------------
__global__ void k_offsets(const int* __restrict__ idx, int* __restrict__ off) {
  int b = blockIdx.x * blockDim.x + threadIdx.x;
  if (b > B_GR) return;
  if (b == B_GR) { off[B_GR] = N_TOT; return; }
  int lo = 0, hi = N_TOT;
  while (lo < hi) { int mid = (lo + hi) >> 1; if (idx[mid] < b) lo = mid + 1; else hi = mid; }
  off[b] = lo;
}

// ---------------- K0b: pre-transpose all GEMM weights (tiny, once per call) ----------------
__global__ void k_prep(const float* __restrict__ w1, const float* __restrict__ pw1,
                       const float* __restrict__ pw2, const float* __restrict__ pw3,
                       float* __restrict__ w1T, float* __restrict__ pw1T,
                       float* __restrict__ pw2T, float* __restrict__ pw3T) {
  int t = blockIdx.x * 256 + threadIdx.x;          // 64 blocks * 256 = 16384 threads
  for (int i = t; i < 64 * 64; i += 16384)  { int r = i >> 6, c = i & 63;  w1T[c * 64 + r]   = w1[i]; }
  for (int i = t; i < 256 * 128; i += 16384){ int r = i >> 7, c = i & 127; pw1T[c * 256 + r] = pw1[i]; }
  for (int i = t; i < 128 * 256; i += 16384){ int r = i >> 8, c = i & 255; pw2T[c * 128 + r] = pw2[i]; }
  for (int i = t; i < 64 * 128; i += 16384) { int r = i >> 7, c = i & 127; pw3T[c * 64 + r]  = pw3[i]; }
}

// ---------------- K1: h = X@W1^T + b1 -> STORE h (GEMM paid ONCE); stats partials ----------------
__global__ __launch_bounds__(256) void k_bn_stats(const float* __restrict__ X, const float* __restrict__ W1T,
                                                  const float* __restrict__ b1, float* __restrict__ h,
                                                  float* __restrict__ pSum, float* __restrict__ pSq) {
  __shared__ float As[64][68];
  __shared__ float Wt[64][68];
  int tid = threadIdx.x, ty = tid >> 4, tx = tid & 15;
  int n0 = blockIdx.x * 64;
  float acc[4][4] = {};
  load_A64(X, 64, n0, 0, As, tid);
  load_A64(W1T, 64, 0, 0, Wt, tid);
  __syncthreads();
  mm64(As, Wt, ty, tx, acc);
  float4 bv = *(const float4*)&b1[tx * 4];
  float cs[4] = {0, 0, 0, 0}, cq[4] = {0, 0, 0, 0};
#pragma unroll
  for (int i = 0; i < 4; i++) {
    float4 o;
    o.x = acc[i][0] + bv.x; o.y = acc[i][1] + bv.y;
    o.z = acc[i][2] + bv.z; o.w = acc[i][3] + bv.w;
    *(float4*)&h[(size_t)(n0 + ty * 4 + i) * 64 + tx * 4] = o;
    cs[0] += o.x; cq[0] = fmaf(o.x, o.x, cq[0]);
    cs[1] += o.y; cq[1] = fmaf(o.y, o.y, cq[1]);
    cs[2] += o.z; cq[2] = fmaf(o.z, o.z, cq[2]);
    cs[3] += o.w; cq[3] = fmaf(o.w, o.w, cq[3]);
  }
  __syncthreads();
  float* red = &As[0][0];
#pragma unroll
  for (int j = 0; j < 4; j++) {
    red[ty * 64 + tx * 4 + j] = cs[j];
    red[1024 + ty * 64 + tx * 4 + j] = cq[j];
  }
  __syncthreads();
  if (tid < 64) {
    float s = 0, q = 0;
#pragma unroll
    for (int t = 0; t < 16; t++) { s += red[t * 64 + tid]; q += red[1024 + t * 64 + tid]; }
    pSum[(size_t)blockIdx.x * 64 + tid] = s;
    pSq[(size_t)blockIdx.x * 64 + tid] = q;
  }
}

// ---------------- K2a: finalize BN -> affine aff[0:64]=A, aff[64:128]=C ----------------
__global__ __launch_bounds__(256) void k_bn_final(const float* __restrict__ pSum, const float* __restrict__ pSq,
                                                  const float* __restrict__ bn_g, const float* __restrict__ bn_b,
                                                  const float* __restrict__ c_b1, float* __restrict__ aff) {
  int c = blockIdx.x;
  float s = 0, q = 0;
  for (int i = threadIdx.x; i < 8192; i += 256) {
    s += pSum[(size_t)i * 64 + c];
    q += pSq[(size_t)i * 64 + c];
  }
  __shared__ float rs[256], rq[256];
  rs[threadIdx.x] = s; rq[threadIdx.x] = q;
  __syncthreads();
  for (int st = 128; st > 0; st >>= 1) {
    if (threadIdx.x < st) { rs[threadIdx.x] += rs[threadIdx.x + st]; rq[threadIdx.x] += rq[threadIdx.x + st]; }
    __syncthreads();
  }
  if (threadIdx.x == 0) {
    float mu = rs[0] / (float)N_TOT;
    float var = rq[0] / (float)N_TOT - mu * mu;
    var = fmaxf(var, 0.0f);
    float A = bn_g[c] * rsqrtf(var + 1e-5f);
    aff[c] = A;
    aff[64 + c] = bn_b[c] + (0.0f - mu) * A + bn_b[c] * 0.0f;  // placeholder, fixed below
  }
  // NOTE: b1 already added into h inside k_bn_stats, so affine shift must NOT re-add it:
  // hhat = (h - mu)*A + bn_b  ->  C = bn_b - mu*A.  (written above minus the c_b1 term)
  if (threadIdx.x == 0) {
    float mu = rs[0] / (float)N_TOT;
    float var = rq[0] / (float)N_TOT - mu * mu;
    var = fmaxf(var, 0.0f);
    float A = bn_g[c] * rsqrtf(var + 1e-5f);
    aff[c] = A;
    aff[64 + c] = bn_b[c] - mu * A;
  }
}

// ---------------- K2b: LSTM step1 from biases only; shared part of step-2 gates ----------------
__global__ __launch_bounds__(256) void k_lstm1(const float* __restrict__ bih, const float* __restrict__ bhh,
                                               const float* __restrict__ wih, const float* __restrict__ whh,
                                               float* __restrict__ q1, float* __restrict__ c1, float* __restrict__ sh2) {
  __shared__ float g1[256];
  __shared__ float q1s[64];
  int tid = threadIdx.x;
  g1[tid] = bih[tid] + bhh[tid];
  __syncthreads();
  if (tid < 64) {
    float ig = sigf(g1[tid]);
    float gg = tanhf(g1[128 + tid]);
    float cc = ig * gg;
    float og = sigf(g1[192 + tid]);
    float qv = og * tanhf(cc);
    q1s[tid] = qv; q1[tid] = qv; c1[tid] = cc;
  }
  __syncthreads();
  float acc = g1[tid];
  for (int k = 0; k < 64; k++)
    acc = fmaf(wih[(size_t)tid * 128 + k] + whh[(size_t)tid * 64 + k], q1s[k], acc);
  sh2[tid] = acc;
}

// ---------------- K3: streaming gate: coalesced h -> LDS[64][65] -> thread-per-row dot ----------------
__global__ __launch_bounds__(256) void k_gate_h(const float* __restrict__ h, const float* __restrict__ aff,
                                                const float* __restrict__ w2, const float* __restrict__ cb2,
                                                const float* __restrict__ eps_gate,
                                                float* __restrict__ lamWS, float* __restrict__ lamOut,
                                                int* __restrict__ presCnt) {
  __shared__ float Hs[64][65];   // pad 65: bank=(r+d)%32 -> max 2-way aliasing (free)
  __shared__ float A2s[64], C2s[64], w2s[64];
  int tid = threadIdx.x;
  if (tid < 64) { A2s[tid] = aff[tid]; C2s[tid] = aff[64 + tid]; w2s[tid] = w2[tid]; }
  int n0 = blockIdx.x * 64;
  // stage: coalesced float4 global reads, scalar LDS stores (2-way max)
#pragma unroll
  for (int s = 0; s < 4; s++) {
    int e4 = tid * 4 + s * 1024;
    int r = e4 >> 6, c = e4 & 63;
    float4 v = *(const float4*)&h[(size_t)(n0 + r) * 64 + c];
    Hs[r][c] = v.x; Hs[r][c + 1] = v.y; Hs[r][c + 2] = v.z; Hs[r][c + 3] = v.w;
  }
  __syncthreads();
  // 4 threads per row, each a 16-dim quarter dot, all in-register
  int r = tid >> 2, q = tid & 3;
  float p = 0.f;
#pragma unroll
  for (int j = 0; j < 16; j++) {
    int d = q * 16 + j;
    p = fmaf(fmaxf(fmaf(Hs[r][d], A2s[d], C2s[d]), 0.f), w2s[d], p);
  }
  p += __shfl_xor(p, 1);
  p += __shfl_xor(p, 2);               // all 4 quad lanes now hold the row sum
  p += cb2[0];
  unsigned long long m = __ballot(q == 0 && p > 0.0f);
  if (q == 0) {
    int row = n0 + r;
    float eg = eps_gate[row];
    float eps = 0.9999f - 0.9998f * eg;
    float gi = (flog2(eps) - flog2(1.0f - eps)) * LN2;
    float lam = sigf(gi + p);
    lamWS[row] = lam;
    lamOut[row] = lam;
  }
  if ((tid & 63) == 0) atomicAdd(presCnt, (int)__popcll(m));
}

// ---------------- K4: wave-per-graph: stats, noisy, KL, 2-stream deferred-max online softmax ----------------
__global__ __launch_bounds__(256) void k_graph(const float* __restrict__ X, const float* __restrict__ noise,
                                               const float* __restrict__ lam, const int* __restrict__ off,
                                               const float* __restrict__ q1g,
                                               float* __restrict__ noisy, float* __restrict__ r1,
                                               float* __restrict__ klp) {
  int wg = blockIdx.x * 4 + (threadIdx.x >> 6);
  int lane = threadIdx.x & 63;
  bool lo = lane < 32;
  int n0 = off[wg], cnt = off[wg + 1] - n0;
  if (cnt == 0) {
    r1[(size_t)wg * 64 + lane] = 0.0f;
    if (lane == 0) klp[wg] = 0.0f;
    return;
  }
  float q1v2 = q1g[lane] * LOG2E;
  const float* xp = X + (size_t)n0 * 64 + lane;
  float s0 = 0.f, q0 = 0.f, s1 = 0.f, q1_ = 0.f;
  int n = 0;
  for (; n + 2 <= cnt; n += 2) {
    float a = xp[(size_t)n * 64], b = xp[(size_t)(n + 1) * 64];
    s0 += a; q0 = fmaf(a, a, q0);
    s1 += b; q1_ = fmaf(b, b, q1_);
  }
  if (n < cnt) { float a = xp[(size_t)n * 64]; s0 += a; q0 = fmaf(a, a, q0); }
  float c = (float)cnt;
  float mean = (s0 + s1) / c;
  float var = fmaxf(((q0 + q1_) - c * mean * mean) / fmaxf(c - 1.f, 1.f), 0.f);
  float sd = sqrtf(var);
  float inv = frcp(sd + 1e-7f);
  float S1 = wave_sum(sd * sd * inv * inv);
  const float* zp = noise + (size_t)n0 * 64 + lane;
  float* nw = noisy + (size_t)n0 * 64 + lane;
  const float THR = 8.f;
  float t2acc = 0.f, sumOm2 = 0.f;
  float m0 = -INFINITY, l0 = 0.f, r0 = 0.f;
  float m1 = -INFINITY, l1 = 0.f, r1a = 0.f;
  n = 0;
  for (; n + 2 <= cnt; n += 2) {
    float lamA = lam[n0 + n], lamB = lam[n0 + n + 1];
    float xA = xp[(size_t)n * 64], xB = xp[(size_t)(n + 1) * 64];
    float zA = zp[(size_t)n * 64], zB = zp[(size_t)(n + 1) * 64];
    float omA = 1.f - lamA, omB = 1.f - lamB;
    float nvA = fmaf(lamA, xA, omA * mean) + zA * (omA * sd);
    float nvB = fmaf(lamB, xB, omB * mean) + zB * (omB * sd);
    nw[(size_t)n * 64] = nvA;
    nw[(size_t)(n + 1) * 64] = nvB;
    float ldA = lamA * (xA - mean) * inv; t2acc = fmaf(ldA, ldA, t2acc);
    float ldB = lamB * (xB - mean) * inv; t2acc = fmaf(ldB, ldB, t2acc);
    sumOm2 = fmaf(omA, omA, sumOm2); sumOm2 = fmaf(omB, omB, sumOm2);
    float e0, e1;
    wave_sum2(nvA * q1v2, nvB * q1v2, lo, e0, e1);
    if (e0 > m0 + THR) { float sc = fexp2(m0 - e0); l0 *= sc; r0 *= sc; m0 = e0; }
    float pA = fexp2(e0 - m0); l0 += pA; r0 = fmaf(pA, nvA, r0);
    if (e1 > m1 + THR) { float sc = fexp2(m1 - e1); l1 *= sc; r1a *= sc; m1 = e1; }
    float pB = fexp2(e1 - m1); l1 += pB; r1a = fmaf(pB, nvB, r1a);
  }
  if (n < cnt) {
    float lamA = lam[n0 + n];
    float xA = xp[(size_t)n * 64];
    float zA = zp[(size_t)n * 64];
    float omA = 1.f - lamA;
    float nvA = fmaf(lamA, xA, omA * mean) + zA * (omA * sd);
    nw[(size_t)n * 64] = nvA;
    float ldA = lamA * (xA - mean) * inv; t2acc = fmaf(ldA, ldA, t2acc);
    sumOm2 = fmaf(omA, omA, sumOm2);
    float e0 = wave_sum(nvA * q1v2);
    if (e0 > m0 + THR) { float sc = fexp2(m0 - e0); l0 *= sc; r0 *= sc; m0 = e0; }
    float pA = fexp2(e0 - m0); l0 += pA; r0 = fmaf(pA, nvA, r0);
  }
  float M = fmaxf(m0, m1);
  float sc0 = fexp2(m0 - M), sc1 = fexp2(m1 - M);
  float L = l0 * sc0 + l1 * sc1;
  float R = r0 * sc0 + r1a * sc1;
  r1[(size_t)wg * 64 + lane] = R / L;
  float t2tot = wave_sum(t2acc);
  if (lane == 0) klp[wg] = fmaf(0.5f * sumOm2, S1, t2tot);
}

// ---------------- K5: Set2Set step-2 LSTM: gates = sh2 + r1 @ R^T, 16 graphs/block ----------------
__global__ __launch_bounds__(256) void k_lstm2(const float* __restrict__ r1, const float* __restrict__ wih,
                                               const float* __restrict__ sh2, const float* __restrict__ c1g,
                                               float* __restrict__ qstar) {
  __shared__ float Rs[2][64][64];
  __shared__ float r1s[16][64];
  __shared__ float sh2s[256], c1s[64];
  int tid = threadIdx.x;
  int d = tid & 63, rg = tid >> 6;
  int g0 = blockIdx.x * 16;
  sh2s[tid] = sh2[tid];
  if (tid < 64) c1s[tid] = c1g[tid];
  {
    int e4 = tid * 4;
    int r = e4 >> 6, k = e4 & 63;
    *(float4*)&r1s[r][k] = *(const float4*)&r1[(size_t)(g0 + r) * 64 + k];
  }
  float acc[4][4] = {};
#pragma unroll
  for (int jp = 0; jp < 2; jp++) {
    __syncthreads();
    {
      int gate = jp * 2 + (tid >= 128 ? 1 : 0);
      int dd2 = tid & 63;
      if ((tid & 127) < 64) {
        int row = gate * 64 + dd2;
        const float* src = &wih[(size_t)row * 128 + 64];
        for (int k = 0; k < 64; k += 4) {
          float4 v = *(const float4*)&src[k];
          Rs[gate - jp * 2][k + 0][dd2] = v.x;
          Rs[gate - jp * 2][k + 1][dd2] = v.y;
          Rs[gate - jp * 2][k + 2][dd2] = v.z;
          Rs[gate - jp * 2][k + 3][dd2] = v.w;
        }
      }
    }
    __syncthreads();
    for (int k = 0; k < 64; k++) {
      float bj0 = Rs[0][k][d];
      float bj1 = Rs[1][k][d];
#pragma unroll
      for (int i = 0; i < 4; i++) {
        float a = r1s[rg * 4 + i][k];
        acc[i][jp * 2 + 0] = fmaf(a, bj0, acc[i][jp * 2 + 0]);
        acc[i][jp * 2 + 1] = fmaf(a, bj1, acc[i][jp * 2 + 1]);
      }
    }
  }
#pragma unroll
  for (int i = 0; i < 4; i++) {
    int row = g0 + rg * 4 + i;
    float ig = acc[i][0] + sh2s[d];
    float fg = acc[i][1] + sh2s[64 + d];
    float gg = acc[i][2] + sh2s[128 + d];
    float og = acc[i][3] + sh2s[192 + d];
    float c2 = sigf(fg) * c1s[d] + sigf(ig) * tanhf(gg);
    float q2 = sigf(og) * tanhf(c2);
    qstar[(size_t)row * 128 + d] = q2;
  }
}

// ---------------- K6: attention step 2, wave-per-graph, 2-stream deferred-max online softmax ----------------
__global__ __launch_bounds__(256) void k_attn2(const float* __restrict__ noisy, const int* __restrict__ off,
                                               float* __restrict__ qstar) {
  int wg = blockIdx.x * 4 + (threadIdx.x >> 6);
  int lane = threadIdx.x & 63;
  bool lo = lane < 32;
  int n0 = off[wg], cnt = off[wg + 1] - n0;
  float q2v2 = qstar[(size_t)wg * 128 + lane] * LOG2E;
  if (cnt == 0) { qstar[(size_t)wg * 128 + 64 + lane] = 0.f; return; }
  const float* np_ = noisy + (size_t)n0 * 64 + lane;
  const float THR = 8.f;
  float m0 = -INFINITY, l0 = 0.f, r0 = 0.f;
  float m1 = -INFINITY, l1 = 0.f, r1a = 0.f;
  int n = 0;
  for (; n + 2 <= cnt; n += 2) {
    float nvA = np_[(size_t)n * 64];
    float nvB = np_[(size_t)(n + 1) * 64];
    float e0, e1;
    wave_sum2(nvA * q2v2, nvB * q2v2, lo, e0, e1);
    if (e0 > m0 + THR) { float sc = fexp2(m0 - e0); l0 *= sc; r0 *= sc; m0 = e0; }
    float pA = fexp2(e0 - m0); l0 += pA; r0 = fmaf(pA, nvA, r0);
    if (e1 > m1 + THR) { float sc = fexp2(m1 - e1); l1 *= sc; r1a *= sc; m1 = e1; }
    float pB = fexp2(e1 - m1); l1 += pB; r1a = fmaf(pB, nvB, r1a);
  }
  if (n < cnt) {
    float nvA = np_[(size_t)n * 64];
    float e0 = wave_sum(nvA * q2v2);
    if (e0 > m0 + THR) { float sc = fexp2(m0 - e0); l0 *= sc; r0 *= sc; m0 = e0; }
    float pA = fexp2(e0 - m0); l0 += pA; r0 = fmaf(pA, nvA, r0);
  }
  float M = fmaxf(m0, m1);
  float sc0 = fexp2(m0 - M), sc1 = fexp2(m1 - M);
  float L = l0 * sc0 + l1 * sc1;
  float R = r0 * sc0 + r1a * sc1;
  qstar[(size_t)wg * 128 + 64 + lane] = R / L;
}

// ---------------- K7/8/9: predictor linear layers (pre-transposed weights) ----------------
template <int KDIM, int ODIM, bool RELU>
__global__ __launch_bounds__(256) void k_linear(const float* __restrict__ A, const float* __restrict__ WT,
                                                const float* __restrict__ bias, float* __restrict__ C) {
  __shared__ float As[64][68];
  __shared__ float Wt[64][68];
  int tid = threadIdx.x, ty = tid >> 4, tx = tid & 15;
  int n0 = blockIdx.x * 64, c0 = blockIdx.y * 64;
  float acc[4][4] = {};
  for (int kt = 0; kt < KDIM; kt += 64) {
    __syncthreads();
    load_A64(A, KDIM, n0, kt, As, tid);
    load_A64(WT, ODIM, kt, c0, Wt, tid);   // WT is [KDIM][ODIM] row-major
    __syncthreads();
    mm64(As, Wt, ty, tx, acc);
  }
#pragma unroll
  for (int i = 0; i < 4; i++) {
    int row = n0 + ty * 4 + i;
    float4 o;
    float v0 = acc[i][0] + bias[c0 + tx * 4 + 0];
    float v1 = acc[i][1] + bias[c0 + tx * 4 + 1];
    float v2 = acc[i][2] + bias[c0 + tx * 4 + 2];
    float v3 = acc[i][3] + bias[c0 + tx * 4 + 3];
    if (RELU) { v0 = fmaxf(v0, 0.f); v1 = fmaxf(v1, 0.f); v2 = fmaxf(v2, 0.f); v3 = fmaxf(v3, 0.f); }
    o.x = v0; o.y = v1; o.z = v2; o.w = v3;
    *(float4*)&C[(size_t)row * ODIM + c0 + tx * 4] = o;
  }
}

// ---------------- K10: final scalars ----------------
__global__ __launch_bounds__(256) void k_final(const float* __restrict__ klp, const int* __restrict__ presCnt,
                                               float* __restrict__ out) {
  __shared__ float red[256];
  float s = 0.0f;
  for (int i = threadIdx.x; i < B_GR; i += 256) s += klp[i];
  red[threadIdx.x] = s;
  __syncthreads();
  for (int st = 128; st > 0; st >>= 1) {
    if (threadIdx.x < st) red[threadIdx.x] += red[threadIdx.x + st];
    __syncthreads();
  }
  if (threadIdx.x == 0) {
    out[(size_t)B_GR * 64] = red[0] / (float)(B_GR * 64);
    out[(size_t)B_GR * 64 + 1] = (float)(*presCnt) / (float)N_TOT;
  }
}

// ---------------- launcher ----------------
extern "C" void kernel_launch(void* const* d_in, const int* in_sizes, int n_in,
                              void* d_out, int out_size, void* d_ws, size_t ws_size,
                              hipStream_t stream) {
  const float* features = (const float*)d_in[0];
  const int*   bidx     = (const int*)d_in[1];
  const float* eps_gate = (const float*)d_in[2];
  const float* noise    = (const float*)d_in[3];
  const float* c_w1 = (const float*)d_in[4];
  const float* c_b1 = (const float*)d_in[5];
  const float* bn_g = (const float*)d_in[6];
  const float* bn_b = (const float*)d_in[7];
  const float* c_w2 = (const float*)d_in[8];
  const float* c_b2 = (const float*)d_in[9];
  const float* wih  = (const float*)d_in[10];
  const float* whh  = (const float*)d_in[11];
  const float* bih  = (const float*)d_in[12];
  const float* bhh  = (const float*)d_in[13];
  const float* p_w1 = (const float*)d_in[14];
  const float* p_b1 = (const float*)d_in[15];
  const float* p_w2 = (const float*)d_in[16];
  const float* p_b2 = (const float*)d_in[17];
  const float* p_w3 = (const float*)d_in[18];
  const float* p_b3 = (const float*)d_in[19];
  float* out = (float*)d_out;

  float* wsf   = (float*)d_ws;
  int*   offp  = (int*)wsf;                                 // (B+1) ints
  float* pSum  = wsf + 16448;                               // 8192*64
  float* pSq   = pSum + 524288;                             // 8192*64
  float* aff   = pSq + 524288;                              // 128
  float* q1w   = aff + 128;                                 // 64
  float* c1w   = q1w + 64;                                  // 64
  float* sh2w  = c1w + 64;                                  // 256
  float* lamw  = sh2w + 256;                                // N
  float* cw1T  = lamw + (size_t)N_TOT;                      // 64*64
  float* pw1T  = cw1T + 4096;                               // 128*256
  float* pw2T  = pw1T + 32768;                              // 256*128
  float* pw3T  = pw2T + 32768;                              // 128*64
  float* hw    = pw3T + 8192;                               // N*64  (h; later overwritten by noisy)
  float* noisyw = hw;                                       // shared buffer: h dead after k_gate_h
  float* r1w    = hw + (size_t)N_TOT * 64;                  // B*64
  float* qstarw = r1w + (size_t)B_GR * 64;                  // B*128
  float* z1w    = qstarw + (size_t)B_GR * 128;              // B*256
  float* z2w    = z1w + (size_t)B_GR * 256;                 // B*128
  float* klpw   = z2w + (size_t)B_GR * 128;                 // B
  int*   presw  = (int*)(klpw + B_GR);

  float* lamOut = out + (size_t)B_GR * 64 + 2;

  hipMemsetAsync(presw, 0, sizeof(int), stream);

  k_offsets<<<(B_GR + 1 + 255) / 256, 256, 0, stream>>>(bidx, offp);
  k_prep<<<64, 256, 0, stream>>>(c_w1, p_w1, p_w2, p_w3, cw1T, pw1T, pw2T, pw3T);
  k_bn_stats<<<N_TOT / 64, 256, 0, stream>>>(features, cw1T, c_b1, hw, pSum, pSq);
  k_bn_final<<<64, 256, 0, stream>>>(pSum, pSq, bn_g, bn_b, c_b1, aff);
  k_lstm1<<<1, 256, 0, stream>>>(bih, bhh, wih, whh, q1w, c1w, sh2w);
  k_gate_h<<<N_TOT / 64, 256, 0, stream>>>(hw, aff, c_w2, c_b2, eps_gate, lamw, lamOut, presw);
  k_graph<<<B_GR / 4, 256, 0, stream>>>(features, noise, lamw, offp, q1w, noisyw, r1w, klpw);
  k_lstm2<<<B_GR / 16, 256, 0, stream>>>(r1w, wih, sh2w, c1w, qstarw);
  k_attn2<<<B_GR / 4, 256, 0, stream>>>(noisyw, offp, qstarw);
  k_linear<128, 256, true><<<dim3(B_GR / 64, 4), 256, 0, stream>>>(qstarw, pw1T, p_b1, z1w);
  k_linear<256, 128, true><<<dim3(B_GR / 64, 2), 256, 0, stream>>>(z1w, pw2T, p_b2, z2w);
  k_linear<128, 64, false><<<dim3(B_GR / 64, 1), 256, 0, stream>>>(z2w, pw3T, p_b3, out);
  k_final<<<1, 256, 0, stream>>>(klpw, presw, out);
}

// Round 8
// 395.709 us; speedup vs baseline: 1.8948x; 1.8948x over previous
//
#include <hip/hip_runtime.h>
#include <math.h>

#define N_TOT 524288
#define B_GR  16384

#define LOG2E 1.44269504088896f
#define LN2   0.69314718055995f

// ---------------- small device helpers ----------------
__device__ __forceinline__ float fexp2(float x) { return __builtin_amdgcn_exp2f(x); }
__device__ __forceinline__ float flog2(float x) { return __builtin_amdgcn_logf(x); }
__device__ __forceinline__ float frcp(float x)  { return __builtin_amdgcn_rcpf(x); }
__device__ __forceinline__ float sigf(float x)  { return frcp(1.0f + fexp2(-x * LOG2E)); }

__device__ __forceinline__ float wave_sum(float v) {
#pragma unroll
  for (int o = 32; o > 0; o >>= 1) v += __shfl_xor(v, o);
  return v;
}
// Reduce TWO values across 64 lanes with 8 shuffles (vs 12).
__device__ __forceinline__ void wave_sum2(float p0, float p1, bool lo, float& e0, float& e1) {
  float a = p0 + __shfl_xor(p0, 32);
  float b = p1 + __shfl_xor(p1, 32);
  float c = lo ? a : b;
#pragma unroll
  for (int o = 16; o > 0; o >>= 1) c += __shfl_xor(c, o);
  float d = __shfl_xor(c, 32);
  e0 = lo ? c : d;
  e1 = lo ? d : c;
}

// ---------------- 64x64 f32 register-tiled GEMM pieces ----------------
__device__ __forceinline__ void load_A64(const float* __restrict__ A, size_t lda, int n0, int k0,
                                         float (*As)[68], int tid) {
#pragma unroll
  for (int s = 0; s < 4; s++) {
    int e4 = tid * 4 + s * 1024;
    int r = e4 >> 6, k = e4 & 63;
    *(float4*)&As[r][k] = *(const float4*)&A[(size_t)(n0 + r) * lda + k0 + k];
  }
}
__device__ __forceinline__ void mm64(const float (*As)[68], const float (*Wt)[68],
                                     int ty, int tx, float acc[4][4]) {
#pragma unroll
  for (int k4 = 0; k4 < 64; k4 += 4) {
    float4 b0 = *(const float4*)&Wt[k4 + 0][tx * 4];
    float4 b1 = *(const float4*)&Wt[k4 + 1][tx * 4];
    float4 b2 = *(const float4*)&Wt[k4 + 2][tx * 4];
    float4 b3 = *(const float4*)&Wt[k4 + 3][tx * 4];
#pragma unroll
    for (int i = 0; i < 4; i++) {
      float4 a = *(const float4*)&As[ty * 4 + i][k4];
      acc[i][0] = fmaf(a.w, b3.x, fmaf(a.z, b2.x, fmaf(a.y, b1.x, fmaf(a.x, b0.x, acc[i][0]))));
      acc[i][1] = fmaf(a.w, b3.y, fmaf(a.z, b2.y, fmaf(a.y, b1.y, fmaf(a.x, b0.y, acc[i][1]))));
      acc[i][2] = fmaf(a.w, b3.z, fmaf(a.z, b2.z, fmaf(a.y, b1.z, fmaf(a.x, b0.z, acc[i][2]))));
      acc[i][3] = fmaf(a.w, b3.w, fmaf(a.z, b2.w, fmaf(a.y, b1.w, fmaf(a.x, b0.w, acc[i][3]))));
    }
  }
}

// ---------------- K0a: graph offsets via binary search (batch_index is sorted) ----------------
__global__ void k_offsets(const int* __restrict__ idx, int* __restrict__ off) {
  int b = blockIdx.x * blockDim.x + threadIdx.x;
  if (b > B_GR) return;
  if (b == B_GR) { off[B_GR] = N_TOT; return; }
  int lo = 0, hi = N_TOT;
  while (lo < hi) { int mid = (lo + hi) >> 1; if (idx[mid] < b) lo = mid + 1; else hi = mid; }
  off[b] = lo;
}

// ---------------- K0b: pre-transpose all GEMM weights (tiny, once per call) ----------------
__global__ void k_prep(const float* __restrict__ w1, const float* __restrict__ pw1,
                       const float* __restrict__ pw2, const float* __restrict__ pw3,
                       float* __restrict__ w1T, float* __restrict__ pw1T,
                       float* __restrict__ pw2T, float* __restrict__ pw3T) {
  int t = blockIdx.x * 256 + threadIdx.x;          // 64 blocks * 256 = 16384 threads
  for (int i = t; i < 64 * 64; i += 16384)  { int r = i >> 6, c = i & 63;  w1T[c * 64 + r]   = w1[i]; }
  for (int i = t; i < 256 * 128; i += 16384){ int r = i >> 7, c = i & 127; pw1T[c * 256 + r] = pw1[i]; }
  for (int i = t; i < 128 * 256; i += 16384){ int r = i >> 8, c = i & 255; pw2T[c * 128 + r] = pw2[i]; }
  for (int i = t; i < 64 * 128; i += 16384) { int r = i >> 7, c = i & 127; pw3T[c * 64 + r]  = pw3[i]; }
}

// ---------------- K1: h = X@W1^T + b1 -> STORE h (GEMM paid ONCE); stats partials ----------------
__global__ __launch_bounds__(256) void k_bn_stats(const float* __restrict__ X, const float* __restrict__ W1T,
                                                  const float* __restrict__ b1, float* __restrict__ h,
                                                  float* __restrict__ pSum, float* __restrict__ pSq) {
  __shared__ float As[64][68];
  __shared__ float Wt[64][68];
  int tid = threadIdx.x, ty = tid >> 4, tx = tid & 15;
  int n0 = blockIdx.x * 64;
  float acc[4][4] = {};
  load_A64(X, 64, n0, 0, As, tid);
  load_A64(W1T, 64, 0, 0, Wt, tid);
  __syncthreads();
  mm64(As, Wt, ty, tx, acc);
  float4 bv = *(const float4*)&b1[tx * 4];
  float cs[4] = {0, 0, 0, 0}, cq[4] = {0, 0, 0, 0};
#pragma unroll
  for (int i = 0; i < 4; i++) {
    float4 o;
    o.x = acc[i][0] + bv.x; o.y = acc[i][1] + bv.y;
    o.z = acc[i][2] + bv.z; o.w = acc[i][3] + bv.w;
    *(float4*)&h[(size_t)(n0 + ty * 4 + i) * 64 + tx * 4] = o;
    cs[0] += o.x; cq[0] = fmaf(o.x, o.x, cq[0]);
    cs[1] += o.y; cq[1] = fmaf(o.y, o.y, cq[1]);
    cs[2] += o.z; cq[2] = fmaf(o.z, o.z, cq[2]);
    cs[3] += o.w; cq[3] = fmaf(o.w, o.w, cq[3]);
  }
  __syncthreads();
  float* red = &As[0][0];
#pragma unroll
  for (int j = 0; j < 4; j++) {
    red[ty * 64 + tx * 4 + j] = cs[j];
    red[1024 + ty * 64 + tx * 4 + j] = cq[j];
  }
  __syncthreads();
  if (tid < 64) {
    float s = 0, q = 0;
#pragma unroll
    for (int t = 0; t < 16; t++) { s += red[t * 64 + tid]; q += red[1024 + t * 64 + tid]; }
    pSum[(size_t)blockIdx.x * 64 + tid] = s;
    pSq[(size_t)blockIdx.x * 64 + tid] = q;
  }
}

// ---------------- K2a: finalize BN -> affine aff[0:64]=A, aff[64:128]=C ----------------
// b1 is already inside h, so hhat = (h - mu)*A + bn_b  ->  C = bn_b - mu*A.
__global__ __launch_bounds__(256) void k_bn_final(const float* __restrict__ pSum, const float* __restrict__ pSq,
                                                  const float* __restrict__ bn_g, const float* __restrict__ bn_b,
                                                  float* __restrict__ aff) {
  int c = blockIdx.x;
  float s = 0, q = 0;
  for (int i = threadIdx.x; i < 8192; i += 256) {
    s += pSum[(size_t)i * 64 + c];
    q += pSq[(size_t)i * 64 + c];
  }
  __shared__ float rs[256], rq[256];
  rs[threadIdx.x] = s; rq[threadIdx.x] = q;
  __syncthreads();
  for (int st = 128; st > 0; st >>= 1) {
    if (threadIdx.x < st) { rs[threadIdx.x] += rs[threadIdx.x + st]; rq[threadIdx.x] += rq[threadIdx.x + st]; }
    __syncthreads();
  }
  if (threadIdx.x == 0) {
    float mu = rs[0] / (float)N_TOT;
    float var = rq[0] / (float)N_TOT - mu * mu;
    var = fmaxf(var, 0.0f);
    float A = bn_g[c] * rsqrtf(var + 1e-5f);
    aff[c] = A;
    aff[64 + c] = bn_b[c] - mu * A;
  }
}

// ---------------- K2b: LSTM step1 from biases only; shared part of step-2 gates ----------------
__global__ __launch_bounds__(256) void k_lstm1(const float* __restrict__ bih, const float* __restrict__ bhh,
                                               const float* __restrict__ wih, const float* __restrict__ whh,
                                               float* __restrict__ q1, float* __restrict__ c1, float* __restrict__ sh2) {
  __shared__ float g1[256];
  __shared__ float q1s[64];
  int tid = threadIdx.x;
  g1[tid] = bih[tid] + bhh[tid];
  __syncthreads();
  if (tid < 64) {
    float ig = sigf(g1[tid]);
    float gg = tanhf(g1[128 + tid]);
    float cc = ig * gg;
    float og = sigf(g1[192 + tid]);
    float qv = og * tanhf(cc);
    q1s[tid] = qv; q1[tid] = qv; c1[tid] = cc;
  }
  __syncthreads();
  float acc = g1[tid];
  for (int k = 0; k < 64; k++)
    acc = fmaf(wih[(size_t)tid * 128 + k] + whh[(size_t)tid * 64 + k], q1s[k], acc);
  sh2[tid] = acc;
}

// ---------------- K3: streaming gate: coalesced h -> LDS -> thread-per-row dot.
// NO global atomics: per-block preserve-count goes to presPart[block] (summed in k_final).
__global__ __launch_bounds__(256) void k_gate_h(const float* __restrict__ h, const float* __restrict__ aff,
                                                const float* __restrict__ w2, const float* __restrict__ cb2,
                                                const float* __restrict__ eps_gate,
                                                float* __restrict__ lamWS, float* __restrict__ lamOut,
                                                int* __restrict__ presPart) {
  __shared__ float Hs[64][65];   // pad 65: max 2-way aliasing (free)
  __shared__ float A2s[64], C2s[64], w2s[64];
  __shared__ int pcnt[4];
  int tid = threadIdx.x;
  if (tid < 64) { A2s[tid] = aff[tid]; C2s[tid] = aff[64 + tid]; w2s[tid] = w2[tid]; }
  int n0 = blockIdx.x * 64;
#pragma unroll
  for (int s = 0; s < 4; s++) {
    int e4 = tid * 4 + s * 1024;
    int r = e4 >> 6, c = e4 & 63;
    float4 v = *(const float4*)&h[(size_t)(n0 + r) * 64 + c];
    Hs[r][c] = v.x; Hs[r][c + 1] = v.y; Hs[r][c + 2] = v.z; Hs[r][c + 3] = v.w;
  }
  __syncthreads();
  // 4 threads per row, each a 16-dim quarter dot, all in-register
  int r = tid >> 2, q = tid & 3;
  float p = 0.f;
#pragma unroll
  for (int j = 0; j < 16; j++) {
    int d = q * 16 + j;
    p = fmaf(fmaxf(fmaf(Hs[r][d], A2s[d], C2s[d]), 0.f), w2s[d], p);
  }
  p += __shfl_xor(p, 1);
  p += __shfl_xor(p, 2);               // all 4 quad lanes now hold the row sum
  p += cb2[0];
  unsigned long long m = __ballot(q == 0 && p > 0.0f);
  if ((tid & 63) == 0) pcnt[tid >> 6] = (int)__popcll(m);
  if (q == 0) {
    int row = n0 + r;
    float eg = eps_gate[row];
    float eps = 0.9999f - 0.9998f * eg;
    float gi = (flog2(eps) - flog2(1.0f - eps)) * LN2;
    float lam = sigf(gi + p);
    lamWS[row] = lam;
    lamOut[row] = lam;
  }
  __syncthreads();
  if (tid == 0) presPart[blockIdx.x] = pcnt[0] + pcnt[1] + pcnt[2] + pcnt[3];
}

// ---------------- K4: wave-per-graph: stats, noisy, KL, 2-stream deferred-max online softmax ----------------
__global__ __launch_bounds__(256) void k_graph(const float* __restrict__ X, const float* __restrict__ noise,
                                               const float* __restrict__ lam, const int* __restrict__ off,
                                               const float* __restrict__ q1g,
                                               float* __restrict__ noisy, float* __restrict__ r1,
                                               float* __restrict__ klp) {
  int wg = blockIdx.x * 4 + (threadIdx.x >> 6);
  int lane = threadIdx.x & 63;
  bool lo = lane < 32;
  int n0 = off[wg], cnt = off[wg + 1] - n0;
  if (cnt == 0) {
    r1[(size_t)wg * 64 + lane] = 0.0f;
    if (lane == 0) klp[wg] = 0.0f;
    return;
  }
  float q1v2 = q1g[lane] * LOG2E;
  const float* xp = X + (size_t)n0 * 64 + lane;
  float s0 = 0.f, q0 = 0.f, s1 = 0.f, q1_ = 0.f;
  int n = 0;
  for (; n + 2 <= cnt; n += 2) {
    float a = xp[(size_t)n * 64], b = xp[(size_t)(n + 1) * 64];
    s0 += a; q0 = fmaf(a, a, q0);
    s1 += b; q1_ = fmaf(b, b, q1_);
  }
  if (n < cnt) { float a = xp[(size_t)n * 64]; s0 += a; q0 = fmaf(a, a, q0); }
  float c = (float)cnt;
  float mean = (s0 + s1) / c;
  float var = fmaxf(((q0 + q1_) - c * mean * mean) / fmaxf(c - 1.f, 1.f), 0.f);
  float sd = sqrtf(var);
  float inv = frcp(sd + 1e-7f);
  float S1 = wave_sum(sd * sd * inv * inv);
  const float* zp = noise + (size_t)n0 * 64 + lane;
  float* nw = noisy + (size_t)n0 * 64 + lane;
  const float THR = 8.f;
  float t2acc = 0.f, sumOm2 = 0.f;
  float m0 = -INFINITY, l0 = 0.f, r0 = 0.f;
  float m1 = -INFINITY, l1 = 0.f, r1a = 0.f;
  n = 0;
  for (; n + 2 <= cnt; n += 2) {
    float lamA = lam[n0 + n], lamB = lam[n0 + n + 1];
    float xA = xp[(size_t)n * 64], xB = xp[(size_t)(n + 1) * 64];
    float zA = zp[(size_t)n * 64], zB = zp[(size_t)(n + 1) * 64];
    float omA = 1.f - lamA, omB = 1.f - lamB;
    float nvA = fmaf(lamA, xA, omA * mean) + zA * (omA * sd);
    float nvB = fmaf(lamB, xB, omB * mean) + zB * (omB * sd);
    nw[(size_t)n * 64] = nvA;
    nw[(size_t)(n + 1) * 64] = nvB;
    float ldA = lamA * (xA - mean) * inv; t2acc = fmaf(ldA, ldA, t2acc);
    float ldB = lamB * (xB - mean) * inv; t2acc = fmaf(ldB, ldB, t2acc);
    sumOm2 = fmaf(omA, omA, sumOm2); sumOm2 = fmaf(omB, omB, sumOm2);
    float e0, e1;
    wave_sum2(nvA * q1v2, nvB * q1v2, lo, e0, e1);
    if (e0 > m0 + THR) { float sc = fexp2(m0 - e0); l0 *= sc; r0 *= sc; m0 = e0; }
    float pA = fexp2(e0 - m0); l0 += pA; r0 = fmaf(pA, nvA, r0);
    if (e1 > m1 + THR) { float sc = fexp2(m1 - e1); l1 *= sc; r1a *= sc; m1 = e1; }
    float pB = fexp2(e1 - m1); l1 += pB; r1a = fmaf(pB, nvB, r1a);
  }
  if (n < cnt) {
    float lamA = lam[n0 + n];
    float xA = xp[(size_t)n * 64];
    float zA = zp[(size_t)n * 64];
    float omA = 1.f - lamA;
    float nvA = fmaf(lamA, xA, omA * mean) + zA * (omA * sd);
    nw[(size_t)n * 64] = nvA;
    float ldA = lamA * (xA - mean) * inv; t2acc = fmaf(ldA, ldA, t2acc);
    sumOm2 = fmaf(omA, omA, sumOm2);
    float e0 = wave_sum(nvA * q1v2);
    if (e0 > m0 + THR) { float sc = fexp2(m0 - e0); l0 *= sc; r0 *= sc; m0 = e0; }
    float pA = fexp2(e0 - m0); l0 += pA; r0 = fmaf(pA, nvA, r0);
  }
  float M = fmaxf(m0, m1);
  float sc0 = fexp2(m0 - M), sc1 = fexp2(m1 - M);
  float L = l0 * sc0 + l1 * sc1;
  float R = r0 * sc0 + r1a * sc1;
  r1[(size_t)wg * 64 + lane] = R / L;
  float t2tot = wave_sum(t2acc);
  if (lane == 0) klp[wg] = fmaf(0.5f * sumOm2, S1, t2tot);
}

// ---------------- K5: Set2Set step-2 LSTM: gates = sh2 + r1 @ R^T, 16 graphs/block ----------------
__global__ __launch_bounds__(256) void k_lstm2(const float* __restrict__ r1, const float* __restrict__ wih,
                                               const float* __restrict__ sh2, const float* __restrict__ c1g,
                                               float* __restrict__ qstar) {
  __shared__ float Rs[2][64][64];
  __shared__ float r1s[16][64];
  __shared__ float sh2s[256], c1s[64];
  int tid = threadIdx.x;
  int d = tid & 63, rg = tid >> 6;
  int g0 = blockIdx.x * 16;
  sh2s[tid] = sh2[tid];
  if (tid < 64) c1s[tid] = c1g[tid];
  {
    int e4 = tid * 4;
    int r = e4 >> 6, k = e4 & 63;
    *(float4*)&r1s[r][k] = *(const float4*)&r1[(size_t)(g0 + r) * 64 + k];
  }
  float acc[4][4] = {};
#pragma unroll
  for (int jp = 0; jp < 2; jp++) {
    __syncthreads();
    {
      int gate = jp * 2 + (tid >= 128 ? 1 : 0);
      int dd2 = tid & 63;
      if ((tid & 127) < 64) {
        int row = gate * 64 + dd2;
        const float* src = &wih[(size_t)row * 128 + 64];
        for (int k = 0; k < 64; k += 4) {
          float4 v = *(const float4*)&src[k];
          Rs[gate - jp * 2][k + 0][dd2] = v.x;
          Rs[gate - jp * 2][k + 1][dd2] = v.y;
          Rs[gate - jp * 2][k + 2][dd2] = v.z;
          Rs[gate - jp * 2][k + 3][dd2] = v.w;
        }
      }
    }
    __syncthreads();
    for (int k = 0; k < 64; k++) {
      float bj0 = Rs[0][k][d];
      float bj1 = Rs[1][k][d];
#pragma unroll
      for (int i = 0; i < 4; i++) {
        float a = r1s[rg * 4 + i][k];
        acc[i][jp * 2 + 0] = fmaf(a, bj0, acc[i][jp * 2 + 0]);
        acc[i][jp * 2 + 1] = fmaf(a, bj1, acc[i][jp * 2 + 1]);
      }
    }
  }
#pragma unroll
  for (int i = 0; i < 4; i++) {
    int row = g0 + rg * 4 + i;
    float ig = acc[i][0] + sh2s[d];
    float fg = acc[i][1] + sh2s[64 + d];
    float gg = acc[i][2] + sh2s[128 + d];
    float og = acc[i][3] + sh2s[192 + d];
    float c2 = sigf(fg) * c1s[d] + sigf(ig) * tanhf(gg);
    float q2 = sigf(og) * tanhf(c2);
    qstar[(size_t)row * 128 + d] = q2;
  }
}

// ---------------- K6: attention step 2, wave-per-graph, 2-stream deferred-max online softmax ----------------
__global__ __launch_bounds__(256) void k_attn2(const float* __restrict__ noisy, const int* __restrict__ off,
                                               float* __restrict__ qstar) {
  int wg = blockIdx.x * 4 + (threadIdx.x >> 6);
  int lane = threadIdx.x & 63;
  bool lo = lane < 32;
  int n0 = off[wg], cnt = off[wg + 1] - n0;
  float q2v2 = qstar[(size_t)wg * 128 + lane] * LOG2E;
  if (cnt == 0) { qstar[(size_t)wg * 128 + 64 + lane] = 0.f; return; }
  const float* np_ = noisy + (size_t)n0 * 64 + lane;
  const float THR = 8.f;
  float m0 = -INFINITY, l0 = 0.f, r0 = 0.f;
  float m1 = -INFINITY, l1 = 0.f, r1a = 0.f;
  int n = 0;
  for (; n + 2 <= cnt; n += 2) {
    float nvA = np_[(size_t)n * 64];
    float nvB = np_[(size_t)(n + 1) * 64];
    float e0, e1;
    wave_sum2(nvA * q2v2, nvB * q2v2, lo, e0, e1);
    if (e0 > m0 + THR) { float sc = fexp2(m0 - e0); l0 *= sc; r0 *= sc; m0 = e0; }
    float pA = fexp2(e0 - m0); l0 += pA; r0 = fmaf(pA, nvA, r0);
    if (e1 > m1 + THR) { float sc = fexp2(m1 - e1); l1 *= sc; r1a *= sc; m1 = e1; }
    float pB = fexp2(e1 - m1); l1 += pB; r1a = fmaf(pB, nvB, r1a);
  }
  if (n < cnt) {
    float nvA = np_[(size_t)n * 64];
    float e0 = wave_sum(nvA * q2v2);
    if (e0 > m0 + THR) { float sc = fexp2(m0 - e0); l0 *= sc; r0 *= sc; m0 = e0; }
    float pA = fexp2(e0 - m0); l0 += pA; r0 = fmaf(pA, nvA, r0);
  }
  float M = fmaxf(m0, m1);
  float sc0 = fexp2(m0 - M), sc1 = fexp2(m1 - M);
  float L = l0 * sc0 + l1 * sc1;
  float R = r0 * sc0 + r1a * sc1;
  qstar[(size_t)wg * 128 + 64 + lane] = R / L;
}

// ---------------- K7/8/9: predictor linear layers (pre-transposed weights) ----------------
template <int KDIM, int ODIM, bool RELU>
__global__ __launch_bounds__(256) void k_linear(const float* __restrict__ A, const float* __restrict__ WT,
                                                const float* __restrict__ bias, float* __restrict__ C) {
  __shared__ float As[64][68];
  __shared__ float Wt[64][68];
  int tid = threadIdx.x, ty = tid >> 4, tx = tid & 15;
  int n0 = blockIdx.x * 64, c0 = blockIdx.y * 64;
  float acc[4][4] = {};
  for (int kt = 0; kt < KDIM; kt += 64) {
    __syncthreads();
    load_A64(A, KDIM, n0, kt, As, tid);
    load_A64(WT, ODIM, kt, c0, Wt, tid);   // WT is [KDIM][ODIM] row-major
    __syncthreads();
    mm64(As, Wt, ty, tx, acc);
  }
#pragma unroll
  for (int i = 0; i < 4; i++) {
    int row = n0 + ty * 4 + i;
    float4 o;
    float v0 = acc[i][0] + bias[c0 + tx * 4 + 0];
    float v1 = acc[i][1] + bias[c0 + tx * 4 + 1];
    float v2 = acc[i][2] + bias[c0 + tx * 4 + 2];
    float v3 = acc[i][3] + bias[c0 + tx * 4 + 3];
    if (RELU) { v0 = fmaxf(v0, 0.f); v1 = fmaxf(v1, 0.f); v2 = fmaxf(v2, 0.f); v3 = fmaxf(v3, 0.f); }
    o.x = v0; o.y = v1; o.z = v2; o.w = v3;
    *(float4*)&C[(size_t)row * ODIM + c0 + tx * 4] = o;
  }
}

// ---------------- K10: final scalars (KL mean + preserve rate from per-block partials) ----------------
__global__ __launch_bounds__(256) void k_final(const float* __restrict__ klp, const int* __restrict__ presPart,
                                               float* __restrict__ out) {
  __shared__ float red[256];
  __shared__ int redi[256];
  float s = 0.0f;
  int pc = 0;
  for (int i = threadIdx.x; i < B_GR; i += 256) s += klp[i];
  for (int i = threadIdx.x; i < 8192; i += 256) pc += presPart[i];
  red[threadIdx.x] = s;
  redi[threadIdx.x] = pc;
  __syncthreads();
  for (int st = 128; st > 0; st >>= 1) {
    if (threadIdx.x < st) {
      red[threadIdx.x] += red[threadIdx.x + st];
      redi[threadIdx.x] += redi[threadIdx.x + st];
    }
    __syncthreads();
  }
  if (threadIdx.x == 0) {
    out[(size_t)B_GR * 64] = red[0] / (float)(B_GR * 64);
    out[(size_t)B_GR * 64 + 1] = (float)redi[0] / (float)N_TOT;
  }
}

// ---------------- launcher ----------------
extern "C" void kernel_launch(void* const* d_in, const int* in_sizes, int n_in,
                              void* d_out, int out_size, void* d_ws, size_t ws_size,
                              hipStream_t stream) {
  const float* features = (const float*)d_in[0];
  const int*   bidx     = (const int*)d_in[1];
  const float* eps_gate = (const float*)d_in[2];
  const float* noise    = (const float*)d_in[3];
  const float* c_w1 = (const float*)d_in[4];
  const float* c_b1 = (const float*)d_in[5];
  const float* bn_g = (const float*)d_in[6];
  const float* bn_b = (const float*)d_in[7];
  const float* c_w2 = (const float*)d_in[8];
  const float* c_b2 = (const float*)d_in[9];
  const float* wih  = (const float*)d_in[10];
  const float* whh  = (const float*)d_in[11];
  const float* bih  = (const float*)d_in[12];
  const float* bhh  = (const float*)d_in[13];
  const float* p_w1 = (const float*)d_in[14];
  const float* p_b1 = (const float*)d_in[15];
  const float* p_w2 = (const float*)d_in[16];
  const float* p_b2 = (const float*)d_in[17];
  const float* p_w3 = (const float*)d_in[18];
  const float* p_b3 = (const float*)d_in[19];
  float* out = (float*)d_out;

  float* wsf   = (float*)d_ws;
  int*   offp  = (int*)wsf;                                 // (B+1) ints
  float* pSum  = wsf + 16448;                               // 8192*64
  float* pSq   = pSum + 524288;                             // 8192*64
  float* aff   = pSq + 524288;                              // 128
  float* q1w   = aff + 128;                                 // 64
  float* c1w   = q1w + 64;                                  // 64
  float* sh2w  = c1w + 64;                                  // 256
  float* lamw  = sh2w + 256;                                // N
  float* cw1T  = lamw + (size_t)N_TOT;                      // 64*64
  float* pw1T  = cw1T + 4096;                               // 128*256
  float* pw2T  = pw1T + 32768;                              // 256*128
  float* pw3T  = pw2T + 32768;                              // 128*64
  float* hw    = pw3T + 8192;                               // N*64  (h; later overwritten by noisy)
  float* noisyw = hw;                                       // shared buffer: h dead after k_gate_h
  float* r1w    = hw + (size_t)N_TOT * 64;                  // B*64
  float* qstarw = r1w + (size_t)B_GR * 64;                  // B*128
  float* z1w    = qstarw + (size_t)B_GR * 128;              // B*256
  float* z2w    = z1w + (size_t)B_GR * 256;                 // B*128
  float* klpw   = z2w + (size_t)B_GR * 128;                 // B
  int*   presPart = (int*)(klpw + B_GR);                    // 8192 ints

  float* lamOut = out + (size_t)B_GR * 64 + 2;

  k_offsets<<<(B_GR + 1 + 255) / 256, 256, 0, stream>>>(bidx, offp);
  k_prep<<<64, 256, 0, stream>>>(c_w1, p_w1, p_w2, p_w3, cw1T, pw1T, pw2T, pw3T);
  k_bn_stats<<<N_TOT / 64, 256, 0, stream>>>(features, cw1T, c_b1, hw, pSum, pSq);
  k_bn_final<<<64, 256, 0, stream>>>(pSum, pSq, bn_g, bn_b, aff);
  k_lstm1<<<1, 256, 0, stream>>>(bih, bhh, wih, whh, q1w, c1w, sh2w);
  k_gate_h<<<N_TOT / 64, 256, 0, stream>>>(hw, aff, c_w2, c_b2, eps_gate, lamw, lamOut, presPart);
  k_graph<<<B_GR / 4, 256, 0, stream>>>(features, noise, lamw, offp, q1w, noisyw, r1w, klpw);
  k_lstm2<<<B_GR / 16, 256, 0, stream>>>(r1w, wih, sh2w, c1w, qstarw);
  k_attn2<<<B_GR / 4, 256, 0, stream>>>(noisyw, offp, qstarw);
  k_linear<128, 256, true><<<dim3(B_GR / 64, 4), 256, 0, stream>>>(qstarw, pw1T, p_b1, z1w);
  k_linear<256, 128, true><<<dim3(B_GR / 64, 2), 256, 0, stream>>>(z1w, pw2T, p_b2, z2w);
  k_linear<128, 64, false><<<dim3(B_GR / 64, 1), 256, 0, stream>>>(z2w, pw3T, p_b3, out);
  k_final<<<1, 256, 0, stream>>>(klpw, presPart, out);
}

// Round 9
// 391.211 us; speedup vs baseline: 1.9166x; 1.0115x over previous
//
#include <hip/hip_runtime.h>
#include <math.h>

#define N_TOT 524288
#define B_GR  16384

#define LOG2E 1.44269504088896f
#define LN2   0.69314718055995f

// ---------------- small device helpers ----------------
__device__ __forceinline__ float fexp2(float x) { return __builtin_amdgcn_exp2f(x); }
__device__ __forceinline__ float flog2(float x) { return __builtin_amdgcn_logf(x); }
__device__ __forceinline__ float frcp(float x)  { return __builtin_amdgcn_rcpf(x); }
__device__ __forceinline__ float sigf(float x)  { return frcp(1.0f + fexp2(-x * LOG2E)); }

__device__ __forceinline__ float wave_sum(float v) {
#pragma unroll
  for (int o = 32; o > 0; o >>= 1) v += __shfl_xor(v, o);
  return v;
}
// Reduce TWO values across 64 lanes with 8 shuffles (vs 12).
__device__ __forceinline__ void wave_sum2(float p0, float p1, bool lo, float& e0, float& e1) {
  float a = p0 + __shfl_xor(p0, 32);
  float b = p1 + __shfl_xor(p1, 32);
  float c = lo ? a : b;
#pragma unroll
  for (int o = 16; o > 0; o >>= 1) c += __shfl_xor(c, o);
  float d = __shfl_xor(c, 32);
  e0 = lo ? c : d;
  e1 = lo ? d : c;
}

// ---------------- 64x64 f32 register-tiled GEMM pieces ----------------
__device__ __forceinline__ void load_A64(const float* __restrict__ A, size_t lda, int n0, int k0,
                                         float (*As)[68], int tid) {
#pragma unroll
  for (int s = 0; s < 4; s++) {
    int e4 = tid * 4 + s * 1024;
    int r = e4 >> 6, k = e4 & 63;
    *(float4*)&As[r][k] = *(const float4*)&A[(size_t)(n0 + r) * lda + k0 + k];
  }
}
__device__ __forceinline__ void mm64(const float (*As)[68], const float (*Wt)[68],
                                     int ty, int tx, float acc[4][4]) {
#pragma unroll
  for (int k4 = 0; k4 < 64; k4 += 4) {
    float4 b0 = *(const float4*)&Wt[k4 + 0][tx * 4];
    float4 b1 = *(const float4*)&Wt[k4 + 1][tx * 4];
    float4 b2 = *(const float4*)&Wt[k4 + 2][tx * 4];
    float4 b3 = *(const float4*)&Wt[k4 + 3][tx * 4];
#pragma unroll
    for (int i = 0; i < 4; i++) {
      float4 a = *(const float4*)&As[ty * 4 + i][k4];
      acc[i][0] = fmaf(a.w, b3.x, fmaf(a.z, b2.x, fmaf(a.y, b1.x, fmaf(a.x, b0.x, acc[i][0]))));
      acc[i][1] = fmaf(a.w, b3.y, fmaf(a.z, b2.y, fmaf(a.y, b1.y, fmaf(a.x, b0.y, acc[i][1]))));
      acc[i][2] = fmaf(a.w, b3.z, fmaf(a.z, b2.z, fmaf(a.y, b1.z, fmaf(a.x, b0.z, acc[i][2]))));
      acc[i][3] = fmaf(a.w, b3.w, fmaf(a.z, b2.w, fmaf(a.y, b1.w, fmaf(a.x, b0.w, acc[i][3]))));
    }
  }
}

// ---------------- K0a: graph offsets via binary search (batch_index is sorted) ----------------
__global__ void k_offsets(const int* __restrict__ idx, int* __restrict__ off) {
  int b = blockIdx.x * blockDim.x + threadIdx.x;
  if (b > B_GR) return;
  if (b == B_GR) { off[B_GR] = N_TOT; return; }
  int lo = 0, hi = N_TOT;
  while (lo < hi) { int mid = (lo + hi) >> 1; if (idx[mid] < b) lo = mid + 1; else hi = mid; }
  off[b] = lo;
}

// ---------------- K0b: pre-transpose weights; build RTg[k][d][j] for fused LSTM2 ----------------
__global__ void k_prep(const float* __restrict__ w1, const float* __restrict__ pw1,
                       const float* __restrict__ pw2, const float* __restrict__ pw3,
                       const float* __restrict__ wih,
                       float* __restrict__ w1T, float* __restrict__ pw1T,
                       float* __restrict__ pw2T, float* __restrict__ pw3T,
                       float* __restrict__ rtg) {
  int t = blockIdx.x * 256 + threadIdx.x;          // 64 blocks * 256 = 16384 threads
  for (int i = t; i < 64 * 64; i += 16384)  { int r = i >> 6, c = i & 63;  w1T[c * 64 + r]   = w1[i]; }
  for (int i = t; i < 256 * 128; i += 16384){ int r = i >> 7, c = i & 127; pw1T[c * 256 + r] = pw1[i]; }
  for (int i = t; i < 128 * 256; i += 16384){ int r = i >> 8, c = i & 255; pw2T[c * 128 + r] = pw2[i]; }
  for (int i = t; i < 64 * 128; i += 16384) { int r = i >> 7, c = i & 127; pw3T[c * 64 + r]  = pw3[i]; }
  // RTg[((k*64)+d)*4 + j] = Wih[j*64+d][64+k]  (j = gate index i,f,g,o)
  for (int i = t; i < 64 * 64 * 4; i += 16384) {
    int k = i >> 8, rem = i & 255, d = rem >> 2, j = rem & 3;
    rtg[i] = wih[(size_t)(j * 64 + d) * 128 + 64 + k];
  }
}

// ---------------- K1: h = X@W1^T + b1 -> STORE h (GEMM paid ONCE); stats partials ----------------
__global__ __launch_bounds__(256) void k_bn_stats(const float* __restrict__ X, const float* __restrict__ W1T,
                                                  const float* __restrict__ b1, float* __restrict__ h,
                                                  float* __restrict__ pSum, float* __restrict__ pSq) {
  __shared__ float As[64][68];
  __shared__ float Wt[64][68];
  int tid = threadIdx.x, ty = tid >> 4, tx = tid & 15;
  int n0 = blockIdx.x * 64;
  float acc[4][4] = {};
  load_A64(X, 64, n0, 0, As, tid);
  load_A64(W1T, 64, 0, 0, Wt, tid);
  __syncthreads();
  mm64(As, Wt, ty, tx, acc);
  float4 bv = *(const float4*)&b1[tx * 4];
  float cs[4] = {0, 0, 0, 0}, cq[4] = {0, 0, 0, 0};
#pragma unroll
  for (int i = 0; i < 4; i++) {
    float4 o;
    o.x = acc[i][0] + bv.x; o.y = acc[i][1] + bv.y;
    o.z = acc[i][2] + bv.z; o.w = acc[i][3] + bv.w;
    *(float4*)&h[(size_t)(n0 + ty * 4 + i) * 64 + tx * 4] = o;
    cs[0] += o.x; cq[0] = fmaf(o.x, o.x, cq[0]);
    cs[1] += o.y; cq[1] = fmaf(o.y, o.y, cq[1]);
    cs[2] += o.z; cq[2] = fmaf(o.z, o.z, cq[2]);
    cs[3] += o.w; cq[3] = fmaf(o.w, o.w, cq[3]);
  }
  __syncthreads();
  float* red = &As[0][0];
#pragma unroll
  for (int j = 0; j < 4; j++) {
    red[ty * 64 + tx * 4 + j] = cs[j];
    red[1024 + ty * 64 + tx * 4 + j] = cq[j];
  }
  __syncthreads();
  if (tid < 64) {
    float s = 0, q = 0;
#pragma unroll
    for (int t = 0; t < 16; t++) { s += red[t * 64 + tid]; q += red[1024 + t * 64 + tid]; }
    pSum[(size_t)blockIdx.x * 64 + tid] = s;
    pSq[(size_t)blockIdx.x * 64 + tid] = q;
  }
}

// ---------------- K2a: finalize BN -> affine aff[0:64]=A, aff[64:128]=C ----------------
// b1 is already inside h: hhat = (h - mu)*A + bn_b  ->  C = bn_b - mu*A.
__global__ __launch_bounds__(256) void k_bn_final(const float* __restrict__ pSum, const float* __restrict__ pSq,
                                                  const float* __restrict__ bn_g, const float* __restrict__ bn_b,
                                                  float* __restrict__ aff) {
  int c = blockIdx.x;
  float s = 0, q = 0;
  for (int i = threadIdx.x; i < 8192; i += 256) {
    s += pSum[(size_t)i * 64 + c];
    q += pSq[(size_t)i * 64 + c];
  }
  __shared__ float rs[256], rq[256];
  rs[threadIdx.x] = s; rq[threadIdx.x] = q;
  __syncthreads();
  for (int st = 128; st > 0; st >>= 1) {
    if (threadIdx.x < st) { rs[threadIdx.x] += rs[threadIdx.x + st]; rq[threadIdx.x] += rq[threadIdx.x + st]; }
    __syncthreads();
  }
  if (threadIdx.x == 0) {
    float mu = rs[0] / (float)N_TOT;
    float var = rq[0] / (float)N_TOT - mu * mu;
    var = fmaxf(var, 0.0f);
    float A = bn_g[c] * rsqrtf(var + 1e-5f);
    aff[c] = A;
    aff[64 + c] = bn_b[c] - mu * A;
  }
}

// ---------------- K2b: LSTM step1 from biases only; shared part of step-2 gates ----------------
__global__ __launch_bounds__(256) void k_lstm1(const float* __restrict__ bih, const float* __restrict__ bhh,
                                               const float* __restrict__ wih, const float* __restrict__ whh,
                                               float* __restrict__ q1, float* __restrict__ c1, float* __restrict__ sh2) {
  __shared__ float g1[256];
  __shared__ float q1s[64];
  int tid = threadIdx.x;
  g1[tid] = bih[tid] + bhh[tid];
  __syncthreads();
  if (tid < 64) {
    float ig = sigf(g1[tid]);
    float gg = tanhf(g1[128 + tid]);
    float cc = ig * gg;
    float og = sigf(g1[192 + tid]);
    float qv = og * tanhf(cc);
    q1s[tid] = qv; q1[tid] = qv; c1[tid] = cc;
  }
  __syncthreads();
  float acc = g1[tid];
  for (int k = 0; k < 64; k++)
    acc = fmaf(wih[(size_t)tid * 128 + k] + whh[(size_t)tid * 64 + k], q1s[k], acc);
  sh2[tid] = acc;
}

// ---------------- K3: streaming gate (no global atomics) ----------------
__global__ __launch_bounds__(256) void k_gate_h(const float* __restrict__ h, const float* __restrict__ aff,
                                                const float* __restrict__ w2, const float* __restrict__ cb2,
                                                const float* __restrict__ eps_gate,
                                                float* __restrict__ lamWS, float* __restrict__ lamOut,
                                                int* __restrict__ presPart) {
  __shared__ float Hs[64][65];   // pad 65: max 2-way aliasing (free)
  __shared__ float A2s[64], C2s[64], w2s[64];
  __shared__ int pcnt[4];
  int tid = threadIdx.x;
  if (tid < 64) { A2s[tid] = aff[tid]; C2s[tid] = aff[64 + tid]; w2s[tid] = w2[tid]; }
  int n0 = blockIdx.x * 64;
#pragma unroll
  for (int s = 0; s < 4; s++) {
    int e4 = tid * 4 + s * 1024;
    int r = e4 >> 6, c = e4 & 63;
    float4 v = *(const float4*)&h[(size_t)(n0 + r) * 64 + c];
    Hs[r][c] = v.x; Hs[r][c + 1] = v.y; Hs[r][c + 2] = v.z; Hs[r][c + 3] = v.w;
  }
  __syncthreads();
  int r = tid >> 2, q = tid & 3;
  float p = 0.f;
#pragma unroll
  for (int j = 0; j < 16; j++) {
    int d = q * 16 + j;
    p = fmaf(fmaxf(fmaf(Hs[r][d], A2s[d], C2s[d]), 0.f), w2s[d], p);
  }
  p += __shfl_xor(p, 1);
  p += __shfl_xor(p, 2);
  p += cb2[0];
  unsigned long long m = __ballot(q == 0 && p > 0.0f);
  if ((tid & 63) == 0) pcnt[tid >> 6] = (int)__popcll(m);
  if (q == 0) {
    int row = n0 + r;
    float eg = eps_gate[row];
    float eps = 0.9999f - 0.9998f * eg;
    float gi = (flog2(eps) - flog2(1.0f - eps)) * LN2;
    float lam = sigf(gi + p);
    lamWS[row] = lam;
    lamOut[row] = lam;
  }
  __syncthreads();
  if (tid == 0) presPart[blockIdx.x] = pcnt[0] + pcnt[1] + pcnt[2] + pcnt[3];
}

// ---------------- K4: FUSED wave-per-graph: stats, noisy, KL, attn1, LSTM2, attn2 ----------------
// Per-graph tail is wave-local: r1 -> gates = sh2 + r1@R^T (RTg matvec, L2-resident)
// -> q2 -> attention-2 over the noisy rows this wave JUST wrote (L2-hot re-read).
__global__ __launch_bounds__(256) void k_graph_full(const float* __restrict__ X, const float* __restrict__ noise,
                                                    const float* __restrict__ lam, const int* __restrict__ off,
                                                    const float* __restrict__ q1g, const float* __restrict__ c1g,
                                                    const float* __restrict__ sh2g, const float* __restrict__ rtg,
                                                    float* __restrict__ noisy, float* __restrict__ qstar,
                                                    float* __restrict__ klp) {
  int wg = blockIdx.x * 4 + (threadIdx.x >> 6);
  int lane = threadIdx.x & 63;
  bool lo = lane < 32;
  int n0 = off[wg], cnt = off[wg + 1] - n0;
  const float THR = 8.f;
  const float* xp = X + (size_t)n0 * 64 + lane;
  const float* zp = noise + (size_t)n0 * 64 + lane;
  float* nw = noisy + (size_t)n0 * 64 + lane;
  float r1v = 0.f;

  if (cnt > 0) {
    // ---- pass 1: per-dim mean / unbiased std (lane-local, 2 streams) ----
    float s0 = 0.f, q0 = 0.f, s1 = 0.f, q1_ = 0.f;
    int n = 0;
    for (; n + 2 <= cnt; n += 2) {
      float a = xp[(size_t)n * 64], b = xp[(size_t)(n + 1) * 64];
      s0 += a; q0 = fmaf(a, a, q0);
      s1 += b; q1_ = fmaf(b, b, q1_);
    }
    if (n < cnt) { float a = xp[(size_t)n * 64]; s0 += a; q0 = fmaf(a, a, q0); }
    float c = (float)cnt;
    float mean = (s0 + s1) / c;
    float var = fmaxf(((q0 + q1_) - c * mean * mean) / fmaxf(c - 1.f, 1.f), 0.f);
    float sd = sqrtf(var);
    float inv = frcp(sd + 1e-7f);
    float S1 = wave_sum(sd * sd * inv * inv);
    // ---- pass 2: noisy + KL + online-softmax attention step 1 ----
    float q1v2 = q1g[lane] * LOG2E;
    float t2acc = 0.f, sumOm2 = 0.f;
    float m0 = -INFINITY, l0 = 0.f, r0 = 0.f;
    float m1 = -INFINITY, l1 = 0.f, r1a = 0.f;
    n = 0;
    for (; n + 2 <= cnt; n += 2) {
      float lamA = lam[n0 + n], lamB = lam[n0 + n + 1];
      float xA = xp[(size_t)n * 64], xB = xp[(size_t)(n + 1) * 64];
      float zA = zp[(size_t)n * 64], zB = zp[(size_t)(n + 1) * 64];
      float omA = 1.f - lamA, omB = 1.f - lamB;
      float nvA = fmaf(lamA, xA, omA * mean) + zA * (omA * sd);
      float nvB = fmaf(lamB, xB, omB * mean) + zB * (omB * sd);
      nw[(size_t)n * 64] = nvA;
      nw[(size_t)(n + 1) * 64] = nvB;
      float ldA = lamA * (xA - mean) * inv; t2acc = fmaf(ldA, ldA, t2acc);
      float ldB = lamB * (xB - mean) * inv; t2acc = fmaf(ldB, ldB, t2acc);
      sumOm2 = fmaf(omA, omA, sumOm2); sumOm2 = fmaf(omB, omB, sumOm2);
      float e0, e1;
      wave_sum2(nvA * q1v2, nvB * q1v2, lo, e0, e1);
      if (e0 > m0 + THR) { float sc = fexp2(m0 - e0); l0 *= sc; r0 *= sc; m0 = e0; }
      float pA = fexp2(e0 - m0); l0 += pA; r0 = fmaf(pA, nvA, r0);
      if (e1 > m1 + THR) { float sc = fexp2(m1 - e1); l1 *= sc; r1a *= sc; m1 = e1; }
      float pB = fexp2(e1 - m1); l1 += pB; r1a = fmaf(pB, nvB, r1a);
    }
    if (n < cnt) {
      float lamA = lam[n0 + n];
      float xA = xp[(size_t)n * 64];
      float zA = zp[(size_t)n * 64];
      float omA = 1.f - lamA;
      float nvA = fmaf(lamA, xA, omA * mean) + zA * (omA * sd);
      nw[(size_t)n * 64] = nvA;
      float ldA = lamA * (xA - mean) * inv; t2acc = fmaf(ldA, ldA, t2acc);
      sumOm2 = fmaf(omA, omA, sumOm2);
      float e0 = wave_sum(nvA * q1v2);
      if (e0 > m0 + THR) { float sc = fexp2(m0 - e0); l0 *= sc; r0 *= sc; m0 = e0; }
      float pA = fexp2(e0 - m0); l0 += pA; r0 = fmaf(pA, nvA, r0);
    }
    float M = fmaxf(m0, m1);
    float sc0 = fexp2(m0 - M), sc1 = fexp2(m1 - M);
    float L = l0 * sc0 + l1 * sc1;
    float R = r0 * sc0 + r1a * sc1;
    r1v = R / L;
    float t2tot = wave_sum(t2acc);
    if (lane == 0) klp[wg] = fmaf(0.5f * sumOm2, S1, t2tot);
  } else {
    if (lane == 0) klp[wg] = 0.0f;
  }

  // ---- fused LSTM step 2: gates = sh2 + r1 @ R^T via RTg[k][d][4] (L2-resident) ----
  float a0 = 0.f, a1 = 0.f, a2 = 0.f, a3 = 0.f;
  const float4* rt = (const float4*)rtg;
#pragma unroll 4
  for (int k = 0; k < 64; k++) {
    float rk = __shfl(r1v, k);
    float4 w = rt[k * 64 + lane];
    a0 = fmaf(w.x, rk, a0); a1 = fmaf(w.y, rk, a1);
    a2 = fmaf(w.z, rk, a2); a3 = fmaf(w.w, rk, a3);
  }
  float ig = a0 + sh2g[lane];
  float fg = a1 + sh2g[64 + lane];
  float gg = a2 + sh2g[128 + lane];
  float og = a3 + sh2g[192 + lane];
  float c2 = sigf(fg) * c1g[lane] + sigf(ig) * tanhf(gg);
  float q2 = sigf(og) * tanhf(c2);
  qstar[(size_t)wg * 128 + lane] = q2;

  // ---- fused attention step 2 over L2-hot noisy ----
  float r2 = 0.f;
  if (cnt > 0) {
    float q2v2 = q2 * LOG2E;
    float m0 = -INFINITY, l0 = 0.f, r0 = 0.f;
    float m1 = -INFINITY, l1 = 0.f, r1a = 0.f;
    int n = 0;
    for (; n + 2 <= cnt; n += 2) {
      float nvA = nw[(size_t)n * 64];
      float nvB = nw[(size_t)(n + 1) * 64];
      float e0, e1;
      wave_sum2(nvA * q2v2, nvB * q2v2, lo, e0, e1);
      if (e0 > m0 + THR) { float sc = fexp2(m0 - e0); l0 *= sc; r0 *= sc; m0 = e0; }
      float pA = fexp2(e0 - m0); l0 += pA; r0 = fmaf(pA, nvA, r0);
      if (e1 > m1 + THR) { float sc = fexp2(m1 - e1); l1 *= sc; r1a *= sc; m1 = e1; }
      float pB = fexp2(e1 - m1); l1 += pB; r1a = fmaf(pB, nvB, r1a);
    }
    if (n < cnt) {
      float nvA = nw[(size_t)n * 64];
      float e0 = wave_sum(nvA * q2v2);
      if (e0 > m0 + THR) { float sc = fexp2(m0 - e0); l0 *= sc; r0 *= sc; m0 = e0; }
      float pA = fexp2(e0 - m0); l0 += pA; r0 = fmaf(pA, nvA, r0);
    }
    float M = fmaxf(m0, m1);
    float sc0 = fexp2(m0 - M), sc1 = fexp2(m1 - M);
    float L = l0 * sc0 + l1 * sc1;
    float R = r0 * sc0 + r1a * sc1;
    r2 = R / L;
  }
  qstar[(size_t)wg * 128 + 64 + lane] = r2;
}

// ---------------- K7/8/9: predictor linear layers (pre-transposed weights) ----------------
template <int KDIM, int ODIM, bool RELU>
__global__ __launch_bounds__(256) void k_linear(const float* __restrict__ A, const float* __restrict__ WT,
                                                const float* __restrict__ bias, float* __restrict__ C) {
  __shared__ float As[64][68];
  __shared__ float Wt[64][68];
  int tid = threadIdx.x, ty = tid >> 4, tx = tid & 15;
  int n0 = blockIdx.x * 64, c0 = blockIdx.y * 64;
  float acc[4][4] = {};
  for (int kt = 0; kt < KDIM; kt += 64) {
    __syncthreads();
    load_A64(A, KDIM, n0, kt, As, tid);
    load_A64(WT, ODIM, kt, c0, Wt, tid);   // WT is [KDIM][ODIM] row-major
    __syncthreads();
    mm64(As, Wt, ty, tx, acc);
  }
#pragma unroll
  for (int i = 0; i < 4; i++) {
    int row = n0 + ty * 4 + i;
    float4 o;
    float v0 = acc[i][0] + bias[c0 + tx * 4 + 0];
    float v1 = acc[i][1] + bias[c0 + tx * 4 + 1];
    float v2 = acc[i][2] + bias[c0 + tx * 4 + 2];
    float v3 = acc[i][3] + bias[c0 + tx * 4 + 3];
    if (RELU) { v0 = fmaxf(v0, 0.f); v1 = fmaxf(v1, 0.f); v2 = fmaxf(v2, 0.f); v3 = fmaxf(v3, 0.f); }
    o.x = v0; o.y = v1; o.z = v2; o.w = v3;
    *(float4*)&C[(size_t)row * ODIM + c0 + tx * 4] = o;
  }
}

// ---------------- K10: final scalars ----------------
__global__ __launch_bounds__(256) void k_final(const float* __restrict__ klp, const int* __restrict__ presPart,
                                               float* __restrict__ out) {
  __shared__ float red[256];
  __shared__ int redi[256];
  float s = 0.0f;
  int pc = 0;
  for (int i = threadIdx.x; i < B_GR; i += 256) s += klp[i];
  for (int i = threadIdx.x; i < 8192; i += 256) pc += presPart[i];
  red[threadIdx.x] = s;
  redi[threadIdx.x] = pc;
  __syncthreads();
  for (int st = 128; st > 0; st >>= 1) {
    if (threadIdx.x < st) {
      red[threadIdx.x] += red[threadIdx.x + st];
      redi[threadIdx.x] += redi[threadIdx.x + st];
    }
    __syncthreads();
  }
  if (threadIdx.x == 0) {
    out[(size_t)B_GR * 64] = red[0] / (float)(B_GR * 64);
    out[(size_t)B_GR * 64 + 1] = (float)redi[0] / (float)N_TOT;
  }
}

// ---------------- launcher ----------------
extern "C" void kernel_launch(void* const* d_in, const int* in_sizes, int n_in,
                              void* d_out, int out_size, void* d_ws, size_t ws_size,
                              hipStream_t stream) {
  const float* features = (const float*)d_in[0];
  const int*   bidx     = (const int*)d_in[1];
  const float* eps_gate = (const float*)d_in[2];
  const float* noise    = (const float*)d_in[3];
  const float* c_w1 = (const float*)d_in[4];
  const float* c_b1 = (const float*)d_in[5];
  const float* bn_g = (const float*)d_in[6];
  const float* bn_b = (const float*)d_in[7];
  const float* c_w2 = (const float*)d_in[8];
  const float* c_b2 = (const float*)d_in[9];
  const float* wih  = (const float*)d_in[10];
  const float* whh  = (const float*)d_in[11];
  const float* bih  = (const float*)d_in[12];
  const float* bhh  = (const float*)d_in[13];
  const float* p_w1 = (const float*)d_in[14];
  const float* p_b1 = (const float*)d_in[15];
  const float* p_w2 = (const float*)d_in[16];
  const float* p_b2 = (const float*)d_in[17];
  const float* p_w3 = (const float*)d_in[18];
  const float* p_b3 = (const float*)d_in[19];
  float* out = (float*)d_out;

  float* wsf   = (float*)d_ws;
  int*   offp  = (int*)wsf;                                 // (B+1) ints
  float* pSum  = wsf + 16448;                               // 8192*64
  float* pSq   = pSum + 524288;                             // 8192*64
  float* aff   = pSq + 524288;                              // 128
  float* q1w   = aff + 128;                                 // 64
  float* c1w   = q1w + 64;                                  // 64
  float* sh2w  = c1w + 64;                                  // 256
  float* lamw  = sh2w + 256;                                // N
  float* cw1T  = lamw + (size_t)N_TOT;                      // 64*64
  float* pw1T  = cw1T + 4096;                               // 128*256
  float* pw2T  = pw1T + 32768;                              // 256*128
  float* pw3T  = pw2T + 32768;                              // 128*64
  float* rtgw  = pw3T + 8192;                               // 64*256 (RTg)
  float* hw    = rtgw + 16384;                              // N*64  (h; later overwritten by noisy)
  float* noisyw = hw;                                       // shared buffer: h dead after k_gate_h
  float* qstarw = hw + (size_t)N_TOT * 64;                  // B*128
  float* z1w    = qstarw + (size_t)B_GR * 128;              // B*256
  float* z2w    = z1w + (size_t)B_GR * 256;                 // B*128
  float* klpw   = z2w + (size_t)B_GR * 128;                 // B
  int*   presPart = (int*)(klpw + B_GR);                    // 8192 ints

  float* lamOut = out + (size_t)B_GR * 64 + 2;

  k_offsets<<<(B_GR + 1 + 255) / 256, 256, 0, stream>>>(bidx, offp);
  k_prep<<<64, 256, 0, stream>>>(c_w1, p_w1, p_w2, p_w3, wih, cw1T, pw1T, pw2T, pw3T, rtgw);
  k_bn_stats<<<N_TOT / 64, 256, 0, stream>>>(features, cw1T, c_b1, hw, pSum, pSq);
  k_bn_final<<<64, 256, 0, stream>>>(pSum, pSq, bn_g, bn_b, aff);
  k_lstm1<<<1, 256, 0, stream>>>(bih, bhh, wih, whh, q1w, c1w, sh2w);
  k_gate_h<<<N_TOT / 64, 256, 0, stream>>>(hw, aff, c_w2, c_b2, eps_gate, lamw, lamOut, presPart);
  k_graph_full<<<B_GR / 4, 256, 0, stream>>>(features, noise, lamw, offp, q1w, c1w, sh2w, rtgw,
                                             noisyw, qstarw, klpw);
  k_linear<128, 256, true><<<dim3(B_GR / 64, 4), 256, 0, stream>>>(qstarw, pw1T, p_b1, z1w);
  k_linear<256, 128, true><<<dim3(B_GR / 64, 2), 256, 0, stream>>>(z1w, pw2T, p_b2, z2w);
  k_linear<128, 64, false><<<dim3(B_GR / 64, 1), 256, 0, stream>>>(z2w, pw3T, p_b3, out);
  k_final<<<1, 256, 0, stream>>>(klpw, presPart, out);
}

// Round 10
// 355.028 us; speedup vs baseline: 2.1119x; 1.1019x over previous
//
#include <hip/hip_runtime.h>
#include <math.h>

#define N_TOT 524288
#define B_GR  16384

#define LOG2E 1.44269504088896f
#define LN2   0.69314718055995f

// ---------------- small device helpers ----------------
__device__ __forceinline__ float fexp2(float x) { return __builtin_amdgcn_exp2f(x); }
__device__ __forceinline__ float flog2(float x) { return __builtin_amdgcn_logf(x); }
__device__ __forceinline__ float frcp(float x)  { return __builtin_amdgcn_rcpf(x); }
__device__ __forceinline__ float sigf(float x)  { return frcp(1.0f + fexp2(-x * LOG2E)); }

// bf16 pack/unpack (RNE)
__device__ __forceinline__ unsigned short f2bf(float x) {
  unsigned int u = __float_as_uint(x);
  unsigned int r = (u + 0x7FFFu + ((u >> 16) & 1u)) >> 16;
  return (unsigned short)r;
}
__device__ __forceinline__ float bf2f(unsigned short s) {
  return __uint_as_float((unsigned int)s << 16);
}

__device__ __forceinline__ float wave_sum(float v) {
#pragma unroll
  for (int o = 32; o > 0; o >>= 1) v += __shfl_xor(v, o);
  return v;
}
// Reduce TWO values across 64 lanes with 8 shuffles (vs 12).
__device__ __forceinline__ void wave_sum2(float p0, float p1, bool lo, float& e0, float& e1) {
  float a = p0 + __shfl_xor(p0, 32);
  float b = p1 + __shfl_xor(p1, 32);
  float c = lo ? a : b;
#pragma unroll
  for (int o = 16; o > 0; o >>= 1) c += __shfl_xor(c, o);
  float d = __shfl_xor(c, 32);
  e0 = lo ? c : d;
  e1 = lo ? d : c;
}

// ---------------- 64x64 f32 register-tiled GEMM pieces ----------------
__device__ __forceinline__ void load_A64(const float* __restrict__ A, size_t lda, int n0, int k0,
                                         float (*As)[68], int tid) {
#pragma unroll
  for (int s = 0; s < 4; s++) {
    int e4 = tid * 4 + s * 1024;
    int r = e4 >> 6, k = e4 & 63;
    *(float4*)&As[r][k] = *(const float4*)&A[(size_t)(n0 + r) * lda + k0 + k];
  }
}
__device__ __forceinline__ void mm64(const float (*As)[68], const float (*Wt)[68],
                                     int ty, int tx, float acc[4][4]) {
#pragma unroll
  for (int k4 = 0; k4 < 64; k4 += 4) {
    float4 b0 = *(const float4*)&Wt[k4 + 0][tx * 4];
    float4 b1 = *(const float4*)&Wt[k4 + 1][tx * 4];
    float4 b2 = *(const float4*)&Wt[k4 + 2][tx * 4];
    float4 b3 = *(const float4*)&Wt[k4 + 3][tx * 4];
#pragma unroll
    for (int i = 0; i < 4; i++) {
      float4 a = *(const float4*)&As[ty * 4 + i][k4];
      acc[i][0] = fmaf(a.w, b3.x, fmaf(a.z, b2.x, fmaf(a.y, b1.x, fmaf(a.x, b0.x, acc[i][0]))));
      acc[i][1] = fmaf(a.w, b3.y, fmaf(a.z, b2.y, fmaf(a.y, b1.y, fmaf(a.x, b0.y, acc[i][1]))));
      acc[i][2] = fmaf(a.w, b3.z, fmaf(a.z, b2.z, fmaf(a.y, b1.z, fmaf(a.x, b0.z, acc[i][2]))));
      acc[i][3] = fmaf(a.w, b3.w, fmaf(a.z, b2.w, fmaf(a.y, b1.w, fmaf(a.x, b0.w, acc[i][3]))));
    }
  }
}

// ---------------- K0a: graph offsets via binary search (batch_index is sorted) ----------------
__global__ void k_offsets(const int* __restrict__ idx, int* __restrict__ off) {
  int b = blockIdx.x * blockDim.x + threadIdx.x;
  if (b > B_GR) return;
  if (b == B_GR) { off[B_GR] = N_TOT; return; }
  int lo = 0, hi = N_TOT;
  while (lo < hi) { int mid = (lo + hi) >> 1; if (idx[mid] < b) lo = mid + 1; else hi = mid; }
  off[b] = lo;
}

// ---------------- K0b: pre-transpose weights; build RTg[k][d][j] for fused LSTM2 ----------------
__global__ void k_prep(const float* __restrict__ w1, const float* __restrict__ pw1,
                       const float* __restrict__ pw2, const float* __restrict__ pw3,
                       const float* __restrict__ wih,
                       float* __restrict__ w1T, float* __restrict__ pw1T,
                       float* __restrict__ pw2T, float* __restrict__ pw3T,
                       float* __restrict__ rtg) {
  int t = blockIdx.x * 256 + threadIdx.x;          // 64 blocks * 256 = 16384 threads
  for (int i = t; i < 64 * 64; i += 16384)  { int r = i >> 6, c = i & 63;  w1T[c * 64 + r]   = w1[i]; }
  for (int i = t; i < 256 * 128; i += 16384){ int r = i >> 7, c = i & 127; pw1T[c * 256 + r] = pw1[i]; }
  for (int i = t; i < 128 * 256; i += 16384){ int r = i >> 8, c = i & 255; pw2T[c * 128 + r] = pw2[i]; }
  for (int i = t; i < 64 * 128; i += 16384) { int r = i >> 7, c = i & 127; pw3T[c * 64 + r]  = pw3[i]; }
  // RTg[((k*64)+d)*4 + j] = Wih[j*64+d][64+k]  (j = gate index i,f,g,o)
  for (int i = t; i < 64 * 64 * 4; i += 16384) {
    int k = i >> 8, rem = i & 255, d = rem >> 2, j = rem & 3;
    rtg[i] = wih[(size_t)(j * 64 + d) * 128 + 64 + k];
  }
}

// ---------------- K1: h = X@W1^T + b1 -> STORE h as bf16; stats partials (f32-exact) ----------------
__global__ __launch_bounds__(256) void k_bn_stats(const float* __restrict__ X, const float* __restrict__ W1T,
                                                  const float* __restrict__ b1, unsigned short* __restrict__ h,
                                                  float* __restrict__ pSum, float* __restrict__ pSq) {
  __shared__ float As[64][68];
  __shared__ float Wt[64][68];
  int tid = threadIdx.x, ty = tid >> 4, tx = tid & 15;
  int n0 = blockIdx.x * 64;
  float acc[4][4] = {};
  load_A64(X, 64, n0, 0, As, tid);
  load_A64(W1T, 64, 0, 0, Wt, tid);
  __syncthreads();
  mm64(As, Wt, ty, tx, acc);
  float4 bv = *(const float4*)&b1[tx * 4];
  float cs[4] = {0, 0, 0, 0}, cq[4] = {0, 0, 0, 0};
#pragma unroll
  for (int i = 0; i < 4; i++) {
    float h0 = acc[i][0] + bv.x, h1 = acc[i][1] + bv.y;
    float h2 = acc[i][2] + bv.z, h3 = acc[i][3] + bv.w;
    ushort4 hb;
    hb.x = f2bf(h0); hb.y = f2bf(h1); hb.z = f2bf(h2); hb.w = f2bf(h3);
    *(ushort4*)&h[(size_t)(n0 + ty * 4 + i) * 64 + tx * 4] = hb;
    cs[0] += h0; cq[0] = fmaf(h0, h0, cq[0]);
    cs[1] += h1; cq[1] = fmaf(h1, h1, cq[1]);
    cs[2] += h2; cq[2] = fmaf(h2, h2, cq[2]);
    cs[3] += h3; cq[3] = fmaf(h3, h3, cq[3]);
  }
  __syncthreads();
  float* red = &As[0][0];
#pragma unroll
  for (int j = 0; j < 4; j++) {
    red[ty * 64 + tx * 4 + j] = cs[j];
    red[1024 + ty * 64 + tx * 4 + j] = cq[j];
  }
  __syncthreads();
  if (tid < 64) {
    float s = 0, q = 0;
#pragma unroll
    for (int t = 0; t < 16; t++) { s += red[t * 64 + tid]; q += red[1024 + t * 64 + tid]; }
    pSum[(size_t)blockIdx.x * 64 + tid] = s;
    pSq[(size_t)blockIdx.x * 64 + tid] = q;
  }
}

// ---------------- K2a: finalize BN -> affine aff[0:64]=A, aff[64:128]=C ----------------
// b1 is already inside h: hhat = (h - mu)*A + bn_b  ->  C = bn_b - mu*A.
__global__ __launch_bounds__(256) void k_bn_final(const float* __restrict__ pSum, const float* __restrict__ pSq,
                                                  const float* __restrict__ bn_g, const float* __restrict__ bn_b,
                                                  float* __restrict__ aff) {
  int c = blockIdx.x;
  float s = 0, q = 0;
  for (int i = threadIdx.x; i < 8192; i += 256) {
    s += pSum[(size_t)i * 64 + c];
    q += pSq[(size_t)i * 64 + c];
  }
  __shared__ float rs[256], rq[256];
  rs[threadIdx.x] = s; rq[threadIdx.x] = q;
  __syncthreads();
  for (int st = 128; st > 0; st >>= 1) {
    if (threadIdx.x < st) { rs[threadIdx.x] += rs[threadIdx.x + st]; rq[threadIdx.x] += rq[threadIdx.x + st]; }
    __syncthreads();
  }
  if (threadIdx.x == 0) {
    float mu = rs[0] / (float)N_TOT;
    float var = rq[0] / (float)N_TOT - mu * mu;
    var = fmaxf(var, 0.0f);
    float A = bn_g[c] * rsqrtf(var + 1e-5f);
    aff[c] = A;
    aff[64 + c] = bn_b[c] - mu * A;
  }
}

// ---------------- K2b: LSTM step1 from biases only; shared part of step-2 gates ----------------
__global__ __launch_bounds__(256) void k_lstm1(const float* __restrict__ bih, const float* __restrict__ bhh,
                                               const float* __restrict__ wih, const float* __restrict__ whh,
                                               float* __restrict__ q1, float* __restrict__ c1, float* __restrict__ sh2) {
  __shared__ float g1[256];
  __shared__ float q1s[64];
  int tid = threadIdx.x;
  g1[tid] = bih[tid] + bhh[tid];
  __syncthreads();
  if (tid < 64) {
    float ig = sigf(g1[tid]);
    float gg = tanhf(g1[128 + tid]);
    float cc = ig * gg;
    float og = sigf(g1[192 + tid]);
    float qv = og * tanhf(cc);
    q1s[tid] = qv; q1[tid] = qv; c1[tid] = cc;
  }
  __syncthreads();
  float acc = g1[tid];
  for (int k = 0; k < 64; k++)
    acc = fmaf(wih[(size_t)tid * 128 + k] + whh[(size_t)tid * 64 + k], q1s[k], acc);
  sh2[tid] = acc;
}

// ---------------- K3: streaming gate: bf16 h -> LDS f32 -> thread-per-row dot (no atomics) ----------------
__global__ __launch_bounds__(256) void k_gate_h(const unsigned short* __restrict__ h, const float* __restrict__ aff,
                                                const float* __restrict__ w2, const float* __restrict__ cb2,
                                                const float* __restrict__ eps_gate,
                                                float* __restrict__ lamWS, float* __restrict__ lamOut,
                                                int* __restrict__ presPart) {
  __shared__ float Hs[64][65];   // pad 65: max 2-way aliasing (free)
  __shared__ float A2s[64], C2s[64], w2s[64];
  __shared__ int pcnt[4];
  int tid = threadIdx.x;
  if (tid < 64) { A2s[tid] = aff[tid]; C2s[tid] = aff[64 + tid]; w2s[tid] = w2[tid]; }
  int n0 = blockIdx.x * 64;
#pragma unroll
  for (int s = 0; s < 4; s++) {
    int e4 = tid * 4 + s * 1024;
    int r = e4 >> 6, c = e4 & 63;
    ushort4 v = *(const ushort4*)&h[(size_t)(n0 + r) * 64 + c];
    Hs[r][c] = bf2f(v.x); Hs[r][c + 1] = bf2f(v.y);
    Hs[r][c + 2] = bf2f(v.z); Hs[r][c + 3] = bf2f(v.w);
  }
  __syncthreads();
  int r = tid >> 2, q = tid & 3;
  float p = 0.f;
#pragma unroll
  for (int j = 0; j < 16; j++) {
    int d = q * 16 + j;
    p = fmaf(fmaxf(fmaf(Hs[r][d], A2s[d], C2s[d]), 0.f), w2s[d], p);
  }
  p += __shfl_xor(p, 1);
  p += __shfl_xor(p, 2);
  p += cb2[0];
  unsigned long long m = __ballot(q == 0 && p > 0.0f);
  if ((tid & 63) == 0) pcnt[tid >> 6] = (int)__popcll(m);
  if (q == 0) {
    int row = n0 + r;
    float eg = eps_gate[row];
    float eps = 0.9999f - 0.9998f * eg;
    float gi = (flog2(eps) - flog2(1.0f - eps)) * LN2;
    float lam = sigf(gi + p);
    lamWS[row] = lam;
    lamOut[row] = lam;
  }
  __syncthreads();
  if (tid == 0) presPart[blockIdx.x] = pcnt[0] + pcnt[1] + pcnt[2] + pcnt[3];
}

// ---------------- K4: wave-per-graph: stats, noisy(bf16), KL, attn1, fused LSTM2 -> q2 ----------------
__global__ __launch_bounds__(256) void k_graph2(const float* __restrict__ X, const float* __restrict__ noise,
                                                const float* __restrict__ lam, const int* __restrict__ off,
                                                const float* __restrict__ q1g, const float* __restrict__ c1g,
                                                const float* __restrict__ sh2g, const float* __restrict__ rtg,
                                                unsigned short* __restrict__ noisy, float* __restrict__ qstar,
                                                float* __restrict__ klp) {
  int wg = blockIdx.x * 4 + (threadIdx.x >> 6);
  int lane = threadIdx.x & 63;
  bool lo = lane < 32;
  int n0 = off[wg], cnt = off[wg + 1] - n0;
  const float THR = 8.f;
  const float* xp = X + (size_t)n0 * 64 + lane;
  const float* zp = noise + (size_t)n0 * 64 + lane;
  unsigned short* nw = noisy + (size_t)n0 * 64 + lane;
  float r1v = 0.f;

  if (cnt > 0) {
    // ---- pass 1: per-dim mean / unbiased std ----
    float s0 = 0.f, q0 = 0.f, s1 = 0.f, q1_ = 0.f;
    int n = 0;
    for (; n + 2 <= cnt; n += 2) {
      float a = xp[(size_t)n * 64], b = xp[(size_t)(n + 1) * 64];
      s0 += a; q0 = fmaf(a, a, q0);
      s1 += b; q1_ = fmaf(b, b, q1_);
    }
    if (n < cnt) { float a = xp[(size_t)n * 64]; s0 += a; q0 = fmaf(a, a, q0); }
    float c = (float)cnt;
    float mean = (s0 + s1) / c;
    float var = fmaxf(((q0 + q1_) - c * mean * mean) / fmaxf(c - 1.f, 1.f), 0.f);
    float sd = sqrtf(var);
    float inv = frcp(sd + 1e-7f);
    float S1 = wave_sum(sd * sd * inv * inv);
    // ---- pass 2: noisy (bf16 store) + KL + online-softmax attn step 1 ----
    float q1v2 = q1g[lane] * LOG2E;
    float t2acc = 0.f, sumOm2 = 0.f;
    float m0 = -INFINITY, l0 = 0.f, r0 = 0.f;
    float m1 = -INFINITY, l1 = 0.f, r1a = 0.f;
    n = 0;
    for (; n + 2 <= cnt; n += 2) {
      float lamA = lam[n0 + n], lamB = lam[n0 + n + 1];
      float xA = xp[(size_t)n * 64], xB = xp[(size_t)(n + 1) * 64];
      float zA = zp[(size_t)n * 64], zB = zp[(size_t)(n + 1) * 64];
      float omA = 1.f - lamA, omB = 1.f - lamB;
      float nvA = fmaf(lamA, xA, omA * mean) + zA * (omA * sd);
      float nvB = fmaf(lamB, xB, omB * mean) + zB * (omB * sd);
      nw[(size_t)n * 64] = f2bf(nvA);
      nw[(size_t)(n + 1) * 64] = f2bf(nvB);
      float ldA = lamA * (xA - mean) * inv; t2acc = fmaf(ldA, ldA, t2acc);
      float ldB = lamB * (xB - mean) * inv; t2acc = fmaf(ldB, ldB, t2acc);
      sumOm2 = fmaf(omA, omA, sumOm2); sumOm2 = fmaf(omB, omB, sumOm2);
      float e0, e1;
      wave_sum2(nvA * q1v2, nvB * q1v2, lo, e0, e1);
      if (e0 > m0 + THR) { float sc = fexp2(m0 - e0); l0 *= sc; r0 *= sc; m0 = e0; }
      float pA = fexp2(e0 - m0); l0 += pA; r0 = fmaf(pA, nvA, r0);
      if (e1 > m1 + THR) { float sc = fexp2(m1 - e1); l1 *= sc; r1a *= sc; m1 = e1; }
      float pB = fexp2(e1 - m1); l1 += pB; r1a = fmaf(pB, nvB, r1a);
    }
    if (n < cnt) {
      float lamA = lam[n0 + n];
      float xA = xp[(size_t)n * 64];
      float zA = zp[(size_t)n * 64];
      float omA = 1.f - lamA;
      float nvA = fmaf(lamA, xA, omA * mean) + zA * (omA * sd);
      nw[(size_t)n * 64] = f2bf(nvA);
      float ldA = lamA * (xA - mean) * inv; t2acc = fmaf(ldA, ldA, t2acc);
      sumOm2 = fmaf(omA, omA, sumOm2);
      float e0 = wave_sum(nvA * q1v2);
      if (e0 > m0 + THR) { float sc = fexp2(m0 - e0); l0 *= sc; r0 *= sc; m0 = e0; }
      float pA = fexp2(e0 - m0); l0 += pA; r0 = fmaf(pA, nvA, r0);
    }
    float M = fmaxf(m0, m1);
    float sc0 = fexp2(m0 - M), sc1 = fexp2(m1 - M);
    float L = l0 * sc0 + l1 * sc1;
    float R = r0 * sc0 + r1a * sc1;
    r1v = R / L;
    float t2tot = wave_sum(t2acc);
    if (lane == 0) klp[wg] = fmaf(0.5f * sumOm2, S1, t2tot);
  } else {
    if (lane == 0) klp[wg] = 0.0f;
  }

  // ---- fused LSTM step 2: gates = sh2 + r1 @ R^T via RTg[k][d][4] (L2-resident) ----
  float a0 = 0.f, a1 = 0.f, a2 = 0.f, a3 = 0.f;
  const float4* rt = (const float4*)rtg;
#pragma unroll 4
  for (int k = 0; k < 64; k++) {
    float rk = __shfl(r1v, k);
    float4 w = rt[k * 64 + lane];
    a0 = fmaf(w.x, rk, a0); a1 = fmaf(w.y, rk, a1);
    a2 = fmaf(w.z, rk, a2); a3 = fmaf(w.w, rk, a3);
  }
  float ig = a0 + sh2g[lane];
  float fg = a1 + sh2g[64 + lane];
  float gg = a2 + sh2g[128 + lane];
  float og = a3 + sh2g[192 + lane];
  float c2 = sigf(fg) * c1g[lane] + sigf(ig) * tanhf(gg);
  float q2 = sigf(og) * tanhf(c2);
  qstar[(size_t)wg * 128 + lane] = q2;
}

// ---------------- K6: attention step 2, wave-per-graph, bf16 noisy (L3-resident) ----------------
__global__ __launch_bounds__(256) void k_attn2(const unsigned short* __restrict__ noisy, const int* __restrict__ off,
                                               float* __restrict__ qstar) {
  int wg = blockIdx.x * 4 + (threadIdx.x >> 6);
  int lane = threadIdx.x & 63;
  bool lo = lane < 32;
  int n0 = off[wg], cnt = off[wg + 1] - n0;
  float q2v2 = qstar[(size_t)wg * 128 + lane] * LOG2E;
  if (cnt == 0) { qstar[(size_t)wg * 128 + 64 + lane] = 0.f; return; }
  const unsigned short* np_ = noisy + (size_t)n0 * 64 + lane;
  const float THR = 8.f;
  float m0 = -INFINITY, l0 = 0.f, r0 = 0.f;
  float m1 = -INFINITY, l1 = 0.f, r1a = 0.f;
  int n = 0;
  for (; n + 2 <= cnt; n += 2) {
    float nvA = bf2f(np_[(size_t)n * 64]);
    float nvB = bf2f(np_[(size_t)(n + 1) * 64]);
    float e0, e1;
    wave_sum2(nvA * q2v2, nvB * q2v2, lo, e0, e1);
    if (e0 > m0 + THR) { float sc = fexp2(m0 - e0); l0 *= sc; r0 *= sc; m0 = e0; }
    float pA = fexp2(e0 - m0); l0 += pA; r0 = fmaf(pA, nvA, r0);
    if (e1 > m1 + THR) { float sc = fexp2(m1 - e1); l1 *= sc; r1a *= sc; m1 = e1; }
    float pB = fexp2(e1 - m1); l1 += pB; r1a = fmaf(pB, nvB, r1a);
  }
  if (n < cnt) {
    float nvA = bf2f(np_[(size_t)n * 64]);
    float e0 = wave_sum(nvA * q2v2);
    if (e0 > m0 + THR) { float sc = fexp2(m0 - e0); l0 *= sc; r0 *= sc; m0 = e0; }
    float pA = fexp2(e0 - m0); l0 += pA; r0 = fmaf(pA, nvA, r0);
  }
  float M = fmaxf(m0, m1);
  float sc0 = fexp2(m0 - M), sc1 = fexp2(m1 - M);
  float L = l0 * sc0 + l1 * sc1;
  float R = r0 * sc0 + r1a * sc1;
  qstar[(size_t)wg * 128 + 64 + lane] = R / L;
}

// ---------------- K7/8/9: predictor linear layers (pre-transposed weights) ----------------
template <int KDIM, int ODIM, bool RELU>
__global__ __launch_bounds__(256) void k_linear(const float* __restrict__ A, const float* __restrict__ WT,
                                                const float* __restrict__ bias, float* __restrict__ C) {
  __shared__ float As[64][68];
  __shared__ float Wt[64][68];
  int tid = threadIdx.x, ty = tid >> 4, tx = tid & 15;
  int n0 = blockIdx.x * 64, c0 = blockIdx.y * 64;
  float acc[4][4] = {};
  for (int kt = 0; kt < KDIM; kt += 64) {
    __syncthreads();
    load_A64(A, KDIM, n0, kt, As, tid);
    load_A64(WT, ODIM, kt, c0, Wt, tid);   // WT is [KDIM][ODIM] row-major
    __syncthreads();
    mm64(As, Wt, ty, tx, acc);
  }
#pragma unroll
  for (int i = 0; i < 4; i++) {
    int row = n0 + ty * 4 + i;
    float4 o;
    float v0 = acc[i][0] + bias[c0 + tx * 4 + 0];
    float v1 = acc[i][1] + bias[c0 + tx * 4 + 1];
    float v2 = acc[i][2] + bias[c0 + tx * 4 + 2];
    float v3 = acc[i][3] + bias[c0 + tx * 4 + 3];
    if (RELU) { v0 = fmaxf(v0, 0.f); v1 = fmaxf(v1, 0.f); v2 = fmaxf(v2, 0.f); v3 = fmaxf(v3, 0.f); }
    o.x = v0; o.y = v1; o.z = v2; o.w = v3;
    *(float4*)&C[(size_t)row * ODIM + c0 + tx * 4] = o;
  }
}

// ---------------- K10: final scalars ----------------
__global__ __launch_bounds__(256) void k_final(const float* __restrict__ klp, const int* __restrict__ presPart,
                                               float* __restrict__ out) {
  __shared__ float red[256];
  __shared__ int redi[256];
  float s = 0.0f;
  int pc = 0;
  for (int i = threadIdx.x; i < B_GR; i += 256) s += klp[i];
  for (int i = threadIdx.x; i < 8192; i += 256) pc += presPart[i];
  red[threadIdx.x] = s;
  redi[threadIdx.x] = pc;
  __syncthreads();
  for (int st = 128; st > 0; st >>= 1) {
    if (threadIdx.x < st) {
      red[threadIdx.x] += red[threadIdx.x + st];
      redi[threadIdx.x] += redi[threadIdx.x + st];
    }
    __syncthreads();
  }
  if (threadIdx.x == 0) {
    out[(size_t)B_GR * 64] = red[0] / (float)(B_GR * 64);
    out[(size_t)B_GR * 64 + 1] = (float)redi[0] / (float)N_TOT;
  }
}

// ---------------- launcher ----------------
extern "C" void kernel_launch(void* const* d_in, const int* in_sizes, int n_in,
                              void* d_out, int out_size, void* d_ws, size_t ws_size,
                              hipStream_t stream) {
  const float* features = (const float*)d_in[0];
  const int*   bidx     = (const int*)d_in[1];
  const float* eps_gate = (const float*)d_in[2];
  const float* noise    = (const float*)d_in[3];
  const float* c_w1 = (const float*)d_in[4];
  const float* c_b1 = (const float*)d_in[5];
  const float* bn_g = (const float*)d_in[6];
  const float* bn_b = (const float*)d_in[7];
  const float* c_w2 = (const float*)d_in[8];
  const float* c_b2 = (const float*)d_in[9];
  const float* wih  = (const float*)d_in[10];
  const float* whh  = (const float*)d_in[11];
  const float* bih  = (const float*)d_in[12];
  const float* bhh  = (const float*)d_in[13];
  const float* p_w1 = (const float*)d_in[14];
  const float* p_b1 = (const float*)d_in[15];
  const float* p_w2 = (const float*)d_in[16];
  const float* p_b2 = (const float*)d_in[17];
  const float* p_w3 = (const float*)d_in[18];
  const float* p_b3 = (const float*)d_in[19];
  float* out = (float*)d_out;

  float* wsf   = (float*)d_ws;
  int*   offp  = (int*)wsf;                                 // (B+1) ints
  float* pSum  = wsf + 16448;                               // 8192*64
  float* pSq   = pSum + 524288;                             // 8192*64
  float* aff   = pSq + 524288;                              // 128
  float* q1w   = aff + 128;                                 // 64
  float* c1w   = q1w + 64;                                  // 64
  float* sh2w  = c1w + 64;                                  // 256
  float* lamw  = sh2w + 256;                                // N
  float* cw1T  = lamw + (size_t)N_TOT;                      // 64*64
  float* pw1T  = cw1T + 4096;                               // 128*256
  float* pw2T  = pw1T + 32768;                              // 256*128
  float* pw3T  = pw2T + 32768;                              // 128*64
  float* rtgw  = pw3T + 8192;                               // 64*256 (RTg)
  float* hwf   = rtgw + 16384;                              // N*64 float-sized region (bf16 uses half)
  unsigned short* hb = (unsigned short*)hwf;                // h as bf16; later overwritten by noisy
  unsigned short* noisyb = hb;                              // shared buffer: h dead after k_gate_h
  float* qstarw = hwf + (size_t)N_TOT * 64;                 // B*128
  float* z1w    = qstarw + (size_t)B_GR * 128;              // B*256
  float* z2w    = z1w + (size_t)B_GR * 256;                 // B*128
  float* klpw   = z2w + (size_t)B_GR * 128;                 // B
  int*   presPart = (int*)(klpw + B_GR);                    // 8192 ints

  float* lamOut = out + (size_t)B_GR * 64 + 2;

  k_offsets<<<(B_GR + 1 + 255) / 256, 256, 0, stream>>>(bidx, offp);
  k_prep<<<64, 256, 0, stream>>>(c_w1, p_w1, p_w2, p_w3, wih, cw1T, pw1T, pw2T, pw3T, rtgw);
  k_bn_stats<<<N_TOT / 64, 256, 0, stream>>>(features, cw1T, c_b1, hb, pSum, pSq);
  k_bn_final<<<64, 256, 0, stream>>>(pSum, pSq, bn_g, bn_b, aff);
  k_lstm1<<<1, 256, 0, stream>>>(bih, bhh, wih, whh, q1w, c1w, sh2w);
  k_gate_h<<<N_TOT / 64, 256, 0, stream>>>(hb, aff, c_w2, c_b2, eps_gate, lamw, lamOut, presPart);
  k_graph2<<<B_GR / 4, 256, 0, stream>>>(features, noise, lamw, offp, q1w, c1w, sh2w, rtgw,
                                         noisyb, qstarw, klpw);
  k_attn2<<<B_GR / 4, 256, 0, stream>>>(noisyb, offp, qstarw);
  k_linear<128, 256, true><<<dim3(B_GR / 64, 4), 256, 0, stream>>>(qstarw, pw1T, p_b1, z1w);
  k_linear<256, 128, true><<<dim3(B_GR / 64, 2), 256, 0, stream>>>(z1w, pw2T, p_b2, z2w);
  k_linear<128, 64, false><<<dim3(B_GR / 64, 1), 256, 0, stream>>>(z2w, pw3T, p_b3, out);
  k_final<<<1, 256, 0, stream>>>(klpw, presPart, out);
}

// Round 11
// 334.252 us; speedup vs baseline: 2.2432x; 1.0622x over previous
//
#include <hip/hip_runtime.h>
#include <math.h>

#define N_TOT 524288
#define B_GR  16384
#define CAPR  64

#define LOG2E 1.44269504088896f
#define LN2   0.69314718055995f

// ---------------- small device helpers ----------------
__device__ __forceinline__ float fexp2(float x) { return __builtin_amdgcn_exp2f(x); }
__device__ __forceinline__ float flog2(float x) { return __builtin_amdgcn_logf(x); }
__device__ __forceinline__ float frcp(float x)  { return __builtin_amdgcn_rcpf(x); }
__device__ __forceinline__ float sigf(float x)  { return frcp(1.0f + fexp2(-x * LOG2E)); }

// bf16 pack/unpack (RNE)
__device__ __forceinline__ unsigned int f2bf(float x) {
  unsigned int u = __float_as_uint(x);
  return (u + 0x7FFFu + ((u >> 16) & 1u)) >> 16;
}
__device__ __forceinline__ float bf2f(unsigned int s) {
  return __uint_as_float(s << 16);
}

__device__ __forceinline__ float wave_sum(float v) {
#pragma unroll
  for (int o = 32; o > 0; o >>= 1) v += __shfl_xor(v, o);
  return v;
}
// Reduce TWO values across 64 lanes with 8 shuffles (vs 12).
__device__ __forceinline__ void wave_sum2(float p0, float p1, bool lo, float& e0, float& e1) {
  float a = p0 + __shfl_xor(p0, 32);
  float b = p1 + __shfl_xor(p1, 32);
  float c = lo ? a : b;
#pragma unroll
  for (int o = 16; o > 0; o >>= 1) c += __shfl_xor(c, o);
  float d = __shfl_xor(c, 32);
  e0 = lo ? c : d;
  e1 = lo ? d : c;
}

// ---------------- 64x64 f32 register-tiled GEMM pieces ----------------
__device__ __forceinline__ void load_A64(const float* __restrict__ A, size_t lda, int n0, int k0,
                                         float (*As)[68], int tid) {
#pragma unroll
  for (int s = 0; s < 4; s++) {
    int e4 = tid * 4 + s * 1024;
    int r = e4 >> 6, k = e4 & 63;
    *(float4*)&As[r][k] = *(const float4*)&A[(size_t)(n0 + r) * lda + k0 + k];
  }
}
__device__ __forceinline__ void mm64(const float (*As)[68], const float (*Wt)[68],
                                     int ty, int tx, float acc[4][4]) {
#pragma unroll
  for (int k4 = 0; k4 < 64; k4 += 4) {
    float4 b0 = *(const float4*)&Wt[k4 + 0][tx * 4];
    float4 b1 = *(const float4*)&Wt[k4 + 1][tx * 4];
    float4 b2 = *(const float4*)&Wt[k4 + 2][tx * 4];
    float4 b3 = *(const float4*)&Wt[k4 + 3][tx * 4];
#pragma unroll
    for (int i = 0; i < 4; i++) {
      float4 a = *(const float4*)&As[ty * 4 + i][k4];
      acc[i][0] = fmaf(a.w, b3.x, fmaf(a.z, b2.x, fmaf(a.y, b1.x, fmaf(a.x, b0.x, acc[i][0]))));
      acc[i][1] = fmaf(a.w, b3.y, fmaf(a.z, b2.y, fmaf(a.y, b1.y, fmaf(a.x, b0.y, acc[i][1]))));
      acc[i][2] = fmaf(a.w, b3.z, fmaf(a.z, b2.z, fmaf(a.y, b1.z, fmaf(a.x, b0.z, acc[i][2]))));
      acc[i][3] = fmaf(a.w, b3.w, fmaf(a.z, b2.w, fmaf(a.y, b1.w, fmaf(a.x, b0.w, acc[i][3]))));
    }
  }
}

// ---------------- K0a: graph offsets via binary search (batch_index is sorted) ----------------
__global__ void k_offsets(const int* __restrict__ idx, int* __restrict__ off) {
  int b = blockIdx.x * blockDim.x + threadIdx.x;
  if (b > B_GR) return;
  if (b == B_GR) { off[B_GR] = N_TOT; return; }
  int lo = 0, hi = N_TOT;
  while (lo < hi) { int mid = (lo + hi) >> 1; if (idx[mid] < b) lo = mid + 1; else hi = mid; }
  off[b] = lo;
}

// ---------------- K0b: pre-transpose weights; build RTg[k][d][j] for fused LSTM2 ----------------
__global__ void k_prep(const float* __restrict__ w1, const float* __restrict__ pw1,
                       const float* __restrict__ pw2, const float* __restrict__ pw3,
                       const float* __restrict__ wih,
                       float* __restrict__ w1T, float* __restrict__ pw1T,
                       float* __restrict__ pw2T, float* __restrict__ pw3T,
                       float* __restrict__ rtg) {
  int t = blockIdx.x * 256 + threadIdx.x;          // 64 blocks * 256 = 16384 threads
  for (int i = t; i < 64 * 64; i += 16384)  { int r = i >> 6, c = i & 63;  w1T[c * 64 + r]   = w1[i]; }
  for (int i = t; i < 256 * 128; i += 16384){ int r = i >> 7, c = i & 127; pw1T[c * 256 + r] = pw1[i]; }
  for (int i = t; i < 128 * 256; i += 16384){ int r = i >> 8, c = i & 255; pw2T[c * 128 + r] = pw2[i]; }
  for (int i = t; i < 64 * 128; i += 16384) { int r = i >> 7, c = i & 127; pw3T[c * 64 + r]  = pw3[i]; }
  // RTg[((k*64)+d)*4 + j] = Wih[j*64+d][64+k]  (j = gate index i,f,g,o)
  for (int i = t; i < 64 * 64 * 4; i += 16384) {
    int k = i >> 8, rem = i & 255, d = rem >> 2, j = rem & 3;
    rtg[i] = wih[(size_t)(j * 64 + d) * 128 + 64 + k];
  }
}

// ---------------- K1: h = X@W1^T + b1 -> STORE h as bf16; stats partials (f32-exact) ----------------
__global__ __launch_bounds__(256) void k_bn_stats(const float* __restrict__ X, const float* __restrict__ W1T,
                                                  const float* __restrict__ b1, unsigned short* __restrict__ h,
                                                  float* __restrict__ pSum, float* __restrict__ pSq) {
  __shared__ float As[64][68];
  __shared__ float Wt[64][68];
  int tid = threadIdx.x, ty = tid >> 4, tx = tid & 15;
  int n0 = blockIdx.x * 64;
  float acc[4][4] = {};
  load_A64(X, 64, n0, 0, As, tid);
  load_A64(W1T, 64, 0, 0, Wt, tid);
  __syncthreads();
  mm64(As, Wt, ty, tx, acc);
  float4 bv = *(const float4*)&b1[tx * 4];
  float cs[4] = {0, 0, 0, 0}, cq[4] = {0, 0, 0, 0};
#pragma unroll
  for (int i = 0; i < 4; i++) {
    float h0 = acc[i][0] + bv.x, h1 = acc[i][1] + bv.y;
    float h2 = acc[i][2] + bv.z, h3 = acc[i][3] + bv.w;
    ushort4 hb;
    hb.x = (unsigned short)f2bf(h0); hb.y = (unsigned short)f2bf(h1);
    hb.z = (unsigned short)f2bf(h2); hb.w = (unsigned short)f2bf(h3);
    *(ushort4*)&h[(size_t)(n0 + ty * 4 + i) * 64 + tx * 4] = hb;
    cs[0] += h0; cq[0] = fmaf(h0, h0, cq[0]);
    cs[1] += h1; cq[1] = fmaf(h1, h1, cq[1]);
    cs[2] += h2; cq[2] = fmaf(h2, h2, cq[2]);
    cs[3] += h3; cq[3] = fmaf(h3, h3, cq[3]);
  }
  __syncthreads();
  float* red = &As[0][0];
#pragma unroll
  for (int j = 0; j < 4; j++) {
    red[ty * 64 + tx * 4 + j] = cs[j];
    red[1024 + ty * 64 + tx * 4 + j] = cq[j];
  }
  __syncthreads();
  if (tid < 64) {
    float s = 0, q = 0;
#pragma unroll
    for (int t = 0; t < 16; t++) { s += red[t * 64 + tid]; q += red[1024 + t * 64 + tid]; }
    pSum[(size_t)blockIdx.x * 64 + tid] = s;
    pSq[(size_t)blockIdx.x * 64 + tid] = q;
  }
}

// ---------------- K2a: finalize BN -> affine aff[0:64]=A, aff[64:128]=C ----------------
__global__ __launch_bounds__(256) void k_bn_final(const float* __restrict__ pSum, const float* __restrict__ pSq,
                                                  const float* __restrict__ bn_g, const float* __restrict__ bn_b,
                                                  float* __restrict__ aff) {
  int c = blockIdx.x;
  float s = 0, q = 0;
  for (int i = threadIdx.x; i < 8192; i += 256) {
    s += pSum[(size_t)i * 64 + c];
    q += pSq[(size_t)i * 64 + c];
  }
  __shared__ float rs[256], rq[256];
  rs[threadIdx.x] = s; rq[threadIdx.x] = q;
  __syncthreads();
  for (int st = 128; st > 0; st >>= 1) {
    if (threadIdx.x < st) { rs[threadIdx.x] += rs[threadIdx.x + st]; rq[threadIdx.x] += rq[threadIdx.x + st]; }
    __syncthreads();
  }
  if (threadIdx.x == 0) {
    float mu = rs[0] / (float)N_TOT;
    float var = rq[0] / (float)N_TOT - mu * mu;
    var = fmaxf(var, 0.0f);
    float A = bn_g[c] * rsqrtf(var + 1e-5f);
    aff[c] = A;
    aff[64 + c] = bn_b[c] - mu * A;
  }
}

// ---------------- K2b: LSTM step1 from biases only; shared part of step-2 gates ----------------
__global__ __launch_bounds__(256) void k_lstm1(const float* __restrict__ bih, const float* __restrict__ bhh,
                                               const float* __restrict__ wih, const float* __restrict__ whh,
                                               float* __restrict__ q1, float* __restrict__ c1, float* __restrict__ sh2) {
  __shared__ float g1[256];
  __shared__ float q1s[64];
  int tid = threadIdx.x;
  g1[tid] = bih[tid] + bhh[tid];
  __syncthreads();
  if (tid < 64) {
    float ig = sigf(g1[tid]);
    float gg = tanhf(g1[128 + tid]);
    float cc = ig * gg;
    float og = sigf(g1[192 + tid]);
    float qv = og * tanhf(cc);
    q1s[tid] = qv; q1[tid] = qv; c1[tid] = cc;
  }
  __syncthreads();
  float acc = g1[tid];
  for (int k = 0; k < 64; k++)
    acc = fmaf(wih[(size_t)tid * 128 + k] + whh[(size_t)tid * 64 + k], q1s[k], acc);
  sh2[tid] = acc;
}

// ---------------- K3: streaming gate: bf16 h -> LDS f32 -> thread-per-row dot (no atomics) ----------------
__global__ __launch_bounds__(256) void k_gate_h(const unsigned short* __restrict__ h, const float* __restrict__ aff,
                                                const float* __restrict__ w2, const float* __restrict__ cb2,
                                                const float* __restrict__ eps_gate,
                                                float* __restrict__ lamWS, float* __restrict__ lamOut,
                                                int* __restrict__ presPart) {
  __shared__ float Hs[64][65];
  __shared__ float A2s[64], C2s[64], w2s[64];
  __shared__ int pcnt[4];
  int tid = threadIdx.x;
  if (tid < 64) { A2s[tid] = aff[tid]; C2s[tid] = aff[64 + tid]; w2s[tid] = w2[tid]; }
  int n0 = blockIdx.x * 64;
#pragma unroll
  for (int s = 0; s < 4; s++) {
    int e4 = tid * 4 + s * 1024;
    int r = e4 >> 6, c = e4 & 63;
    ushort4 v = *(const ushort4*)&h[(size_t)(n0 + r) * 64 + c];
    Hs[r][c] = bf2f(v.x); Hs[r][c + 1] = bf2f(v.y);
    Hs[r][c + 2] = bf2f(v.z); Hs[r][c + 3] = bf2f(v.w);
  }
  __syncthreads();
  int r = tid >> 2, q = tid & 3;
  float p = 0.f;
#pragma unroll
  for (int j = 0; j < 16; j++) {
    int d = q * 16 + j;
    p = fmaf(fmaxf(fmaf(Hs[r][d], A2s[d], C2s[d]), 0.f), w2s[d], p);
  }
  p += __shfl_xor(p, 1);
  p += __shfl_xor(p, 2);
  p += cb2[0];
  unsigned long long m = __ballot(q == 0 && p > 0.0f);
  if ((tid & 63) == 0) pcnt[tid >> 6] = (int)__popcll(m);
  if (q == 0) {
    int row = n0 + r;
    float eg = eps_gate[row];
    float eps = 0.9999f - 0.9998f * eg;
    float gi = (flog2(eps) - flog2(1.0f - eps)) * LN2;
    float lam = sigf(gi + p);
    lamWS[row] = lam;
    lamOut[row] = lam;
  }
  __syncthreads();
  if (tid == 0) presPart[blockIdx.x] = pcnt[0] + pcnt[1] + pcnt[2] + pcnt[3];
}

// ---------------- K4: FULLY register-resident wave-per-graph pipeline ----------------
// Stats (f32-exact), noisy (bf16, REGISTERS ONLY - never written to memory), KL,
// attn1 (online softmax), fused LSTM2, attn2 from registers. Fallback to global
// memory path for the (astronomically rare) cnt > CAPR graph.
__global__ __launch_bounds__(256) void k_graph_reg(const float* __restrict__ X, const float* __restrict__ noise,
                                                   const float* __restrict__ lam, const int* __restrict__ off,
                                                   const float* __restrict__ q1g, const float* __restrict__ c1g,
                                                   const float* __restrict__ sh2g, const float* __restrict__ rtg,
                                                   unsigned short* __restrict__ noisyFB, float* __restrict__ qstar,
                                                   float* __restrict__ klp) {
  int wg = blockIdx.x * 4 + (threadIdx.x >> 6);
  int lane = threadIdx.x & 63;
  bool lo = lane < 32;
  int n0 = off[wg], cnt = off[wg + 1] - n0;
  const float THR = 8.f;
  const float* xp = X + (size_t)n0 * 64 + lane;
  const float* zp = noise + (size_t)n0 * 64 + lane;
  float r1v = 0.f;
  bool fits = (cnt <= CAPR);
  unsigned int pk[CAPR / 2];   // packed bf16 pairs: X in pass1, overwritten with noisy in pass2

  if (cnt > 0 && fits) {
    // ---- pass 1: stream X (f32-exact stats), stash bf16 X into regs ----
    float s0 = 0.f, q0 = 0.f, s1 = 0.f, q1_ = 0.f;
#pragma unroll
    for (int np = 0; np < CAPR / 2; np++) {
      int n = 2 * np;
      if (n < cnt) {
        float a = xp[(size_t)n * 64];
        s0 += a; q0 = fmaf(a, a, q0);
        float b = 0.f;
        if (n + 1 < cnt) {
          b = xp[(size_t)(n + 1) * 64];
          s1 += b; q1_ = fmaf(b, b, q1_);
        }
        pk[np] = (f2bf(b) << 16) | f2bf(a);
      }
    }
    float c = (float)cnt;
    float mean = (s0 + s1) / c;
    float var = fmaxf(((q0 + q1_) - c * mean * mean) / fmaxf(c - 1.f, 1.f), 0.f);
    float sd = sqrtf(var);
    float inv = frcp(sd + 1e-7f);
    float S1 = wave_sum(sd * sd * inv * inv);
    // ---- pass 2: noise+lam -> noisy (bf16 into SAME regs), KL, attn1 ----
    float q1v2 = q1g[lane] * LOG2E;
    float t2acc = 0.f, sumOm2 = 0.f;
    float m0 = -INFINITY, l0 = 0.f, r0 = 0.f;
    float m1 = -INFINITY, l1 = 0.f, r1a = 0.f;
#pragma unroll
    for (int np = 0; np < CAPR / 2; np++) {
      int n = 2 * np;
      if (n < cnt) {
        bool hasB = (n + 1 < cnt);
        unsigned int p2 = pk[np];
        float xA = bf2f(p2 & 0xffffu), xB = bf2f(p2 >> 16);
        float lamA = lam[n0 + n];
        float zA = zp[(size_t)n * 64];
        float lamB = hasB ? lam[n0 + n + 1] : 0.f;
        float zB = hasB ? zp[(size_t)(n + 1) * 64] : 0.f;
        float omA = 1.f - lamA, omB = 1.f - lamB;
        float nvA = fmaf(lamA, xA, omA * mean) + zA * (omA * sd);
        float nvB = fmaf(lamB, xB, omB * mean) + zB * (omB * sd);
        pk[np] = (f2bf(nvB) << 16) | f2bf(nvA);
        float ldA = lamA * (xA - mean) * inv; t2acc = fmaf(ldA, ldA, t2acc);
        sumOm2 = fmaf(omA, omA, sumOm2);
        if (hasB) {
          float ldB = lamB * (xB - mean) * inv; t2acc = fmaf(ldB, ldB, t2acc);
          sumOm2 = fmaf(omB, omB, sumOm2);
        }
        float e0, e1;
        wave_sum2(nvA * q1v2, hasB ? nvB * q1v2 : 0.f, lo, e0, e1);
        if (e0 > m0 + THR) { float sc = fexp2(m0 - e0); l0 *= sc; r0 *= sc; m0 = e0; }
        float pA = fexp2(e0 - m0); l0 += pA; r0 = fmaf(pA, nvA, r0);
        if (hasB) {
          if (e1 > m1 + THR) { float sc = fexp2(m1 - e1); l1 *= sc; r1a *= sc; m1 = e1; }
          float pB = fexp2(e1 - m1); l1 += pB; r1a = fmaf(pB, nvB, r1a);
        }
      }
    }
    float M = fmaxf(m0, m1);
    float sc0 = fexp2(m0 - M), sc1 = (m1 == -INFINITY) ? 0.f : fexp2(m1 - M);
    float L = l0 * sc0 + l1 * sc1;
    float R = r0 * sc0 + r1a * sc1;
    r1v = R / L;
    float t2tot = wave_sum(t2acc);
    if (lane == 0) klp[wg] = fmaf(0.5f * sumOm2, S1, t2tot);
  } else if (cnt > 0) {
    // ---- fallback (cnt > CAPR): global-memory path, bf16 noisy to noisyFB ----
    unsigned short* nw = noisyFB + (size_t)n0 * 64 + lane;
    float s0 = 0.f, q0 = 0.f;
    for (int n = 0; n < cnt; n++) { float a = xp[(size_t)n * 64]; s0 += a; q0 = fmaf(a, a, q0); }
    float c = (float)cnt;
    float mean = s0 / c;
    float var = fmaxf((q0 - c * mean * mean) / fmaxf(c - 1.f, 1.f), 0.f);
    float sd = sqrtf(var);
    float inv = frcp(sd + 1e-7f);
    float S1 = wave_sum(sd * sd * inv * inv);
    float q1v2 = q1g[lane] * LOG2E;
    float t2acc = 0.f, sumOm2 = 0.f;
    float m0 = -INFINITY, l0 = 0.f, r0 = 0.f;
    for (int n = 0; n < cnt; n++) {
      float lamA = lam[n0 + n];
      float xA = xp[(size_t)n * 64];
      float zA = zp[(size_t)n * 64];
      float omA = 1.f - lamA;
      float nvA = fmaf(lamA, xA, omA * mean) + zA * (omA * sd);
      nw[(size_t)n * 64] = (unsigned short)f2bf(nvA);
      float ldA = lamA * (xA - mean) * inv; t2acc = fmaf(ldA, ldA, t2acc);
      sumOm2 = fmaf(omA, omA, sumOm2);
      float e0 = wave_sum(nvA * q1v2);
      if (e0 > m0 + THR) { float sc = fexp2(m0 - e0); l0 *= sc; r0 *= sc; m0 = e0; }
      float pA = fexp2(e0 - m0); l0 += pA; r0 = fmaf(pA, nvA, r0);
    }
    r1v = r0 / l0;
    float t2tot = wave_sum(t2acc);
    if (lane == 0) klp[wg] = fmaf(0.5f * sumOm2, S1, t2tot);
  } else {
    if (lane == 0) klp[wg] = 0.0f;
  }

  // ---- fused LSTM step 2: gates = sh2 + r1 @ R^T via RTg[k][d][4] (L2-resident) ----
  float a0 = 0.f, a1 = 0.f, a2 = 0.f, a3 = 0.f;
  const float4* rt = (const float4*)rtg;
#pragma unroll 4
  for (int k = 0; k < 64; k++) {
    float rk = __shfl(r1v, k);
    float4 w = rt[k * 64 + lane];
    a0 = fmaf(w.x, rk, a0); a1 = fmaf(w.y, rk, a1);
    a2 = fmaf(w.z, rk, a2); a3 = fmaf(w.w, rk, a3);
  }
  float ig = a0 + sh2g[lane];
  float fg = a1 + sh2g[64 + lane];
  float gg = a2 + sh2g[128 + lane];
  float og = a3 + sh2g[192 + lane];
  float c2 = sigf(fg) * c1g[lane] + sigf(ig) * tanhf(gg);
  float q2 = sigf(og) * tanhf(c2);
  qstar[(size_t)wg * 128 + lane] = q2;

  // ---- fused attention step 2: noisy straight from registers (zero memory) ----
  float r2v = 0.f;
  if (cnt > 0) {
    float q2v2 = q2 * LOG2E;
    float m0 = -INFINITY, l0 = 0.f, r0 = 0.f;
    float m1 = -INFINITY, l1 = 0.f, r1a = 0.f;
    if (fits) {
#pragma unroll
      for (int np = 0; np < CAPR / 2; np++) {
        int n = 2 * np;
        if (n < cnt) {
          bool hasB = (n + 1 < cnt);
          unsigned int p2 = pk[np];
          float nvA = bf2f(p2 & 0xffffu), nvB = bf2f(p2 >> 16);
          float e0, e1;
          wave_sum2(nvA * q2v2, hasB ? nvB * q2v2 : 0.f, lo, e0, e1);
          if (e0 > m0 + THR) { float sc = fexp2(m0 - e0); l0 *= sc; r0 *= sc; m0 = e0; }
          float pA = fexp2(e0 - m0); l0 += pA; r0 = fmaf(pA, nvA, r0);
          if (hasB) {
            if (e1 > m1 + THR) { float sc = fexp2(m1 - e1); l1 *= sc; r1a *= sc; m1 = e1; }
            float pB = fexp2(e1 - m1); l1 += pB; r1a = fmaf(pB, nvB, r1a);
          }
        }
      }
    } else {
      const unsigned short* np_ = noisyFB + (size_t)n0 * 64 + lane;
      for (int n = 0; n < cnt; n++) {
        float nvA = bf2f(np_[(size_t)n * 64]);
        float e0 = wave_sum(nvA * q2v2);
        if (e0 > m0 + THR) { float sc = fexp2(m0 - e0); l0 *= sc; r0 *= sc; m0 = e0; }
        float pA = fexp2(e0 - m0); l0 += pA; r0 = fmaf(pA, nvA, r0);
      }
    }
    float M = fmaxf(m0, m1);
    float sc0 = fexp2(m0 - M), sc1 = (m1 == -INFINITY) ? 0.f : fexp2(m1 - M);
    float L = l0 * sc0 + l1 * sc1;
    float R = r0 * sc0 + r1a * sc1;
    r2v = R / L;
  }
  qstar[(size_t)wg * 128 + 64 + lane] = r2v;
}

// ---------------- K7/8/9: predictor linear layers (pre-transposed weights) ----------------
template <int KDIM, int ODIM, bool RELU>
__global__ __launch_bounds__(256) void k_linear(const float* __restrict__ A, const float* __restrict__ WT,
                                                const float* __restrict__ bias, float* __restrict__ C) {
  __shared__ float As[64][68];
  __shared__ float Wt[64][68];
  int tid = threadIdx.x, ty = tid >> 4, tx = tid & 15;
  int n0 = blockIdx.x * 64, c0 = blockIdx.y * 64;
  float acc[4][4] = {};
  for (int kt = 0; kt < KDIM; kt += 64) {
    __syncthreads();
    load_A64(A, KDIM, n0, kt, As, tid);
    load_A64(WT, ODIM, kt, c0, Wt, tid);   // WT is [KDIM][ODIM] row-major
    __syncthreads();
    mm64(As, Wt, ty, tx, acc);
  }
#pragma unroll
  for (int i = 0; i < 4; i++) {
    int row = n0 + ty * 4 + i;
    float4 o;
    float v0 = acc[i][0] + bias[c0 + tx * 4 + 0];
    float v1 = acc[i][1] + bias[c0 + tx * 4 + 1];
    float v2 = acc[i][2] + bias[c0 + tx * 4 + 2];
    float v3 = acc[i][3] + bias[c0 + tx * 4 + 3];
    if (RELU) { v0 = fmaxf(v0, 0.f); v1 = fmaxf(v1, 0.f); v2 = fmaxf(v2, 0.f); v3 = fmaxf(v3, 0.f); }
    o.x = v0; o.y = v1; o.z = v2; o.w = v3;
    *(float4*)&C[(size_t)row * ODIM + c0 + tx * 4] = o;
  }
}

// ---------------- K10: final scalars ----------------
__global__ __launch_bounds__(256) void k_final(const float* __restrict__ klp, const int* __restrict__ presPart,
                                               float* __restrict__ out) {
  __shared__ float red[256];
  __shared__ int redi[256];
  float s = 0.0f;
  int pc = 0;
  for (int i = threadIdx.x; i < B_GR; i += 256) s += klp[i];
  for (int i = threadIdx.x; i < 8192; i += 256) pc += presPart[i];
  red[threadIdx.x] = s;
  redi[threadIdx.x] = pc;
  __syncthreads();
  for (int st = 128; st > 0; st >>= 1) {
    if (threadIdx.x < st) {
      red[threadIdx.x] += red[threadIdx.x + st];
      redi[threadIdx.x] += redi[threadIdx.x + st];
    }
    __syncthreads();
  }
  if (threadIdx.x == 0) {
    out[(size_t)B_GR * 64] = red[0] / (float)(B_GR * 64);
    out[(size_t)B_GR * 64 + 1] = (float)redi[0] / (float)N_TOT;
  }
}

// ---------------- launcher ----------------
extern "C" void kernel_launch(void* const* d_in, const int* in_sizes, int n_in,
                              void* d_out, int out_size, void* d_ws, size_t ws_size,
                              hipStream_t stream) {
  const float* features = (const float*)d_in[0];
  const int*   bidx     = (const int*)d_in[1];
  const float* eps_gate = (const float*)d_in[2];
  const float* noise    = (const float*)d_in[3];
  const float* c_w1 = (const float*)d_in[4];
  const float* c_b1 = (const float*)d_in[5];
  const float* bn_g = (const float*)d_in[6];
  const float* bn_b = (const float*)d_in[7];
  const float* c_w2 = (const float*)d_in[8];
  const float* c_b2 = (const float*)d_in[9];
  const float* wih  = (const float*)d_in[10];
  const float* whh  = (const float*)d_in[11];
  const float* bih  = (const float*)d_in[12];
  const float* bhh  = (const float*)d_in[13];
  const float* p_w1 = (const float*)d_in[14];
  const float* p_b1 = (const float*)d_in[15];
  const float* p_w2 = (const float*)d_in[16];
  const float* p_b2 = (const float*)d_in[17];
  const float* p_w3 = (const float*)d_in[18];
  const float* p_b3 = (const float*)d_in[19];
  float* out = (float*)d_out;

  float* wsf   = (float*)d_ws;
  int*   offp  = (int*)wsf;                                 // (B+1) ints
  float* pSum  = wsf + 16448;                               // 8192*64
  float* pSq   = pSum + 524288;                             // 8192*64
  float* aff   = pSq + 524288;                              // 128
  float* q1w   = aff + 128;                                 // 64
  float* c1w   = q1w + 64;                                  // 64
  float* sh2w  = c1w + 64;                                  // 256
  float* lamw  = sh2w + 256;                                // N
  float* cw1T  = lamw + (size_t)N_TOT;                      // 64*64
  float* pw1T  = cw1T + 4096;                               // 128*256
  float* pw2T  = pw1T + 32768;                              // 256*128
  float* pw3T  = pw2T + 32768;                              // 128*64
  float* rtgw  = pw3T + 8192;                               // 64*256 (RTg)
  float* hwf   = rtgw + 16384;                              // N*64 float-sized region
  unsigned short* hb = (unsigned short*)hwf;                // h as bf16; later reused as noisy fallback
  unsigned short* noisyFB = hb;                             // fallback noisy (h dead after k_gate_h)
  float* qstarw = hwf + (size_t)N_TOT * 64;                 // B*128
  float* z1w    = qstarw + (size_t)B_GR * 128;              // B*256
  float* z2w    = z1w + (size_t)B_GR * 256;                 // B*128
  float* klpw   = z2w + (size_t)B_GR * 128;                 // B
  int*   presPart = (int*)(klpw + B_GR);                    // 8192 ints

  float* lamOut = out + (size_t)B_GR * 64 + 2;

  k_offsets<<<(B_GR + 1 + 255) / 256, 256, 0, stream>>>(bidx, offp);
  k_prep<<<64, 256, 0, stream>>>(c_w1, p_w1, p_w2, p_w3, wih, cw1T, pw1T, pw2T, pw3T, rtgw);
  k_bn_stats<<<N_TOT / 64, 256, 0, stream>>>(features, cw1T, c_b1, hb, pSum, pSq);
  k_bn_final<<<64, 256, 0, stream>>>(pSum, pSq, bn_g, bn_b, aff);
  k_lstm1<<<1, 256, 0, stream>>>(bih, bhh, wih, whh, q1w, c1w, sh2w);
  k_gate_h<<<N_TOT / 64, 256, 0, stream>>>(hb, aff, c_w2, c_b2, eps_gate, lamw, lamOut, presPart);
  k_graph_reg<<<B_GR / 4, 256, 0, stream>>>(features, noise, lamw, offp, q1w, c1w, sh2w, rtgw,
                                            noisyFB, qstarw, klpw);
  k_linear<128, 256, true><<<dim3(B_GR / 64, 4), 256, 0, stream>>>(qstarw, pw1T, p_b1, z1w);
  k_linear<256, 128, true><<<dim3(B_GR / 64, 2), 256, 0, stream>>>(z1w, pw2T, p_b2, z2w);
  k_linear<128, 64, false><<<dim3(B_GR / 64, 1), 256, 0, stream>>>(z2w, pw3T, p_b3, out);
  k_final<<<1, 256, 0, stream>>>(klpw, presPart, out);
}

// Round 12
// 317.550 us; speedup vs baseline: 2.3611x; 1.0526x over previous
//
#include <hip/hip_runtime.h>
#include <math.h>

#define N_TOT 524288
#define B_GR  16384
#define CAPR  64

#define LOG2E 1.44269504088896f
#define LN2   0.69314718055995f

// ---------------- small device helpers ----------------
__device__ __forceinline__ float fexp2(float x) { return __builtin_amdgcn_exp2f(x); }
__device__ __forceinline__ float flog2(float x) { return __builtin_amdgcn_logf(x); }
__device__ __forceinline__ float frcp(float x)  { return __builtin_amdgcn_rcpf(x); }
__device__ __forceinline__ float sigf(float x)  { return frcp(1.0f + fexp2(-x * LOG2E)); }

// bf16 pack/unpack (RNE)
__device__ __forceinline__ unsigned int f2bf(float x) {
  unsigned int u = __float_as_uint(x);
  return (u + 0x7FFFu + ((u >> 16) & 1u)) >> 16;
}
__device__ __forceinline__ float bf2f(unsigned int s) {
  return __uint_as_float(s << 16);
}

// ---- DPP-based 64-lane sum: 6 VALU dpp-adds + readlane broadcast.
// Replaces ds_bpermute shuffle chains (~30cy DS ops) with ~2cy VALU ops.
template <int CTRL>
__device__ __forceinline__ float dppadd(float v) {
  return v + __int_as_float(__builtin_amdgcn_update_dpp(
      0, __float_as_int(v), CTRL, 0xF, 0xF, true));
}
__device__ __forceinline__ float wave_red(float v) {
  v = dppadd<0x111>(v);   // row_shr:1
  v = dppadd<0x112>(v);   // row_shr:2
  v = dppadd<0x114>(v);   // row_shr:4
  v = dppadd<0x118>(v);   // row_shr:8   -> lane15 of each row has row sum
  v = dppadd<0x142>(v);   // row_bcast15 -> lane31 has 0-31, lane63 has 32-63
  v = dppadd<0x143>(v);   // row_bcast31 -> lane63 has full sum
  return __int_as_float(__builtin_amdgcn_readlane(__float_as_int(v), 63));
}

// legacy shuffle reduce (kept for small 4-lane combines in k_gate_h)
__device__ __forceinline__ float wave_sum(float v) {
#pragma unroll
  for (int o = 32; o > 0; o >>= 1) v += __shfl_xor(v, o);
  return v;
}

// ---------------- 64x64 f32 register-tiled GEMM pieces ----------------
__device__ __forceinline__ void load_A64(const float* __restrict__ A, size_t lda, int n0, int k0,
                                         float (*As)[68], int tid) {
#pragma unroll
  for (int s = 0; s < 4; s++) {
    int e4 = tid * 4 + s * 1024;
    int r = e4 >> 6, k = e4 & 63;
    *(float4*)&As[r][k] = *(const float4*)&A[(size_t)(n0 + r) * lda + k0 + k];
  }
}
__device__ __forceinline__ void mm64(const float (*As)[68], const float (*Wt)[68],
                                     int ty, int tx, float acc[4][4]) {
#pragma unroll
  for (int k4 = 0; k4 < 64; k4 += 4) {
    float4 b0 = *(const float4*)&Wt[k4 + 0][tx * 4];
    float4 b1 = *(const float4*)&Wt[k4 + 1][tx * 4];
    float4 b2 = *(const float4*)&Wt[k4 + 2][tx * 4];
    float4 b3 = *(const float4*)&Wt[k4 + 3][tx * 4];
#pragma unroll
    for (int i = 0; i < 4; i++) {
      float4 a = *(const float4*)&As[ty * 4 + i][k4];
      acc[i][0] = fmaf(a.w, b3.x, fmaf(a.z, b2.x, fmaf(a.y, b1.x, fmaf(a.x, b0.x, acc[i][0]))));
      acc[i][1] = fmaf(a.w, b3.y, fmaf(a.z, b2.y, fmaf(a.y, b1.y, fmaf(a.x, b0.y, acc[i][1]))));
      acc[i][2] = fmaf(a.w, b3.z, fmaf(a.z, b2.z, fmaf(a.y, b1.z, fmaf(a.x, b0.z, acc[i][2]))));
      acc[i][3] = fmaf(a.w, b3.w, fmaf(a.z, b2.w, fmaf(a.y, b1.w, fmaf(a.x, b0.w, acc[i][3]))));
    }
  }
}

// ---------------- K0a: graph offsets via binary search (batch_index is sorted) ----------------
__global__ void k_offsets(const int* __restrict__ idx, int* __restrict__ off) {
  int b = blockIdx.x * blockDim.x + threadIdx.x;
  if (b > B_GR) return;
  if (b == B_GR) { off[B_GR] = N_TOT; return; }
  int lo = 0, hi = N_TOT;
  while (lo < hi) { int mid = (lo + hi) >> 1; if (idx[mid] < b) lo = mid + 1; else hi = mid; }
  off[b] = lo;
}

// ---------------- K0b: pre-transpose weights; build RTg[k][d][j] for fused LSTM2 ----------------
__global__ void k_prep(const float* __restrict__ w1, const float* __restrict__ pw1,
                       const float* __restrict__ pw2, const float* __restrict__ pw3,
                       const float* __restrict__ wih,
                       float* __restrict__ w1T, float* __restrict__ pw1T,
                       float* __restrict__ pw2T, float* __restrict__ pw3T,
                       float* __restrict__ rtg) {
  int t = blockIdx.x * 256 + threadIdx.x;          // 64 blocks * 256 = 16384 threads
  for (int i = t; i < 64 * 64; i += 16384)  { int r = i >> 6, c = i & 63;  w1T[c * 64 + r]   = w1[i]; }
  for (int i = t; i < 256 * 128; i += 16384){ int r = i >> 7, c = i & 127; pw1T[c * 256 + r] = pw1[i]; }
  for (int i = t; i < 128 * 256; i += 16384){ int r = i >> 8, c = i & 255; pw2T[c * 128 + r] = pw2[i]; }
  for (int i = t; i < 64 * 128; i += 16384) { int r = i >> 7, c = i & 127; pw3T[c * 64 + r]  = pw3[i]; }
  // RTg[((k*64)+d)*4 + j] = Wih[j*64+d][64+k]  (j = gate index i,f,g,o)
  for (int i = t; i < 64 * 64 * 4; i += 16384) {
    int k = i >> 8, rem = i & 255, d = rem >> 2, j = rem & 3;
    rtg[i] = wih[(size_t)(j * 64 + d) * 128 + 64 + k];
  }
}

// ---------------- K1: h = X@W1^T + b1 -> STORE h as bf16; stats partials (f32-exact) ----------------
__global__ __launch_bounds__(256) void k_bn_stats(const float* __restrict__ X, const float* __restrict__ W1T,
                                                  const float* __restrict__ b1, unsigned short* __restrict__ h,
                                                  float* __restrict__ pSum, float* __restrict__ pSq) {
  __shared__ float As[64][68];
  __shared__ float Wt[64][68];
  int tid = threadIdx.x, ty = tid >> 4, tx = tid & 15;
  int n0 = blockIdx.x * 64;
  float acc[4][4] = {};
  load_A64(X, 64, n0, 0, As, tid);
  load_A64(W1T, 64, 0, 0, Wt, tid);
  __syncthreads();
  mm64(As, Wt, ty, tx, acc);
  float4 bv = *(const float4*)&b1[tx * 4];
  float cs[4] = {0, 0, 0, 0}, cq[4] = {0, 0, 0, 0};
#pragma unroll
  for (int i = 0; i < 4; i++) {
    float h0 = acc[i][0] + bv.x, h1 = acc[i][1] + bv.y;
    float h2 = acc[i][2] + bv.z, h3 = acc[i][3] + bv.w;
    ushort4 hb;
    hb.x = (unsigned short)f2bf(h0); hb.y = (unsigned short)f2bf(h1);
    hb.z = (unsigned short)f2bf(h2); hb.w = (unsigned short)f2bf(h3);
    *(ushort4*)&h[(size_t)(n0 + ty * 4 + i) * 64 + tx * 4] = hb;
    cs[0] += h0; cq[0] = fmaf(h0, h0, cq[0]);
    cs[1] += h1; cq[1] = fmaf(h1, h1, cq[1]);
    cs[2] += h2; cq[2] = fmaf(h2, h2, cq[2]);
    cs[3] += h3; cq[3] = fmaf(h3, h3, cq[3]);
  }
  __syncthreads();
  float* red = &As[0][0];
#pragma unroll
  for (int j = 0; j < 4; j++) {
    red[ty * 64 + tx * 4 + j] = cs[j];
    red[1024 + ty * 64 + tx * 4 + j] = cq[j];
  }
  __syncthreads();
  if (tid < 64) {
    float s = 0, q = 0;
#pragma unroll
    for (int t = 0; t < 16; t++) { s += red[t * 64 + tid]; q += red[1024 + t * 64 + tid]; }
    pSum[(size_t)blockIdx.x * 64 + tid] = s;
    pSq[(size_t)blockIdx.x * 64 + tid] = q;
  }
}

// ---------------- K2a: finalize BN -> affine aff[0:64]=A, aff[64:128]=C ----------------
__global__ __launch_bounds__(256) void k_bn_final(const float* __restrict__ pSum, const float* __restrict__ pSq,
                                                  const float* __restrict__ bn_g, const float* __restrict__ bn_b,
                                                  float* __restrict__ aff) {
  int c = blockIdx.x;
  float s = 0, q = 0;
  for (int i = threadIdx.x; i < 8192; i += 256) {
    s += pSum[(size_t)i * 64 + c];
    q += pSq[(size_t)i * 64 + c];
  }
  __shared__ float rs[256], rq[256];
  rs[threadIdx.x] = s; rq[threadIdx.x] = q;
  __syncthreads();
  for (int st = 128; st > 0; st >>= 1) {
    if (threadIdx.x < st) { rs[threadIdx.x] += rs[threadIdx.x + st]; rq[threadIdx.x] += rq[threadIdx.x + st]; }
    __syncthreads();
  }
  if (threadIdx.x == 0) {
    float mu = rs[0] / (float)N_TOT;
    float var = rq[0] / (float)N_TOT - mu * mu;
    var = fmaxf(var, 0.0f);
    float A = bn_g[c] * rsqrtf(var + 1e-5f);
    aff[c] = A;
    aff[64 + c] = bn_b[c] - mu * A;
  }
}

// ---------------- K2b: LSTM step1 from biases only; shared part of step-2 gates ----------------
__global__ __launch_bounds__(256) void k_lstm1(const float* __restrict__ bih, const float* __restrict__ bhh,
                                               const float* __restrict__ wih, const float* __restrict__ whh,
                                               float* __restrict__ q1, float* __restrict__ c1, float* __restrict__ sh2) {
  __shared__ float g1[256];
  __shared__ float q1s[64];
  int tid = threadIdx.x;
  g1[tid] = bih[tid] + bhh[tid];
  __syncthreads();
  if (tid < 64) {
    float ig = sigf(g1[tid]);
    float gg = tanhf(g1[128 + tid]);
    float cc = ig * gg;
    float og = sigf(g1[192 + tid]);
    float qv = og * tanhf(cc);
    q1s[tid] = qv; q1[tid] = qv; c1[tid] = cc;
  }
  __syncthreads();
  float acc = g1[tid];
  for (int k = 0; k < 64; k++)
    acc = fmaf(wih[(size_t)tid * 128 + k] + whh[(size_t)tid * 64 + k], q1s[k], acc);
  sh2[tid] = acc;
}

// ---------------- K3: streaming gate: bf16 h -> LDS f32 -> thread-per-row dot (no atomics) ----------------
__global__ __launch_bounds__(256) void k_gate_h(const unsigned short* __restrict__ h, const float* __restrict__ aff,
                                                const float* __restrict__ w2, const float* __restrict__ cb2,
                                                const float* __restrict__ eps_gate,
                                                float* __restrict__ lamWS, float* __restrict__ lamOut,
                                                int* __restrict__ presPart) {
  __shared__ float Hs[64][65];
  __shared__ float A2s[64], C2s[64], w2s[64];
  __shared__ int pcnt[4];
  int tid = threadIdx.x;
  if (tid < 64) { A2s[tid] = aff[tid]; C2s[tid] = aff[64 + tid]; w2s[tid] = w2[tid]; }
  int n0 = blockIdx.x * 64;
#pragma unroll
  for (int s = 0; s < 4; s++) {
    int e4 = tid * 4 + s * 1024;
    int r = e4 >> 6, c = e4 & 63;
    ushort4 v = *(const ushort4*)&h[(size_t)(n0 + r) * 64 + c];
    Hs[r][c] = bf2f(v.x); Hs[r][c + 1] = bf2f(v.y);
    Hs[r][c + 2] = bf2f(v.z); Hs[r][c + 3] = bf2f(v.w);
  }
  __syncthreads();
  int r = tid >> 2, q = tid & 3;
  float p = 0.f;
#pragma unroll
  for (int j = 0; j < 16; j++) {
    int d = q * 16 + j;
    p = fmaf(fmaxf(fmaf(Hs[r][d], A2s[d], C2s[d]), 0.f), w2s[d], p);
  }
  p += __shfl_xor(p, 1);
  p += __shfl_xor(p, 2);
  p += cb2[0];
  unsigned long long m = __ballot(q == 0 && p > 0.0f);
  if ((tid & 63) == 0) pcnt[tid >> 6] = (int)__popcll(m);
  if (q == 0) {
    int row = n0 + r;
    float eg = eps_gate[row];
    float eps = 0.9999f - 0.9998f * eg;
    float gi = (flog2(eps) - flog2(1.0f - eps)) * LN2;
    float lam = sigf(gi + p);
    lamWS[row] = lam;
    lamOut[row] = lam;
  }
  __syncthreads();
  if (tid == 0) presPart[blockIdx.x] = pcnt[0] + pcnt[1] + pcnt[2] + pcnt[3];
}

// ---------------- K4: register-resident wave-per-graph pipeline with DPP reductions ----------------
__global__ __launch_bounds__(256) void k_graph_reg(const float* __restrict__ X, const float* __restrict__ noise,
                                                   const float* __restrict__ lam, const int* __restrict__ off,
                                                   const float* __restrict__ q1g, const float* __restrict__ c1g,
                                                   const float* __restrict__ sh2g, const float* __restrict__ rtg,
                                                   unsigned short* __restrict__ noisyFB, float* __restrict__ qstar,
                                                   float* __restrict__ klp) {
  int wg = blockIdx.x * 4 + (threadIdx.x >> 6);
  int lane = threadIdx.x & 63;
  int n0 = off[wg], cnt = off[wg + 1] - n0;
  const float THR = 8.f;
  const float* xp = X + (size_t)n0 * 64 + lane;
  const float* zp = noise + (size_t)n0 * 64 + lane;
  float r1v = 0.f;
  bool fits = (cnt <= CAPR);
  unsigned int pk[CAPR / 2];   // packed bf16 pairs: X in pass1, overwritten with noisy in pass2

  if (cnt > 0 && fits) {
    // ---- pass 1: stream X (f32-exact stats), stash bf16 X into regs ----
    float s0 = 0.f, q0 = 0.f, s1 = 0.f, q1_ = 0.f;
#pragma unroll
    for (int np = 0; np < CAPR / 2; np++) {
      int n = 2 * np;
      if (n < cnt) {
        float a = xp[(size_t)n * 64];
        s0 += a; q0 = fmaf(a, a, q0);
        float b = 0.f;
        if (n + 1 < cnt) {
          b = xp[(size_t)(n + 1) * 64];
          s1 += b; q1_ = fmaf(b, b, q1_);
        }
        pk[np] = (f2bf(b) << 16) | f2bf(a);
      }
    }
    float c = (float)cnt;
    float mean = (s0 + s1) / c;
    float var = fmaxf(((q0 + q1_) - c * mean * mean) / fmaxf(c - 1.f, 1.f), 0.f);
    float sd = sqrtf(var);
    float inv = frcp(sd + 1e-7f);
    float S1 = wave_red(sd * sd * inv * inv);
    // ---- pass 2: noise+lam -> noisy (bf16 into SAME regs), KL, attn1 (DPP reductions) ----
    float q1v2 = q1g[lane] * LOG2E;
    float t2acc = 0.f, sumOm2 = 0.f;
    float m0 = -INFINITY, l0 = 0.f, r0 = 0.f;
    float m1 = -INFINITY, l1 = 0.f, r1a = 0.f;
#pragma unroll
    for (int np = 0; np < CAPR / 2; np++) {
      int n = 2 * np;
      if (n < cnt) {
        bool hasB = (n + 1 < cnt);
        unsigned int p2 = pk[np];
        float xA = bf2f(p2 & 0xffffu), xB = bf2f(p2 >> 16);
        float lamA = lam[n0 + n];
        float zA = zp[(size_t)n * 64];
        float lamB = hasB ? lam[n0 + n + 1] : 0.f;
        float zB = hasB ? zp[(size_t)(n + 1) * 64] : 0.f;
        float omA = 1.f - lamA, omB = 1.f - lamB;
        float nvA = fmaf(lamA, xA, omA * mean) + zA * (omA * sd);
        float nvB = fmaf(lamB, xB, omB * mean) + zB * (omB * sd);
        pk[np] = (f2bf(nvB) << 16) | f2bf(nvA);
        float ldA = lamA * (xA - mean) * inv; t2acc = fmaf(ldA, ldA, t2acc);
        sumOm2 = fmaf(omA, omA, sumOm2);
        if (hasB) {
          float ldB = lamB * (xB - mean) * inv; t2acc = fmaf(ldB, ldB, t2acc);
          sumOm2 = fmaf(omB, omB, sumOm2);
        }
        float e0 = wave_red(nvA * q1v2);
        float e1 = hasB ? wave_red(nvB * q1v2) : 0.f;
        if (e0 > m0 + THR) { float sc = fexp2(m0 - e0); l0 *= sc; r0 *= sc; m0 = e0; }
        float pA = fexp2(e0 - m0); l0 += pA; r0 = fmaf(pA, nvA, r0);
        if (hasB) {
          if (e1 > m1 + THR) { float sc = fexp2(m1 - e1); l1 *= sc; r1a *= sc; m1 = e1; }
          float pB = fexp2(e1 - m1); l1 += pB; r1a = fmaf(pB, nvB, r1a);
        }
      }
    }
    float M = fmaxf(m0, m1);
    float sc0 = fexp2(m0 - M), sc1 = (m1 == -INFINITY) ? 0.f : fexp2(m1 - M);
    float L = l0 * sc0 + l1 * sc1;
    float R = r0 * sc0 + r1a * sc1;
    r1v = R / L;
    float t2tot = wave_red(t2acc);
    if (lane == 0) klp[wg] = fmaf(0.5f * sumOm2, S1, t2tot);
  } else if (cnt > 0) {
    // ---- fallback (cnt > CAPR): global-memory path, bf16 noisy to noisyFB ----
    unsigned short* nw = noisyFB + (size_t)n0 * 64 + lane;
    float s0 = 0.f, q0 = 0.f;
    for (int n = 0; n < cnt; n++) { float a = xp[(size_t)n * 64]; s0 += a; q0 = fmaf(a, a, q0); }
    float c = (float)cnt;
    float mean = s0 / c;
    float var = fmaxf((q0 - c * mean * mean) / fmaxf(c - 1.f, 1.f), 0.f);
    float sd = sqrtf(var);
    float inv = frcp(sd + 1e-7f);
    float S1 = wave_red(sd * sd * inv * inv);
    float q1v2 = q1g[lane] * LOG2E;
    float t2acc = 0.f, sumOm2 = 0.f;
    float m0 = -INFINITY, l0 = 0.f, r0 = 0.f;
    for (int n = 0; n < cnt; n++) {
      float lamA = lam[n0 + n];
      float xA = xp[(size_t)n * 64];
      float zA = zp[(size_t)n * 64];
      float omA = 1.f - lamA;
      float nvA = fmaf(lamA, xA, omA * mean) + zA * (omA * sd);
      nw[(size_t)n * 64] = (unsigned short)f2bf(nvA);
      float ldA = lamA * (xA - mean) * inv; t2acc = fmaf(ldA, ldA, t2acc);
      sumOm2 = fmaf(omA, omA, sumOm2);
      float e0 = wave_red(nvA * q1v2);
      if (e0 > m0 + THR) { float sc = fexp2(m0 - e0); l0 *= sc; r0 *= sc; m0 = e0; }
      float pA = fexp2(e0 - m0); l0 += pA; r0 = fmaf(pA, nvA, r0);
    }
    r1v = r0 / l0;
    float t2tot = wave_red(t2acc);
    if (lane == 0) klp[wg] = fmaf(0.5f * sumOm2, S1, t2tot);
  } else {
    if (lane == 0) klp[wg] = 0.0f;
  }

  // ---- fused LSTM step 2: gates = sh2 + r1 @ R^T via RTg[k][d][4] (L2-resident) ----
  float a0 = 0.f, a1 = 0.f, a2 = 0.f, a3 = 0.f;
  const float4* rt = (const float4*)rtg;
#pragma unroll 4
  for (int k = 0; k < 64; k++) {
    float rk = __shfl(r1v, k);
    float4 w = rt[k * 64 + lane];
    a0 = fmaf(w.x, rk, a0); a1 = fmaf(w.y, rk, a1);
    a2 = fmaf(w.z, rk, a2); a3 = fmaf(w.w, rk, a3);
  }
  float ig = a0 + sh2g[lane];
  float fg = a1 + sh2g[64 + lane];
  float gg = a2 + sh2g[128 + lane];
  float og = a3 + sh2g[192 + lane];
  float c2 = sigf(fg) * c1g[lane] + sigf(ig) * tanhf(gg);
  float q2 = sigf(og) * tanhf(c2);
  qstar[(size_t)wg * 128 + lane] = q2;

  // ---- fused attention step 2: noisy straight from registers (DPP reductions) ----
  float r2v = 0.f;
  if (cnt > 0) {
    float q2v2 = q2 * LOG2E;
    float m0 = -INFINITY, l0 = 0.f, r0 = 0.f;
    float m1 = -INFINITY, l1 = 0.f, r1a = 0.f;
    if (fits) {
#pragma unroll
      for (int np = 0; np < CAPR / 2; np++) {
        int n = 2 * np;
        if (n < cnt) {
          bool hasB = (n + 1 < cnt);
          unsigned int p2 = pk[np];
          float nvA = bf2f(p2 & 0xffffu), nvB = bf2f(p2 >> 16);
          float e0 = wave_red(nvA * q2v2);
          float e1 = hasB ? wave_red(nvB * q2v2) : 0.f;
          if (e0 > m0 + THR) { float sc = fexp2(m0 - e0); l0 *= sc; r0 *= sc; m0 = e0; }
          float pA = fexp2(e0 - m0); l0 += pA; r0 = fmaf(pA, nvA, r0);
          if (hasB) {
            if (e1 > m1 + THR) { float sc = fexp2(m1 - e1); l1 *= sc; r1a *= sc; m1 = e1; }
            float pB = fexp2(e1 - m1); l1 += pB; r1a = fmaf(pB, nvB, r1a);
          }
        }
      }
    } else {
      const unsigned short* np_ = noisyFB + (size_t)n0 * 64 + lane;
      for (int n = 0; n < cnt; n++) {
        float nvA = bf2f(np_[(size_t)n * 64]);
        float e0 = wave_red(nvA * q2v2);
        if (e0 > m0 + THR) { float sc = fexp2(m0 - e0); l0 *= sc; r0 *= sc; m0 = e0; }
        float pA = fexp2(e0 - m0); l0 += pA; r0 = fmaf(pA, nvA, r0);
      }
    }
    float M = fmaxf(m0, m1);
    float sc0 = fexp2(m0 - M), sc1 = (m1 == -INFINITY) ? 0.f : fexp2(m1 - M);
    float L = l0 * sc0 + l1 * sc1;
    float R = r0 * sc0 + r1a * sc1;
    r2v = R / L;
  }
  qstar[(size_t)wg * 128 + 64 + lane] = r2v;
}

// ---------------- K7/8/9: predictor linear layers (pre-transposed weights) ----------------
template <int KDIM, int ODIM, bool RELU>
__global__ __launch_bounds__(256) void k_linear(const float* __restrict__ A, const float* __restrict__ WT,
                                                const float* __restrict__ bias, float* __restrict__ C) {
  __shared__ float As[64][68];
  __shared__ float Wt[64][68];
  int tid = threadIdx.x, ty = tid >> 4, tx = tid & 15;
  int n0 = blockIdx.x * 64, c0 = blockIdx.y * 64;
  float acc[4][4] = {};
  for (int kt = 0; kt < KDIM; kt += 64) {
    __syncthreads();
    load_A64(A, KDIM, n0, kt, As, tid);
    load_A64(WT, ODIM, kt, c0, Wt, tid);   // WT is [KDIM][ODIM] row-major
    __syncthreads();
    mm64(As, Wt, ty, tx, acc);
  }
#pragma unroll
  for (int i = 0; i < 4; i++) {
    int row = n0 + ty * 4 + i;
    float4 o;
    float v0 = acc[i][0] + bias[c0 + tx * 4 + 0];
    float v1 = acc[i][1] + bias[c0 + tx * 4 + 1];
    float v2 = acc[i][2] + bias[c0 + tx * 4 + 2];
    float v3 = acc[i][3] + bias[c0 + tx * 4 + 3];
    if (RELU) { v0 = fmaxf(v0, 0.f); v1 = fmaxf(v1, 0.f); v2 = fmaxf(v2, 0.f); v3 = fmaxf(v3, 0.f); }
    o.x = v0; o.y = v1; o.z = v2; o.w = v3;
    *(float4*)&C[(size_t)row * ODIM + c0 + tx * 4] = o;
  }
}

// ---------------- K10: final scalars ----------------
__global__ __launch_bounds__(256) void k_final(const float* __restrict__ klp, const int* __restrict__ presPart,
                                               float* __restrict__ out) {
  __shared__ float red[256];
  __shared__ int redi[256];
  float s = 0.0f;
  int pc = 0;
  for (int i = threadIdx.x; i < B_GR; i += 256) s += klp[i];
  for (int i = threadIdx.x; i < 8192; i += 256) pc += presPart[i];
  red[threadIdx.x] = s;
  redi[threadIdx.x] = pc;
  __syncthreads();
  for (int st = 128; st > 0; st >>= 1) {
    if (threadIdx.x < st) {
      red[threadIdx.x] += red[threadIdx.x + st];
      redi[threadIdx.x] += redi[threadIdx.x + st];
    }
    __syncthreads();
  }
  if (threadIdx.x == 0) {
    out[(size_t)B_GR * 64] = red[0] / (float)(B_GR * 64);
    out[(size_t)B_GR * 64 + 1] = (float)redi[0] / (float)N_TOT;
  }
}

// ---------------- launcher ----------------
extern "C" void kernel_launch(void* const* d_in, const int* in_sizes, int n_in,
                              void* d_out, int out_size, void* d_ws, size_t ws_size,
                              hipStream_t stream) {
  const float* features = (const float*)d_in[0];
  const int*   bidx     = (const int*)d_in[1];
  const float* eps_gate = (const float*)d_in[2];
  const float* noise    = (const float*)d_in[3];
  const float* c_w1 = (const float*)d_in[4];
  const float* c_b1 = (const float*)d_in[5];
  const float* bn_g = (const float*)d_in[6];
  const float* bn_b = (const float*)d_in[7];
  const float* c_w2 = (const float*)d_in[8];
  const float* c_b2 = (const float*)d_in[9];
  const float* wih  = (const float*)d_in[10];
  const float* whh  = (const float*)d_in[11];
  const float* bih  = (const float*)d_in[12];
  const float* bhh  = (const float*)d_in[13];
  const float* p_w1 = (const float*)d_in[14];
  const float* p_b1 = (const float*)d_in[15];
  const float* p_w2 = (const float*)d_in[16];
  const float* p_b2 = (const float*)d_in[17];
  const float* p_w3 = (const float*)d_in[18];
  const float* p_b3 = (const float*)d_in[19];
  float* out = (float*)d_out;

  float* wsf   = (float*)d_ws;
  int*   offp  = (int*)wsf;                                 // (B+1) ints
  float* pSum  = wsf + 16448;                               // 8192*64
  float* pSq   = pSum + 524288;                             // 8192*64
  float* aff   = pSq + 524288;                              // 128
  float* q1w   = aff + 128;                                 // 64
  float* c1w   = q1w + 64;                                  // 64
  float* sh2w  = c1w + 64;                                  // 256
  float* lamw  = sh2w + 256;                                // N
  float* cw1T  = lamw + (size_t)N_TOT;                      // 64*64
  float* pw1T  = cw1T + 4096;                               // 128*256
  float* pw2T  = pw1T + 32768;                              // 256*128
  float* pw3T  = pw2T + 32768;                              // 128*64
  float* rtgw  = pw3T + 8192;                               // 64*256 (RTg)
  float* hwf   = rtgw + 16384;                              // N*64 float-sized region
  unsigned short* hb = (unsigned short*)hwf;                // h as bf16; later reused as noisy fallback
  unsigned short* noisyFB = hb;                             // fallback noisy (h dead after k_gate_h)
  float* qstarw = hwf + (size_t)N_TOT * 64;                 // B*128
  float* z1w    = qstarw + (size_t)B_GR * 128;              // B*256
  float* z2w    = z1w + (size_t)B_GR * 256;                 // B*128
  float* klpw   = z2w + (size_t)B_GR * 128;                 // B
  int*   presPart = (int*)(klpw + B_GR);                    // 8192 ints

  float* lamOut = out + (size_t)B_GR * 64 + 2;

  k_offsets<<<(B_GR + 1 + 255) / 256, 256, 0, stream>>>(bidx, offp);
  k_prep<<<64, 256, 0, stream>>>(c_w1, p_w1, p_w2, p_w3, wih, cw1T, pw1T, pw2T, pw3T, rtgw);
  k_bn_stats<<<N_TOT / 64, 256, 0, stream>>>(features, cw1T, c_b1, hb, pSum, pSq);
  k_bn_final<<<64, 256, 0, stream>>>(pSum, pSq, bn_g, bn_b, aff);
  k_lstm1<<<1, 256, 0, stream>>>(bih, bhh, wih, whh, q1w, c1w, sh2w);
  k_gate_h<<<N_TOT / 64, 256, 0, stream>>>(hb, aff, c_w2, c_b2, eps_gate, lamw, lamOut, presPart);
  k_graph_reg<<<B_GR / 4, 256, 0, stream>>>(features, noise, lamw, offp, q1w, c1w, sh2w, rtgw,
                                            noisyFB, qstarw, klpw);
  k_linear<128, 256, true><<<dim3(B_GR / 64, 4), 256, 0, stream>>>(qstarw, pw1T, p_b1, z1w);
  k_linear<256, 128, true><<<dim3(B_GR / 64, 2), 256, 0, stream>>>(z1w, pw2T, p_b2, z2w);
  k_linear<128, 64, false><<<dim3(B_GR / 64, 1), 256, 0, stream>>>(z2w, pw3T, p_b3, out);
  k_final<<<1, 256, 0, stream>>>(klpw, presPart, out);
}

// Round 13
// 292.142 us; speedup vs baseline: 2.5665x; 1.0870x over previous
//
#include <hip/hip_runtime.h>
#include <math.h>

#define N_TOT 524288
#define B_GR  16384
#define CAPR  64

#define LOG2E 1.44269504088896f
#define LN2   0.69314718055995f

typedef __attribute__((ext_vector_type(8))) short bf16x8;
typedef __attribute__((ext_vector_type(4))) float f32x4;

// ---------------- small device helpers ----------------
__device__ __forceinline__ float fexp2(float x) { return __builtin_amdgcn_exp2f(x); }
__device__ __forceinline__ float flog2(float x) { return __builtin_amdgcn_logf(x); }
__device__ __forceinline__ float frcp(float x)  { return __builtin_amdgcn_rcpf(x); }
__device__ __forceinline__ float sigf(float x)  { return frcp(1.0f + fexp2(-x * LOG2E)); }

// bf16 pack/unpack (RNE)
__device__ __forceinline__ unsigned int f2bf(float x) {
  unsigned int u = __float_as_uint(x);
  return (u + 0x7FFFu + ((u >> 16) & 1u)) >> 16;
}
__device__ __forceinline__ float bf2f(unsigned int s) {
  return __uint_as_float(s << 16);
}

// ---- DPP-based 64-lane sum ----
template <int CTRL>
__device__ __forceinline__ float dppadd(float v) {
  return v + __int_as_float(__builtin_amdgcn_update_dpp(
      0, __float_as_int(v), CTRL, 0xF, 0xF, true));
}
__device__ __forceinline__ float wave_red(float v) {
  v = dppadd<0x111>(v);   // row_shr:1
  v = dppadd<0x112>(v);   // row_shr:2
  v = dppadd<0x114>(v);   // row_shr:4
  v = dppadd<0x118>(v);   // row_shr:8
  v = dppadd<0x142>(v);   // row_bcast15
  v = dppadd<0x143>(v);   // row_bcast31
  return __int_as_float(__builtin_amdgcn_readlane(__float_as_int(v), 63));
}

// ---------------- 64x64 f32 register-tiled GEMM pieces (still used by k_linear) ----------------
__device__ __forceinline__ void load_A64(const float* __restrict__ A, size_t lda, int n0, int k0,
                                         float (*As)[68], int tid) {
#pragma unroll
  for (int s = 0; s < 4; s++) {
    int e4 = tid * 4 + s * 1024;
    int r = e4 >> 6, k = e4 & 63;
    *(float4*)&As[r][k] = *(const float4*)&A[(size_t)(n0 + r) * lda + k0 + k];
  }
}
__device__ __forceinline__ void mm64(const float (*As)[68], const float (*Wt)[68],
                                     int ty, int tx, float acc[4][4]) {
#pragma unroll
  for (int k4 = 0; k4 < 64; k4 += 4) {
    float4 b0 = *(const float4*)&Wt[k4 + 0][tx * 4];
    float4 b1 = *(const float4*)&Wt[k4 + 1][tx * 4];
    float4 b2 = *(const float4*)&Wt[k4 + 2][tx * 4];
    float4 b3 = *(const float4*)&Wt[k4 + 3][tx * 4];
#pragma unroll
    for (int i = 0; i < 4; i++) {
      float4 a = *(const float4*)&As[ty * 4 + i][k4];
      acc[i][0] = fmaf(a.w, b3.x, fmaf(a.z, b2.x, fmaf(a.y, b1.x, fmaf(a.x, b0.x, acc[i][0]))));
      acc[i][1] = fmaf(a.w, b3.y, fmaf(a.z, b2.y, fmaf(a.y, b1.y, fmaf(a.x, b0.y, acc[i][1]))));
      acc[i][2] = fmaf(a.w, b3.z, fmaf(a.z, b2.z, fmaf(a.y, b1.z, fmaf(a.x, b0.z, acc[i][2]))));
      acc[i][3] = fmaf(a.w, b3.w, fmaf(a.z, b2.w, fmaf(a.y, b1.w, fmaf(a.x, b0.w, acc[i][3]))));
    }
  }
}

// ---------------- K0a: graph offsets via binary search (batch_index is sorted) ----------------
__global__ void k_offsets(const int* __restrict__ idx, int* __restrict__ off) {
  int b = blockIdx.x * blockDim.x + threadIdx.x;
  if (b > B_GR) return;
  if (b == B_GR) { off[B_GR] = N_TOT; return; }
  int lo = 0, hi = N_TOT;
  while (lo < hi) { int mid = (lo + hi) >> 1; if (idx[mid] < b) lo = mid + 1; else hi = mid; }
  off[b] = lo;
}

// ---------------- K0b: pre-transpose weights; RTg for fused LSTM2; bf16 B-fragments for MFMA ----------------
__global__ void k_prep(const float* __restrict__ w1, const float* __restrict__ pw1,
                       const float* __restrict__ pw2, const float* __restrict__ pw3,
                       const float* __restrict__ wih,
                       float* __restrict__ pw1T, float* __restrict__ pw2T,
                       float* __restrict__ pw3T, float* __restrict__ rtg,
                       unsigned short* __restrict__ wfragb) {
  int t = blockIdx.x * 256 + threadIdx.x;          // 64 blocks * 256 = 16384 threads
  for (int i = t; i < 256 * 128; i += 16384){ int r = i >> 7, c = i & 127; pw1T[c * 256 + r] = pw1[i]; }
  for (int i = t; i < 128 * 256; i += 16384){ int r = i >> 8, c = i & 255; pw2T[c * 128 + r] = pw2[i]; }
  for (int i = t; i < 64 * 128; i += 16384) { int r = i >> 7, c = i & 127; pw3T[c * 64 + r]  = pw3[i]; }
  // RTg[((k*64)+d)*4 + j] = Wih[j*64+d][64+k]  (j = gate index i,f,g,o)
  for (int i = t; i < 64 * 64 * 4; i += 16384) {
    int k = i >> 8, rem = i & 255, d = rem >> 2, j = rem & 3;
    rtg[i] = wih[(size_t)(j * 64 + d) * 128 + 64 + k];
  }
  // B-fragments for v_mfma_f32_16x16x32_bf16: frag f=(ctile*2+kh), lane l, elem j:
  //   B[k][col] with k = kh*32 + (l>>4)*8 + j, col = ctile*16 + (l&15);  B[k][c] = w1[c][k].
  for (int i = t; i < 8 * 64 * 8; i += 16384) {
    int f = i >> 9, lane = (i >> 3) & 63, j = i & 7;
    int ct = f >> 1, kh = f & 1;
    int k = kh * 32 + (lane >> 4) * 8 + j;
    int col = ct * 16 + (lane & 15);
    wfragb[i] = (unsigned short)f2bf(w1[(size_t)col * 64 + k]);
  }
}

// ---------------- K1: MFMA h = X@W1^T + b1 -> bf16 h; per-block column stats partials ----------------
// A layout: row = lane&15, k = (lane>>4)*8 + j.  B: pre-packed wfragb.
// C/D layout (m89-verified): col = lane&15, row = (lane>>4)*4 + reg_idx.
__global__ __launch_bounds__(256) void k_bn_stats(const float* __restrict__ X,
                                                  const unsigned short* __restrict__ wfragb,
                                                  const float* __restrict__ b1, unsigned short* __restrict__ h,
                                                  float* __restrict__ pSum, float* __restrict__ pSq) {
  __shared__ float redS[16][64];
  __shared__ float redQ[16][64];
  int tid = threadIdx.x, w = tid >> 6, l = tid & 63;
  int n0 = blockIdx.x * 64;
  int r0 = w * 16;
  int arow = n0 + r0 + (l & 15);
  int kb = (l >> 4) * 8;
  const float* xr = X + (size_t)arow * 64 + kb;
  float4 a00 = *(const float4*)&xr[0];
  float4 a01 = *(const float4*)&xr[4];
  float4 a10 = *(const float4*)&xr[32];
  float4 a11 = *(const float4*)&xr[36];
  bf16x8 A0, A1;
  A0[0] = (short)f2bf(a00.x); A0[1] = (short)f2bf(a00.y); A0[2] = (short)f2bf(a00.z); A0[3] = (short)f2bf(a00.w);
  A0[4] = (short)f2bf(a01.x); A0[5] = (short)f2bf(a01.y); A0[6] = (short)f2bf(a01.z); A0[7] = (short)f2bf(a01.w);
  A1[0] = (short)f2bf(a10.x); A1[1] = (short)f2bf(a10.y); A1[2] = (short)f2bf(a10.z); A1[3] = (short)f2bf(a10.w);
  A1[4] = (short)f2bf(a11.x); A1[5] = (short)f2bf(a11.y); A1[6] = (short)f2bf(a11.z); A1[7] = (short)f2bf(a11.w);
  const bf16x8* wf = (const bf16x8*)wfragb;
  f32x4 acc0 = {0.f, 0.f, 0.f, 0.f}, acc1 = acc0, acc2 = acc0, acc3 = acc0;
  {
    bf16x8 B00 = wf[0 * 64 + l], B01 = wf[1 * 64 + l];
    bf16x8 B10 = wf[2 * 64 + l], B11 = wf[3 * 64 + l];
    bf16x8 B20 = wf[4 * 64 + l], B21 = wf[5 * 64 + l];
    bf16x8 B30 = wf[6 * 64 + l], B31 = wf[7 * 64 + l];
    acc0 = __builtin_amdgcn_mfma_f32_16x16x32_bf16(A0, B00, acc0, 0, 0, 0);
    acc0 = __builtin_amdgcn_mfma_f32_16x16x32_bf16(A1, B01, acc0, 0, 0, 0);
    acc1 = __builtin_amdgcn_mfma_f32_16x16x32_bf16(A0, B10, acc1, 0, 0, 0);
    acc1 = __builtin_amdgcn_mfma_f32_16x16x32_bf16(A1, B11, acc1, 0, 0, 0);
    acc2 = __builtin_amdgcn_mfma_f32_16x16x32_bf16(A0, B20, acc2, 0, 0, 0);
    acc2 = __builtin_amdgcn_mfma_f32_16x16x32_bf16(A1, B21, acc2, 0, 0, 0);
    acc3 = __builtin_amdgcn_mfma_f32_16x16x32_bf16(A0, B30, acc3, 0, 0, 0);
    acc3 = __builtin_amdgcn_mfma_f32_16x16x32_bf16(A1, B31, acc3, 0, 0, 0);
  }
  int c16 = l & 15, rgrp = l >> 4;
  int slot = w * 4 + rgrp;
#pragma unroll
  for (int ct = 0; ct < 4; ct++) {
    f32x4 acc = (ct == 0) ? acc0 : (ct == 1) ? acc1 : (ct == 2) ? acc2 : acc3;
    int col = ct * 16 + c16;
    float bb = b1[col];
    float cs = 0.f, cq = 0.f;
#pragma unroll
    for (int j = 0; j < 4; j++) {
      float hv = acc[j] + bb;
      int row = n0 + r0 + rgrp * 4 + j;
      h[(size_t)row * 64 + col] = (unsigned short)f2bf(hv);
      cs += hv; cq = fmaf(hv, hv, cq);
    }
    redS[slot][col] = cs;
    redQ[slot][col] = cq;
  }
  __syncthreads();
  if (tid < 64) {
    float s = 0.f, q = 0.f;
#pragma unroll
    for (int t = 0; t < 16; t++) { s += redS[t][tid]; q += redQ[t][tid]; }
    pSum[(size_t)blockIdx.x * 64 + tid] = s;
    pSq[(size_t)blockIdx.x * 64 + tid] = q;
  }
}

// ---------------- K2a: finalize BN -> affine aff[0:64]=A, aff[64:128]=C ----------------
__global__ __launch_bounds__(256) void k_bn_final(const float* __restrict__ pSum, const float* __restrict__ pSq,
                                                  const float* __restrict__ bn_g, const float* __restrict__ bn_b,
                                                  float* __restrict__ aff) {
  int c = blockIdx.x;
  float s = 0, q = 0;
  for (int i = threadIdx.x; i < 8192; i += 256) {
    s += pSum[(size_t)i * 64 + c];
    q += pSq[(size_t)i * 64 + c];
  }
  __shared__ float rs[256], rq[256];
  rs[threadIdx.x] = s; rq[threadIdx.x] = q;
  __syncthreads();
  for (int st = 128; st > 0; st >>= 1) {
    if (threadIdx.x < st) { rs[threadIdx.x] += rs[threadIdx.x + st]; rq[threadIdx.x] += rq[threadIdx.x + st]; }
    __syncthreads();
  }
  if (threadIdx.x == 0) {
    float mu = rs[0] / (float)N_TOT;
    float var = rq[0] / (float)N_TOT - mu * mu;
    var = fmaxf(var, 0.0f);
    float A = bn_g[c] * rsqrtf(var + 1e-5f);
    aff[c] = A;
    aff[64 + c] = bn_b[c] - mu * A;
  }
}

// ---------------- K2b: LSTM step1 from biases only; shared part of step-2 gates ----------------
__global__ __launch_bounds__(256) void k_lstm1(const float* __restrict__ bih, const float* __restrict__ bhh,
                                               const float* __restrict__ wih, const float* __restrict__ whh,
                                               float* __restrict__ q1, float* __restrict__ c1, float* __restrict__ sh2) {
  __shared__ float g1[256];
  __shared__ float q1s[64];
  int tid = threadIdx.x;
  g1[tid] = bih[tid] + bhh[tid];
  __syncthreads();
  if (tid < 64) {
    float ig = sigf(g1[tid]);
    float gg = tanhf(g1[128 + tid]);
    float cc = ig * gg;
    float og = sigf(g1[192 + tid]);
    float qv = og * tanhf(cc);
    q1s[tid] = qv; q1[tid] = qv; c1[tid] = cc;
  }
  __syncthreads();
  float acc = g1[tid];
  for (int k = 0; k < 64; k++)
    acc = fmaf(wih[(size_t)tid * 128 + k] + whh[(size_t)tid * 64 + k], q1s[k], acc);
  sh2[tid] = acc;
}

// ---------------- K3: streaming gate: bf16 h -> LDS f32 -> thread-per-row dot (no atomics) ----------------
__global__ __launch_bounds__(256) void k_gate_h(const unsigned short* __restrict__ h, const float* __restrict__ aff,
                                                const float* __restrict__ w2, const float* __restrict__ cb2,
                                                const float* __restrict__ eps_gate,
                                                float* __restrict__ lamWS, float* __restrict__ lamOut,
                                                int* __restrict__ presPart) {
  __shared__ float Hs[64][65];
  __shared__ float A2s[64], C2s[64], w2s[64];
  __shared__ int pcnt[4];
  int tid = threadIdx.x;
  if (tid < 64) { A2s[tid] = aff[tid]; C2s[tid] = aff[64 + tid]; w2s[tid] = w2[tid]; }
  int n0 = blockIdx.x * 64;
#pragma unroll
  for (int s = 0; s < 4; s++) {
    int e4 = tid * 4 + s * 1024;
    int r = e4 >> 6, c = e4 & 63;
    ushort4 v = *(const ushort4*)&h[(size_t)(n0 + r) * 64 + c];
    Hs[r][c] = bf2f(v.x); Hs[r][c + 1] = bf2f(v.y);
    Hs[r][c + 2] = bf2f(v.z); Hs[r][c + 3] = bf2f(v.w);
  }
  __syncthreads();
  int r = tid >> 2, q = tid & 3;
  float p = 0.f;
#pragma unroll
  for (int j = 0; j < 16; j++) {
    int d = q * 16 + j;
    p = fmaf(fmaxf(fmaf(Hs[r][d], A2s[d], C2s[d]), 0.f), w2s[d], p);
  }
  p += __shfl_xor(p, 1);
  p += __shfl_xor(p, 2);
  p += cb2[0];
  unsigned long long m = __ballot(q == 0 && p > 0.0f);
  if ((tid & 63) == 0) pcnt[tid >> 6] = (int)__popcll(m);
  if (q == 0) {
    int row = n0 + r;
    float eg = eps_gate[row];
    float eps = 0.9999f - 0.9998f * eg;
    float gi = (flog2(eps) - flog2(1.0f - eps)) * LN2;
    float lam = sigf(gi + p);
    lamWS[row] = lam;
    lamOut[row] = lam;
  }
  __syncthreads();
  if (tid == 0) presPart[blockIdx.x] = pcnt[0] + pcnt[1] + pcnt[2] + pcnt[3];
}

// ---------------- K4: register-resident wave-per-graph pipeline with DPP reductions ----------------
__global__ __launch_bounds__(256) void k_graph_reg(const float* __restrict__ X, const float* __restrict__ noise,
                                                   const float* __restrict__ lam, const int* __restrict__ off,
                                                   const float* __restrict__ q1g, const float* __restrict__ c1g,
                                                   const float* __restrict__ sh2g, const float* __restrict__ rtg,
                                                   unsigned short* __restrict__ noisyFB, float* __restrict__ qstar,
                                                   float* __restrict__ klp) {
  int wg = blockIdx.x * 4 + (threadIdx.x >> 6);
  int lane = threadIdx.x & 63;
  int n0 = off[wg], cnt = off[wg + 1] - n0;
  const float THR = 8.f;
  const float* xp = X + (size_t)n0 * 64 + lane;
  const float* zp = noise + (size_t)n0 * 64 + lane;
  float r1v = 0.f;
  bool fits = (cnt <= CAPR);
  unsigned int pk[CAPR / 2];

  if (cnt > 0 && fits) {
    float s0 = 0.f, q0 = 0.f, s1 = 0.f, q1_ = 0.f;
#pragma unroll
    for (int np = 0; np < CAPR / 2; np++) {
      int n = 2 * np;
      if (n < cnt) {
        float a = xp[(size_t)n * 64];
        s0 += a; q0 = fmaf(a, a, q0);
        float b = 0.f;
        if (n + 1 < cnt) {
          b = xp[(size_t)(n + 1) * 64];
          s1 += b; q1_ = fmaf(b, b, q1_);
        }
        pk[np] = (f2bf(b) << 16) | f2bf(a);
      }
    }
    float c = (float)cnt;
    float mean = (s0 + s1) / c;
    float var = fmaxf(((q0 + q1_) - c * mean * mean) / fmaxf(c - 1.f, 1.f), 0.f);
    float sd = sqrtf(var);
    float inv = frcp(sd + 1e-7f);
    float S1 = wave_red(sd * sd * inv * inv);
    float q1v2 = q1g[lane] * LOG2E;
    float t2acc = 0.f, sumOm2 = 0.f;
    float m0 = -INFINITY, l0 = 0.f, r0 = 0.f;
    float m1 = -INFINITY, l1 = 0.f, r1a = 0.f;
#pragma unroll
    for (int np = 0; np < CAPR / 2; np++) {
      int n = 2 * np;
      if (n < cnt) {
        bool hasB = (n + 1 < cnt);
        unsigned int p2 = pk[np];
        float xA = bf2f(p2 & 0xffffu), xB = bf2f(p2 >> 16);
        float lamA = lam[n0 + n];
        float zA = zp[(size_t)n * 64];
        float lamB = hasB ? lam[n0 + n + 1] : 0.f;
        float zB = hasB ? zp[(size_t)(n + 1) * 64] : 0.f;
        float omA = 1.f - lamA, omB = 1.f - lamB;
        float nvA = fmaf(lamA, xA, omA * mean) + zA * (omA * sd);
        float nvB = fmaf(lamB, xB, omB * mean) + zB * (omB * sd);
        pk[np] = (f2bf(nvB) << 16) | f2bf(nvA);
        float ldA = lamA * (xA - mean) * inv; t2acc = fmaf(ldA, ldA, t2acc);
        sumOm2 = fmaf(omA, omA, sumOm2);
        if (hasB) {
          float ldB = lamB * (xB - mean) * inv; t2acc = fmaf(ldB, ldB, t2acc);
          sumOm2 = fmaf(omB, omB, sumOm2);
        }
        float e0 = wave_red(nvA * q1v2);
        float e1 = hasB ? wave_red(nvB * q1v2) : 0.f;
        if (e0 > m0 + THR) { float sc = fexp2(m0 - e0); l0 *= sc; r0 *= sc; m0 = e0; }
        float pA = fexp2(e0 - m0); l0 += pA; r0 = fmaf(pA, nvA, r0);
        if (hasB) {
          if (e1 > m1 + THR) { float sc = fexp2(m1 - e1); l1 *= sc; r1a *= sc; m1 = e1; }
          float pB = fexp2(e1 - m1); l1 += pB; r1a = fmaf(pB, nvB, r1a);
        }
      }
    }
    float M = fmaxf(m0, m1);
    float sc0 = fexp2(m0 - M), sc1 = (m1 == -INFINITY) ? 0.f : fexp2(m1 - M);
    float L = l0 * sc0 + l1 * sc1;
    float R = r0 * sc0 + r1a * sc1;
    r1v = R / L;
    float t2tot = wave_red(t2acc);
    if (lane == 0) klp[wg] = fmaf(0.5f * sumOm2, S1, t2tot);
  } else if (cnt > 0) {
    unsigned short* nw = noisyFB + (size_t)n0 * 64 + lane;
    float s0 = 0.f, q0 = 0.f;
    for (int n = 0; n < cnt; n++) { float a = xp[(size_t)n * 64]; s0 += a; q0 = fmaf(a, a, q0); }
    float c = (float)cnt;
    float mean = s0 / c;
    float var = fmaxf((q0 - c * mean * mean) / fmaxf(c - 1.f, 1.f), 0.f);
    float sd = sqrtf(var);
    float inv = frcp(sd + 1e-7f);
    float S1 = wave_red(sd * sd * inv * inv);
    float q1v2 = q1g[lane] * LOG2E;
    float t2acc = 0.f, sumOm2 = 0.f;
    float m0 = -INFINITY, l0 = 0.f, r0 = 0.f;
    for (int n = 0; n < cnt; n++) {
      float lamA = lam[n0 + n];
      float xA = xp[(size_t)n * 64];
      float zA = zp[(size_t)n * 64];
      float omA = 1.f - lamA;
      float nvA = fmaf(lamA, xA, omA * mean) + zA * (omA * sd);
      nw[(size_t)n * 64] = (unsigned short)f2bf(nvA);
      float ldA = lamA * (xA - mean) * inv; t2acc = fmaf(ldA, ldA, t2acc);
      sumOm2 = fmaf(omA, omA, sumOm2);
      float e0 = wave_red(nvA * q1v2);
      if (e0 > m0 + THR) { float sc = fexp2(m0 - e0); l0 *= sc; r0 *= sc; m0 = e0; }
      float pA = fexp2(e0 - m0); l0 += pA; r0 = fmaf(pA, nvA, r0);
    }
    r1v = r0 / l0;
    float t2tot = wave_red(t2acc);
    if (lane == 0) klp[wg] = fmaf(0.5f * sumOm2, S1, t2tot);
  } else {
    if (lane == 0) klp[wg] = 0.0f;
  }

  // ---- fused LSTM step 2 ----
  float a0 = 0.f, a1 = 0.f, a2 = 0.f, a3 = 0.f;
  const float4* rt = (const float4*)rtg;
#pragma unroll 4
  for (int k = 0; k < 64; k++) {
    float rk = __shfl(r1v, k);
    float4 w = rt[k * 64 + lane];
    a0 = fmaf(w.x, rk, a0); a1 = fmaf(w.y, rk, a1);
    a2 = fmaf(w.z, rk, a2); a3 = fmaf(w.w, rk, a3);
  }
  float ig = a0 + sh2g[lane];
  float fg = a1 + sh2g[64 + lane];
  float gg = a2 + sh2g[128 + lane];
  float og = a3 + sh2g[192 + lane];
  float c2 = sigf(fg) * c1g[lane] + sigf(ig) * tanhf(gg);
  float q2 = sigf(og) * tanhf(c2);
  qstar[(size_t)wg * 128 + lane] = q2;

  // ---- fused attention step 2 from registers ----
  float r2v = 0.f;
  if (cnt > 0) {
    float q2v2 = q2 * LOG2E;
    float m0 = -INFINITY, l0 = 0.f, r0 = 0.f;
    float m1 = -INFINITY, l1 = 0.f, r1a = 0.f;
    if (fits) {
#pragma unroll
      for (int np = 0; np < CAPR / 2; np++) {
        int n = 2 * np;
        if (n < cnt) {
          bool hasB = (n + 1 < cnt);
          unsigned int p2 = pk[np];
          float nvA = bf2f(p2 & 0xffffu), nvB = bf2f(p2 >> 16);
          float e0 = wave_red(nvA * q2v2);
          float e1 = hasB ? wave_red(nvB * q2v2) : 0.f;
          if (e0 > m0 + THR) { float sc = fexp2(m0 - e0); l0 *= sc; r0 *= sc; m0 = e0; }
          float pA = fexp2(e0 - m0); l0 += pA; r0 = fmaf(pA, nvA, r0);
          if (hasB) {
            if (e1 > m1 + THR) { float sc = fexp2(m1 - e1); l1 *= sc; r1a *= sc; m1 = e1; }
            float pB = fexp2(e1 - m1); l1 += pB; r1a = fmaf(pB, nvB, r1a);
          }
        }
      }
    } else {
      const unsigned short* np_ = noisyFB + (size_t)n0 * 64 + lane;
      for (int n = 0; n < cnt; n++) {
        float nvA = bf2f(np_[(size_t)n * 64]);
        float e0 = wave_red(nvA * q2v2);
        if (e0 > m0 + THR) { float sc = fexp2(m0 - e0); l0 *= sc; r0 *= sc; m0 = e0; }
        float pA = fexp2(e0 - m0); l0 += pA; r0 = fmaf(pA, nvA, r0);
      }
    }
    float M = fmaxf(m0, m1);
    float sc0 = fexp2(m0 - M), sc1 = (m1 == -INFINITY) ? 0.f : fexp2(m1 - M);
    float L = l0 * sc0 + l1 * sc1;
    float R = r0 * sc0 + r1a * sc1;
    r2v = R / L;
  }
  qstar[(size_t)wg * 128 + 64 + lane] = r2v;
}

// ---------------- K7/8/9: predictor linear layers (pre-transposed weights) ----------------
template <int KDIM, int ODIM, bool RELU>
__global__ __launch_bounds__(256) void k_linear(const float* __restrict__ A, const float* __restrict__ WT,
                                                const float* __restrict__ bias, float* __restrict__ C) {
  __shared__ float As[64][68];
  __shared__ float Wt[64][68];
  int tid = threadIdx.x, ty = tid >> 4, tx = tid & 15;
  int n0 = blockIdx.x * 64, c0 = blockIdx.y * 64;
  float acc[4][4] = {};
  for (int kt = 0; kt < KDIM; kt += 64) {
    __syncthreads();
    load_A64(A, KDIM, n0, kt, As, tid);
    load_A64(WT, ODIM, kt, c0, Wt, tid);
    __syncthreads();
    mm64(As, Wt, ty, tx, acc);
  }
#pragma unroll
  for (int i = 0; i < 4; i++) {
    int row = n0 + ty * 4 + i;
    float4 o;
    float v0 = acc[i][0] + bias[c0 + tx * 4 + 0];
    float v1 = acc[i][1] + bias[c0 + tx * 4 + 1];
    float v2 = acc[i][2] + bias[c0 + tx * 4 + 2];
    float v3 = acc[i][3] + bias[c0 + tx * 4 + 3];
    if (RELU) { v0 = fmaxf(v0, 0.f); v1 = fmaxf(v1, 0.f); v2 = fmaxf(v2, 0.f); v3 = fmaxf(v3, 0.f); }
    o.x = v0; o.y = v1; o.z = v2; o.w = v3;
    *(float4*)&C[(size_t)row * ODIM + c0 + tx * 4] = o;
  }
}

// ---------------- K10: final scalars ----------------
__global__ __launch_bounds__(256) void k_final(const float* __restrict__ klp, const int* __restrict__ presPart,
                                               float* __restrict__ out) {
  __shared__ float red[256];
  __shared__ int redi[256];
  float s = 0.0f;
  int pc = 0;
  for (int i = threadIdx.x; i < B_GR; i += 256) s += klp[i];
  for (int i = threadIdx.x; i < 8192; i += 256) pc += presPart[i];
  red[threadIdx.x] = s;
  redi[threadIdx.x] = pc;
  __syncthreads();
  for (int st = 128; st > 0; st >>= 1) {
    if (threadIdx.x < st) {
      red[threadIdx.x] += red[threadIdx.x + st];
      redi[threadIdx.x] += redi[threadIdx.x + st];
    }
    __syncthreads();
  }
  if (threadIdx.x == 0) {
    out[(size_t)B_GR * 64] = red[0] / (float)(B_GR * 64);
    out[(size_t)B_GR * 64 + 1] = (float)redi[0] / (float)N_TOT;
  }
}

// ---------------- launcher ----------------
extern "C" void kernel_launch(void* const* d_in, const int* in_sizes, int n_in,
                              void* d_out, int out_size, void* d_ws, size_t ws_size,
                              hipStream_t stream) {
  const float* features = (const float*)d_in[0];
  const int*   bidx     = (const int*)d_in[1];
  const float* eps_gate = (const float*)d_in[2];
  const float* noise    = (const float*)d_in[3];
  const float* c_w1 = (const float*)d_in[4];
  const float* c_b1 = (const float*)d_in[5];
  const float* bn_g = (const float*)d_in[6];
  const float* bn_b = (const float*)d_in[7];
  const float* c_w2 = (const float*)d_in[8];
  const float* c_b2 = (const float*)d_in[9];
  const float* wih  = (const float*)d_in[10];
  const float* whh  = (const float*)d_in[11];
  const float* bih  = (const float*)d_in[12];
  const float* bhh  = (const float*)d_in[13];
  const float* p_w1 = (const float*)d_in[14];
  const float* p_b1 = (const float*)d_in[15];
  const float* p_w2 = (const float*)d_in[16];
  const float* p_b2 = (const float*)d_in[17];
  const float* p_w3 = (const float*)d_in[18];
  const float* p_b3 = (const float*)d_in[19];
  float* out = (float*)d_out;

  float* wsf   = (float*)d_ws;
  int*   offp  = (int*)wsf;                                 // (B+1) ints
  float* pSum  = wsf + 16448;                               // 8192*64
  float* pSq   = pSum + 524288;                             // 8192*64
  float* aff   = pSq + 524288;                              // 128
  float* q1w   = aff + 128;                                 // 64
  float* c1w   = q1w + 64;                                  // 64
  float* sh2w  = c1w + 64;                                  // 256
  float* lamw  = sh2w + 256;                                // N
  float* pw1T  = lamw + (size_t)N_TOT;                      // 128*256
  float* pw2T  = pw1T + 32768;                              // 256*128
  float* pw3T  = pw2T + 32768;                              // 128*64
  float* rtgw  = pw3T + 8192;                               // 64*256 (RTg)
  unsigned short* wfragb = (unsigned short*)(rtgw + 16384); // 8*64*8 ushorts (4096)
  float* hwf   = rtgw + 16384 + 2048;                       // N*64 float-sized region
  unsigned short* hb = (unsigned short*)hwf;                // h as bf16; later reused as noisy fallback
  unsigned short* noisyFB = hb;
  float* qstarw = hwf + (size_t)N_TOT * 64;                 // B*128
  float* z1w    = qstarw + (size_t)B_GR * 128;              // B*256
  float* z2w    = z1w + (size_t)B_GR * 256;                 // B*128
  float* klpw   = z2w + (size_t)B_GR * 128;                 // B
  int*   presPart = (int*)(klpw + B_GR);                    // 8192 ints

  float* lamOut = out + (size_t)B_GR * 64 + 2;

  k_offsets<<<(B_GR + 1 + 255) / 256, 256, 0, stream>>>(bidx, offp);
  k_prep<<<64, 256, 0, stream>>>(c_w1, p_w1, p_w2, p_w3, wih, pw1T, pw2T, pw3T, rtgw, wfragb);
  k_bn_stats<<<N_TOT / 64, 256, 0, stream>>>(features, wfragb, c_b1, hb, pSum, pSq);
  k_bn_final<<<64, 256, 0, stream>>>(pSum, pSq, bn_g, bn_b, aff);
  k_lstm1<<<1, 256, 0, stream>>>(bih, bhh, wih, whh, q1w, c1w, sh2w);
  k_gate_h<<<N_TOT / 64, 256, 0, stream>>>(hb, aff, c_w2, c_b2, eps_gate, lamw, lamOut, presPart);
  k_graph_reg<<<B_GR / 4, 256, 0, stream>>>(features, noise, lamw, offp, q1w, c1w, sh2w, rtgw,
                                            noisyFB, qstarw, klpw);
  k_linear<128, 256, true><<<dim3(B_GR / 64, 4), 256, 0, stream>>>(qstarw, pw1T, p_b1, z1w);
  k_linear<256, 128, true><<<dim3(B_GR / 64, 2), 256, 0, stream>>>(z1w, pw2T, p_b2, z2w);
  k_linear<128, 64, false><<<dim3(B_GR / 64, 1), 256, 0, stream>>>(z2w, pw3T, p_b3, out);
  k_final<<<1, 256, 0, stream>>>(klpw, presPart, out);
}